// Round 5
// baseline (1240.081 us; speedup 1.0000x reference)
//
#include <hip/hip_runtime.h>
#include <math.h>

#define HWN 65536

__device__ __forceinline__ float sgm(float x){ return 1.0f/(1.0f+expf(-x)); }

__device__ __forceinline__ void fma4(float acc[4], const float4 w,
                                     const float4 x0, const float4 x1,
                                     const float4 x2, const float4 x3){
    acc[0] += w.x*x0.x + w.y*x1.x + w.z*x2.x + w.w*x3.x;
    acc[1] += w.x*x0.y + w.y*x1.y + w.z*x2.y + w.w*x3.y;
    acc[2] += w.x*x0.z + w.y*x1.z + w.z*x2.z + w.w*x3.z;
    acc[3] += w.x*x0.w + w.y*x1.w + w.z*x2.w + w.w*x3.w;
}

// ---------------------------------------------------------------------------
// K1: input_proj + lb store + lgce_pre (+pooled partials) + qkv + gate.
//
// R5 (SGPR-broadcast, CHUNKED): R4 proved the scalar-pipe weight path works
// (SGPR=112) but 48-56 per-thread accumulators spilled (VGPR=52) -> every
// FMA became spill-shuffle, 522 us. Rule learned: live accs <= ~24 or the
// allocator demotes them. R5: lane = pixel, wave owns an output slice,
// outputs processed in chunks of 16 (acc[16] + xr[4] ~ 24 VGPR). Inner
// iter: 4 ds_read_b32 (2-way bank alias = free) + uniform s_load weights
// (scalar pipe) + 64 v_fmac -> ~95% FMA issue density, LDS:VALU = 0.18.
// Chunking forbids in-place overwrite, so proj output gets its own pt
// buffer: LDS 72 KB, 2 blocks/CU (occupancy proven irrelevant here, R1/R2).
// ---------------------------------------------------------------------------
__global__ __launch_bounds__(256,2) void k1_proj(
    const float* __restrict__ x,   const float* __restrict__ Wp,
    const float* __restrict__ Wpre,const float* __restrict__ bpre,
    const float* __restrict__ Wqkv,
    const float* __restrict__ Wg1, const float* __restrict__ bg1,
    const float* __restrict__ wg2, const float* __restrict__ bg2,
    float* __restrict__ lb, float* __restrict__ pre, float* __restrict__ qkv,
    float* __restrict__ pooled_part, float* __restrict__ gate_part)
{
    __shared__ float xs[128*64];          // 32 KB: x staging
    __shared__ float pt[128*64];          // 32 KB: proj output
    __shared__ float ht[32*64];           // 8 KB: gate hidden
    float4* xs4 = (float4*)xs;

    const int t    = threadIdx.x;
    const int blk  = blockIdx.x;
    const int b    = blk >> 10;           // 1024 blocks per batch
    const int p0   = (blk & 1023) << 6;   // 64 px / block
    const int px   = t & 63;              // lane = pixel
    const int wid  = __builtin_amdgcn_readfirstlane(t >> 6);  // wave id (SGPR)
    const int slot = blk & 63;

    const float4* x4 = (const float4*)x;

    // ---- stage all of x (single burst, coalesced float4)
    #pragma unroll
    for (int i = 0; i < 8; ++i) {
        int idx = t + 256*i;
        int c = idx >> 4, q = idx & 15;
        xs4[c*16 + q] = x4[(size_t)(b*128 + c)*16384 + (p0>>2) + q];
    }
    __syncthreads();

    auto wsum = [&](float val) {
        val += __shfl_xor(val,1);  val += __shfl_xor(val,2);  val += __shfl_xor(val,4);
        val += __shfl_xor(val,8);  val += __shfl_xor(val,16); val += __shfl_xor(val,32);
        return val;
    };

    // ---- proj (128x128): wave owns outs [wid*32, +32), 2 chunks of 16
    #pragma unroll
    for (int chk = 0; chk < 2; ++chk) {
        const int o0 = wid*32 + chk*16;
        float acc[16];
        #pragma unroll
        for (int o = 0; o < 16; ++o) acc[o] = 0.f;

        for (int cc = 0; cc < 128; cc += 4) {
            float xr0 = xs[(cc+0)*64 + px];
            float xr1 = xs[(cc+1)*64 + px];
            float xr2 = xs[(cc+2)*64 + px];
            float xr3 = xs[(cc+3)*64 + px];
            #pragma unroll
            for (int o = 0; o < 16; ++o) {
                const float* wr = &Wp[(o0+o)*128 + cc];   // SGPR-uniform
                acc[o] = fmaf(wr[0], xr0,
                         fmaf(wr[1], xr1,
                         fmaf(wr[2], xr2,
                         fmaf(wr[3], xr3, acc[o]))));
            }
        }
        #pragma unroll
        for (int o = 0; o < 16; ++o) pt[(o0+o)*64 + px] = acc[o];
        if (o0 < 64) {   // lb = proj channels 0..63 (wave-uniform branch)
            #pragma unroll
            for (int o = 0; o < 16; ++o)
                lb[(size_t)(b*64 + o0+o)*HWN + p0 + px] = acc[o];
        }
    }
    __syncthreads();       // proj output ready in pt

    // ---- pre conv (64x64): 1 chunk of 16 per wave
    {
        const int o0 = wid*16;
        float acc[16];
        #pragma unroll
        for (int o = 0; o < 16; ++o) acc[o] = 0.f;

        for (int cc = 0; cc < 64; cc += 4) {
            float xr0 = pt[(cc+0)*64 + px];
            float xr1 = pt[(cc+1)*64 + px];
            float xr2 = pt[(cc+2)*64 + px];
            float xr3 = pt[(cc+3)*64 + px];
            #pragma unroll
            for (int o = 0; o < 16; ++o) {
                const float* wr = &Wpre[(o0+o)*64 + cc];
                acc[o] = fmaf(wr[0], xr0,
                         fmaf(wr[1], xr1,
                         fmaf(wr[2], xr2,
                         fmaf(wr[3], xr3, acc[o]))));
            }
        }
        #pragma unroll
        for (int o = 0; o < 16; ++o) {
            float vv = acc[o] + bpre[o0+o];
            pre[(size_t)(b*64 + o0+o)*HWN + p0 + px] = vv;
            float s = wsum(vv);
            if (px == 0) atomicAdd(&pooled_part[slot*256 + b*64 + o0 + o], s);
        }
    }

    // ---- qkv conv (192x64): 3 chunks of 16 per wave
    #pragma unroll
    for (int chk = 0; chk < 3; ++chk) {
        const int o0 = wid*48 + chk*16;
        float acc[16];
        #pragma unroll
        for (int o = 0; o < 16; ++o) acc[o] = 0.f;

        for (int cc = 0; cc < 64; cc += 4) {
            float xr0 = pt[(64+cc+0)*64 + px];
            float xr1 = pt[(64+cc+1)*64 + px];
            float xr2 = pt[(64+cc+2)*64 + px];
            float xr3 = pt[(64+cc+3)*64 + px];
            #pragma unroll
            for (int o = 0; o < 16; ++o) {
                const float* wr = &Wqkv[(o0+o)*64 + cc];
                acc[o] = fmaf(wr[0], xr0,
                         fmaf(wr[1], xr1,
                         fmaf(wr[2], xr2,
                         fmaf(wr[3], xr3, acc[o]))));
            }
        }
        #pragma unroll
        for (int o = 0; o < 16; ++o)
            qkv[(size_t)(b*192 + o0+o)*HWN + p0 + px] = acc[o];
    }

    // ---- gate hidden (32x64): 1 chunk of 8 per wave
    {
        const int o0 = wid*8;
        float acc[8];
        #pragma unroll
        for (int o = 0; o < 8; ++o) acc[o] = 0.f;

        for (int cc = 0; cc < 64; cc += 4) {
            float xr0 = pt[(64+cc+0)*64 + px];
            float xr1 = pt[(64+cc+1)*64 + px];
            float xr2 = pt[(64+cc+2)*64 + px];
            float xr3 = pt[(64+cc+3)*64 + px];
            #pragma unroll
            for (int o = 0; o < 8; ++o) {
                const float* wr = &Wg1[(o0+o)*64 + cc];
                acc[o] = fmaf(wr[0], xr0,
                         fmaf(wr[1], xr1,
                         fmaf(wr[2], xr2,
                         fmaf(wr[3], xr3, acc[o]))));
            }
        }
        #pragma unroll
        for (int o = 0; o < 8; ++o)
            ht[(o0+o)*64 + px] = fmaxf(acc[o] + bg1[o0+o], 0.f);
    }
    __syncthreads();

    // ---- gate scalar
    if (t < 64) {
        float g = bg2[0];
        #pragma unroll
        for (int c = 0; c < 32; ++c) g += wg2[c]*ht[c*64 + t];
        g = sgm(g);
        g += __shfl_xor(g,1);  g += __shfl_xor(g,2);  g += __shfl_xor(g,4);
        g += __shfl_xor(g,8);  g += __shfl_xor(g,16); g += __shfl_xor(g,32);
        if (t == 0) atomicAdd(&gate_part[slot], g);
    }
}

// ---------------------------------------------------------------------------
// K2: pooled -> cw, gate mean -> kdyn. single block.
// ---------------------------------------------------------------------------
__global__ void k2_small(const float* __restrict__ pooled_part,
                         const float* __restrict__ gate_part,
                         const float* __restrict__ w1, const float* __restrict__ b1,
                         const float* __restrict__ w2, const float* __restrict__ b2,
                         float* __restrict__ cw, float* __restrict__ kdyn)
{
    __shared__ float pl[256];
    const int t = threadIdx.x;
    float s = 0.f;
    for (int sl = 0; sl < 64; ++sl) s += pooled_part[sl*256 + t];
    pl[t] = s * (1.0f/65536.0f);
    __syncthreads();
    const int b = t >> 6, g = (t >> 3) & 7, c = t & 7;
    float h0 = b1[g*2+0], h1 = b1[g*2+1];
    #pragma unroll
    for (int cc = 0; cc < 8; ++cc) {
        float p = pl[b*64 + g*8 + cc];
        h0 += p*w1[g*16 + 0*8 + cc];
        h1 += p*w1[g*16 + 1*8 + cc];
    }
    h0 = fmaxf(h0, 0.f); h1 = fmaxf(h1, 0.f);
    cw[t] = sgm(h0*w2[g*16 + c*2 + 0] + h1*w2[g*16 + c*2 + 1] + b2[g*8+c]);
    if (t == 0) {
        float gs = 0.f;
        for (int sl = 0; sl < 64; ++sl) gs += gate_part[sl];
        float kd = floorf(8.0f * (gs * (1.0f/262144.0f)));
        *kdyn = fminf(fmaxf(kd, 1.0f), 8.0f);
    }
}

// ---------------------------------------------------------------------------
// K3: resp partial sums for thr.
// ---------------------------------------------------------------------------
__global__ __launch_bounds__(256) void k3_thr(
    const float* __restrict__ pre, const float* __restrict__ cw,
    const float* __restrict__ sw,  const float* __restrict__ sb,
    float* __restrict__ thr_sum)
{
    __shared__ float part[4][8];
    const int t = threadIdx.x;
    const int b = blockIdx.x >> 8;
    const int p = ((blockIdx.x & 255) << 8) + t;
    float rs[8];
    #pragma unroll
    for (int g = 0; g < 8; ++g) {
        float xc[8];
        float spa = sb[g];
        #pragma unroll
        for (int c = 0; c < 8; ++c) {
            float xv = pre[(size_t)(b*64 + g*8 + c)*HWN + p];
            xc[c] = xv * cw[b*64 + g*8 + c];
            spa += xc[c]*sw[g*8 + c];
        }
        float sp = sgm(spa);
        float s = 0.f;
        #pragma unroll
        for (int c = 0; c < 8; ++c) s += sgm(xc[c]*sp);
        rs[g] = s;
    }
    const int lane = t & 63, wv = t >> 6;
    #pragma unroll
    for (int g = 0; g < 8; ++g) {
        float val = rs[g];
        val += __shfl_xor(val,1);  val += __shfl_xor(val,2);  val += __shfl_xor(val,4);
        val += __shfl_xor(val,8);  val += __shfl_xor(val,16); val += __shfl_xor(val,32);
        if (lane == 0) part[wv][g] = val;
    }
    __syncthreads();
    if (t < 8)
        atomicAdd(&thr_sum[b*8 + t], part[0][t]+part[1][t]+part[2][t]+part[3][t]);
}

// ---------------------------------------------------------------------------
// K4: depthwise 3x3; block = (b, h, 8-row band of 256 cols).
// In-loop wave-reduced Gram/norm accumulation (no S[64] array -> no spill),
// double-buffered LDS, launch_bounds(256,3). See R3 notes.
// ---------------------------------------------------------------------------
#define K4_ROWSTRIDE 264            // 4 pad | 256 data | 4 pad (floats)
#define K4_BUF (10*K4_ROWSTRIDE)    // 10 halo rows

__global__ __launch_bounds__(256,3) void k4_dw(
    const float* __restrict__ qkv, const float* __restrict__ dww,
    float* __restrict__ v, float* __restrict__ Sg, float* __restrict__ sumsq)
{
    __shared__ float sh[2*K4_BUF];  // 21120 B

    const int t    = threadIdx.x;
    const int b    = blockIdx.x >> 8;         // 256 blocks / batch
    const int h    = (blockIdx.x >> 5) & 7;
    const int band = blockIdx.x & 31;
    const int r0   = band * 8;
    const int lr   = t >> 5;                  // output row 0..7
    const int c0   = (t & 31) * 4;            // group0 cols c0..c0+3; group1 +128
    const int lane = t & 63;

    // edge columns (global col -1 and 256) are always zero; init once per buffer
    if (t < 40) {
        int bufi = t / 20, r = (t % 20) >> 1, side = t & 1;
        sh[bufi*K4_BUF + r*K4_ROWSTRIDE + (side ? 260 : 3)] = 0.0f;
    }

    float4 reg[3];

    auto issue_loads = [&](int ch) {
        const float4* base = (const float4*)(qkv + (size_t)(b*192 + ch)*HWN);
        #pragma unroll
        for (int j = 0; j < 3; ++j) {
            int i = t + 256*j;
            float4 val = make_float4(0.f,0.f,0.f,0.f);
            if (i < 640) {
                int row = i >> 6, col4 = i & 63;
                int gy = r0 - 1 + row;
                if (gy >= 0 && gy < 256) val = base[gy*64 + col4];
            }
            reg[j] = val;
        }
    };

    auto write_lds = [&](float* buf) {
        #pragma unroll
        for (int j = 0; j < 3; ++j) {
            int i = t + 256*j;
            if (i < 640) {
                int row = i >> 6, col4 = i & 63;
                *(float4*)&buf[row*K4_ROWSTRIDE + 4 + col4*4] = reg[j];
            }
        }
    };

    auto conv8 = [&](const float* buf, const float* __restrict__ w9, float out[8]) {
        #pragma unroll
        for (int g = 0; g < 2; ++g) {
            const int cc = c0 + g*128;
            float a0=0.f, a1=0.f, a2=0.f, a3=0.f;
            #pragma unroll
            for (int rr = 0; rr < 3; ++rr) {
                const float* row = &buf[(lr+rr)*K4_ROWSTRIDE + 4 + cc];
                float4 m = *(const float4*)row;
                float l = row[-1], r = row[4];
                float w0 = w9[rr*3+0], w1 = w9[rr*3+1], w2 = w9[rr*3+2];
                a0 = fmaf(w0,l,   fmaf(w1,m.x, fmaf(w2,m.y, a0)));
                a1 = fmaf(w0,m.x, fmaf(w1,m.y, fmaf(w2,m.z, a1)));
                a2 = fmaf(w0,m.y, fmaf(w1,m.z, fmaf(w2,m.w, a2)));
                a3 = fmaf(w0,m.z, fmaf(w1,m.w, fmaf(w2,r,   a3)));
            }
            out[g*4+0]=a0; out[g*4+1]=a1; out[g*4+2]=a2; out[g*4+3]=a3;
        }
    };

    auto wsum = [&](float val) {
        val += __shfl_xor(val,1);  val += __shfl_xor(val,2);  val += __shfl_xor(val,4);
        val += __shfl_xor(val,8);  val += __shfl_xor(val,16); val += __shfl_xor(val,32);
        return val;
    };

    float dq[8][8];

    float* sq_q = &sumsq[b*128 + h*8];
    float* sq_k = &sumsq[b*128 + 64 + h*8];
    float* Sgb  = &Sg[(size_t)(b*8+h)*64];

    issue_loads(h*8 + 0);   // first q channel

    // ---- Q channels: conv + immediate ||q||^2 partial
    #pragma unroll
    for (int ch = 0; ch < 8; ++ch) {
        float* buf = sh + (ch & 1)*K4_BUF;
        write_lds(buf);
        issue_loads(ch < 7 ? (h*8 + ch + 1) : (64 + h*8));
        __syncthreads();
        conv8(buf, dww + (h*8 + ch)*9, dq[ch]);
        float ss = 0.f;
        #pragma unroll
        for (int p = 0; p < 8; ++p) ss = fmaf(dq[ch][p], dq[ch][p], ss);
        ss = wsum(ss);
        if (lane == 0) atomicAdd(&sq_q[ch], ss);
    }

    // ---- K channels: conv + Gram row + ||k||^2, all reduced in-loop
    #pragma unroll
    for (int ch = 0; ch < 8; ++ch) {
        float* buf = sh + (ch & 1)*K4_BUF;
        write_lds(buf);
        issue_loads(ch < 7 ? (64 + h*8 + ch + 1) : (128 + h*8));
        __syncthreads();
        float dk[8];
        conv8(buf, dww + (64 + h*8 + ch)*9, dk);
        float ss = 0.f;
        #pragma unroll
        for (int p = 0; p < 8; ++p) ss = fmaf(dk[p], dk[p], ss);
        ss = wsum(ss);
        if (lane == 0) atomicAdd(&sq_k[ch], ss);
        #pragma unroll
        for (int c = 0; c < 8; ++c) {
            float acc = 0.f;
            #pragma unroll
            for (int p = 0; p < 8; ++p) acc = fmaf(dq[c][p], dk[p], acc);
            acc = wsum(acc);
            if (lane == 0) atomicAdd(&Sgb[c*8 + ch], acc);
        }
    }

    // ---- V channels (compute + store only)
    #pragma unroll
    for (int ch = 0; ch < 8; ++ch) {
        float* buf = sh + (ch & 1)*K4_BUF;
        write_lds(buf);
        if (ch < 7) issue_loads(128 + h*8 + ch + 1);
        __syncthreads();
        float dv[8];
        conv8(buf, dww + (128 + h*8 + ch)*9, dv);
        float* vb = v + (size_t)(b*64 + h*8 + ch)*HWN + (r0 + lr)*256;
        *(float4*)&vb[c0]       = make_float4(dv[0],dv[1],dv[2],dv[3]);
        *(float4*)&vb[c0 + 128] = make_float4(dv[4],dv[5],dv[6],dv[7]);
    }
}

// ---------------------------------------------------------------------------
// K6: finalize attention weights and thr. single block.
// ---------------------------------------------------------------------------
__global__ void k6_attn(const float* __restrict__ Sg, const float* __restrict__ sumsq,
                        const float* __restrict__ temp, const float* __restrict__ kdynp,
                        const float* __restrict__ thr_sum, const float* __restrict__ scales,
                        float* __restrict__ A, float* __restrict__ thr)
{
    const int t = threadIdx.x;
    if (t < 32) thr[t] = thr_sum[t] * (1.0f/(8.0f*65536.0f));
    const int b = t >> 6, h = (t >> 3) & 7, c = t & 7;
    const float kd = *kdynp;
    const float ssum = scales[0]+scales[1]+scales[2]+scales[3];
    const float nq = fmaxf(sqrtf(sumsq[b*128 + h*8 + c]), 1e-12f);
    const float tv = temp[h];
    const float* Srow = Sg + (size_t)(b*8+h)*64 + c*8;
    float a[8];
    #pragma unroll
    for (int d = 0; d < 8; ++d) {
        float nk = fmaxf(sqrtf(sumsq[b*128 + 64 + h*8 + d]), 1e-12f);
        a[d] = Srow[d] / (nq*nk) * tv;
    }
    bool keep[8];
    #pragma unroll
    for (int d = 0; d < 8; ++d) {
        int r = 0;
        #pragma unroll
        for (int e = 0; e < 8; ++e)
            r += (a[e] > a[d]) || (a[e] == a[d] && e < d);
        keep[d] = ((float)r < kd);
    }
    float m = -INFINITY;
    #pragma unroll
    for (int d = 0; d < 8; ++d) if (keep[d]) m = fmaxf(m, a[d]);
    float ex[8]; float sum = 0.f;
    #pragma unroll
    for (int d = 0; d < 8; ++d) { ex[d] = keep[d] ? expf(a[d]-m) : 0.f; sum += ex[d]; }
    const float inv = ssum / sum;
    #pragma unroll
    for (int d = 0; d < 8; ++d)
        A[(size_t)(b*8+h)*64 + c*8 + d] = ex[d]*inv;
}

// ---------------------------------------------------------------------------
// K7: mask path + post conv + residual + attn@v + proj_out, fused epilogue.
// R1 ft-based version (known-good); (256,2).
// ---------------------------------------------------------------------------
__global__ __launch_bounds__(256,2) void k7_final(
    const float* __restrict__ pre, const float* __restrict__ lb, const float* __restrict__ v,
    const float* __restrict__ cw,  const float* __restrict__ thr,
    const float* __restrict__ sw,  const float* __restrict__ sb,
    const float* __restrict__ A,
    const float* __restrict__ Wpost, const float* __restrict__ bpost,
    const float* __restrict__ Wout,  float* __restrict__ out)
{
    __shared__ float pr[64*64];
    __shared__ float vt[64*64];
    __shared__ float ft[128*64];
    float4* pr4 = (float4*)pr;
    float4* vt4 = (float4*)vt;
    float4* ft4 = (float4*)ft;

    const int t   = threadIdx.x;
    const int blk = blockIdx.x;
    const int b   = blk >> 10;
    const int p0  = (blk & 1023) << 6;
    const int pg  = t & 15;
    const int og  = t >> 4;

    const float4* pre4g = (const float4*)pre;
    const float4* v4g   = (const float4*)v;
    #pragma unroll
    for (int i = 0; i < 4; ++i) {
        int idx = t + 256*i;
        int c = idx >> 4, q = idx & 15;
        size_t gi = (size_t)(b*64 + c)*16384 + (p0>>2) + q;
        pr4[c*16+q] = pre4g[gi];
        vt4[c*16+q] = v4g[gi];
    }
    __syncthreads();

    #pragma unroll
    for (int s = 0; s < 2; ++s) {
        int task = t + 256*s;
        int g = task >> 6, px = task & 63;
        float xc[8], xv[8];
        float spa = sb[g];
        #pragma unroll
        for (int c = 0; c < 8; ++c) {
            xv[c] = pr[(g*8+c)*64 + px];
            xc[c] = xv[c]*cw[b*64 + g*8 + c];
            spa += xc[c]*sw[g*8 + c];
        }
        float sp = sgm(spa);
        float th = thr[b*8 + g];
        #pragma unroll
        for (int c = 0; c < 8; ++c) {
            float resp = sgm(xc[c]*sp);
            float mask = resp > th ? 1.0f : resp;
            pr[(g*8+c)*64 + px] = xv[c]*mask;
        }
    }
    __syncthreads();

    {
        const int o0 = og*4;
        float acc[4][4];
        #pragma unroll
        for (int j=0;j<4;++j){acc[j][0]=0.f;acc[j][1]=0.f;acc[j][2]=0.f;acc[j][3]=0.f;}
        const float4* W4 = (const float4*)Wpost;
        for (int c = 0; c < 64; c += 4) {
            float4 x0 = pr4[(c+0)*16+pg];
            float4 x1 = pr4[(c+1)*16+pg];
            float4 x2 = pr4[(c+2)*16+pg];
            float4 x3 = pr4[(c+3)*16+pg];
            #pragma unroll
            for (int j=0;j<4;++j)
                fma4(acc[j], W4[(o0+j)*16 + (c>>2)], x0,x1,x2,x3);
        }
        const float4* lb4 = (const float4*)lb;
        #pragma unroll
        for (int j=0;j<4;++j){
            float bs = bpost[o0+j];
            float4 lv = lb4[(size_t)(b*64 + o0+j)*16384 + (p0>>2) + pg];
            ft4[(64+o0+j)*16 + pg] = make_float4(acc[j][0]+bs+lv.x, acc[j][1]+bs+lv.y,
                                                 acc[j][2]+bs+lv.z, acc[j][3]+bs+lv.w);
        }
    }

    {
        const int ch0 = og*4;
        #pragma unroll
        for (int j = 0; j < 4; ++j) {
            int ch = ch0 + j;
            int hh = ch >> 3, c = ch & 7;
            const float* Ar = A + (size_t)(b*8+hh)*64 + c*8;
            float4 acc = make_float4(0.f,0.f,0.f,0.f);
            #pragma unroll
            for (int d = 0; d < 8; ++d) {
                float av = Ar[d];
                float4 vv = vt4[(hh*8+d)*16 + pg];
                acc.x += av*vv.x; acc.y += av*vv.y; acc.z += av*vv.z; acc.w += av*vv.w;
            }
            ft4[ch*16 + pg] = acc;
        }
    }
    __syncthreads();

    {
        const int o0 = og*8;
        float acc[8][4];
        #pragma unroll
        for (int j=0;j<8;++j){acc[j][0]=0.f;acc[j][1]=0.f;acc[j][2]=0.f;acc[j][3]=0.f;}
        const float4* W4 = (const float4*)Wout;
        for (int c = 0; c < 128; c += 4) {
            float4 x0 = ft4[(c+0)*16+pg];
            float4 x1 = ft4[(c+1)*16+pg];
            float4 x2 = ft4[(c+2)*16+pg];
            float4 x3 = ft4[(c+3)*16+pg];
            #pragma unroll
            for (int j=0;j<8;++j)
                fma4(acc[j], W4[(o0+j)*32 + (c>>2)], x0,x1,x2,x3);
        }
        float4* out4 = (float4*)out;
        #pragma unroll
        for (int j=0;j<8;++j)
            out4[(size_t)(b*128 + o0+j)*16384 + (p0>>2) + pg] =
                make_float4(acc[j][0],acc[j][1],acc[j][2],acc[j][3]);
    }
}

// ---------------------------------------------------------------------------
extern "C" void kernel_launch(void* const* d_in, const int* in_sizes, int n_in,
                              void* d_out, int out_size, void* d_ws, size_t ws_size,
                              hipStream_t stream)
{
    const float* x     = (const float*)d_in[0];
    const float* Wp    = (const float*)d_in[1];
    const float* Wpre  = (const float*)d_in[2];
    const float* bpre  = (const float*)d_in[3];
    const float* w1    = (const float*)d_in[4];
    const float* b1    = (const float*)d_in[5];
    const float* w2    = (const float*)d_in[6];
    const float* b2    = (const float*)d_in[7];
    const float* sw    = (const float*)d_in[8];
    const float* sb    = (const float*)d_in[9];
    const float* Wpost = (const float*)d_in[10];
    const float* bpost = (const float*)d_in[11];
    const float* Wqkv  = (const float*)d_in[12];
    const float* dww   = (const float*)d_in[13];
    const float* Wg1   = (const float*)d_in[14];
    const float* bg1   = (const float*)d_in[15];
    const float* wg2   = (const float*)d_in[16];
    const float* bg2   = (const float*)d_in[17];
    const float* temp  = (const float*)d_in[18];
    const float* scales= (const float*)d_in[19];
    const float* Wout  = (const float*)d_in[20];
    float* out = (float*)d_out;

    float* ws = (float*)d_ws;
    float* pooled_part = ws;                 // 16384
    float* gate_part   = ws + 16384;         // 64
    float* thr_sum     = ws + 16448;         // 32
    float* sumsq       = ws + 16480;         // 512
    float* Sg          = ws + 16992;         // 2048
    float* cw          = ws + 19040;         // 256
    float* kdyn        = ws + 19296;         // 1
    float* thr         = ws + 19328;         // 32
    float* A           = ws + 19360;         // 2048

    float* lb  = ws + 32768;
    float* pre = lb  + 16777216;
    float* qkv = pre + 16777216;
    float* v   = qkv + 50331648;

    hipMemsetAsync(ws, 0, (size_t)19040*sizeof(float), stream);

    k1_proj <<<4096, 256, 0, stream>>>(x, Wp, Wpre, bpre, Wqkv, Wg1, bg1, wg2, bg2,
                                       lb, pre, qkv, pooled_part, gate_part);
    k2_small<<<1,    256, 0, stream>>>(pooled_part, gate_part, w1, b1, w2, b2, cw, kdyn);
    k3_thr  <<<1024, 256, 0, stream>>>(pre, cw, sw, sb, thr_sum);
    k4_dw   <<<1024, 256, 0, stream>>>(qkv, dww, v, Sg, sumsq);
    k6_attn <<<1,    256, 0, stream>>>(Sg, sumsq, temp, kdyn, thr_sum, scales, A, thr);
    k7_final<<<4096, 256, 0, stream>>>(pre, lb, v, cw, thr, sw, sb, A,
                                       Wpost, bpost, Wout, out);
}

// Round 6
// 875.556 us; speedup vs baseline: 1.4163x; 1.4163x over previous
//
#include <hip/hip_runtime.h>
#include <math.h>

#define HWN 65536

__device__ __forceinline__ float sgm(float x){ return 1.0f/(1.0f+expf(-x)); }

__device__ __forceinline__ void fma4(float acc[4], const float4 w,
                                     const float4 x0, const float4 x1,
                                     const float4 x2, const float4 x3){
    acc[0] += w.x*x0.x + w.y*x1.x + w.z*x2.x + w.w*x3.x;
    acc[1] += w.x*x0.y + w.y*x1.y + w.z*x2.y + w.w*x3.y;
    acc[2] += w.x*x0.z + w.y*x1.z + w.z*x2.z + w.w*x3.z;
    acc[3] += w.x*x0.w + w.y*x1.w + w.z*x2.w + w.w*x3.w;
}

// ---------------------------------------------------------------------------
// K1: input_proj + lb store + lgce_pre (+pooled partials) + qkv + gate.
//
// R6: back to R1's proven compute structure (single staging burst,
// per-thread float4 VMEM weights, fma4 -- 385 us known-good). History:
//   R2 split-staging: 410 us (serialized loads).  R4 SGPR-broadcast wide
//   accs: 522 us (VGPR spill at 52).  R5 SGPR chunked: 734 us (scalar-load
//   latency-bound at 2 waves/SIMD).
// The ONLY change vs R1: in-place LDS reuse validated in R3 (proj output
// overwrites the x staging buffer after a barrier; lb stored straight from
// accumulator registers) with launch_bounds(256,2) -- R3's failure was its
// (256,4) bound (VGPR 64 -> 4 GB scratch), not the structure. LDS 64->40 KB
// gives 4 blocks/CU = 16 waves/CU with the identical load pattern: the
// clean occupancy experiment R2 confounded.
// ---------------------------------------------------------------------------
__global__ __launch_bounds__(256,2) void k1_proj(
    const float* __restrict__ x,   const float* __restrict__ Wp,
    const float* __restrict__ Wpre,const float* __restrict__ bpre,
    const float* __restrict__ Wqkv,
    const float* __restrict__ Wg1, const float* __restrict__ bg1,
    const float* __restrict__ wg2, const float* __restrict__ bg2,
    float* __restrict__ lb, float* __restrict__ pre, float* __restrict__ qkv,
    float* __restrict__ pooled_part, float* __restrict__ gate_part)
{
    __shared__ float st[128*64];          // 32 KB: x staging, then proj output
    __shared__ float ht[32*64];           // 8 KB: gate hidden
    float4* st4 = (float4*)st;

    const int t    = threadIdx.x;
    const int blk  = blockIdx.x;
    const int b    = blk >> 10;           // 1024 blocks per batch
    const int p0   = (blk & 1023) << 6;   // 64 px / block
    const int pg   = t & 15;              // pixel group (4 px)
    const int og   = t >> 4;              // output group
    const int slot = blk & 63;

    const float4* x4 = (const float4*)x;

    // ---- stage all of x (one burst: full memory-level parallelism)
    #pragma unroll
    for (int i = 0; i < 8; ++i) {
        int idx = t + 256*i;
        int c = idx >> 4, q = idx & 15;
        st4[c*16 + q] = x4[(size_t)(b*128 + c)*16384 + (p0>>2) + q];
    }
    __syncthreads();

    // ---- proj into registers (reads only), then overwrite st in place
    {
        const int o0 = og*8;
        float acc[8][4];
        #pragma unroll
        for (int j=0;j<8;++j){acc[j][0]=0.f;acc[j][1]=0.f;acc[j][2]=0.f;acc[j][3]=0.f;}
        const float4* W4 = (const float4*)Wp;
        for (int c = 0; c < 128; c += 4) {
            float4 x0 = st4[(c+0)*16+pg];
            float4 x1 = st4[(c+1)*16+pg];
            float4 x2 = st4[(c+2)*16+pg];
            float4 x3 = st4[(c+3)*16+pg];
            #pragma unroll
            for (int j=0;j<8;++j)
                fma4(acc[j], W4[(o0+j)*32 + (c>>2)], x0,x1,x2,x3);
        }
        __syncthreads();   // every thread done READING x before any overwrite

        #pragma unroll
        for (int j=0;j<8;++j)
            st4[(o0+j)*16+pg] = make_float4(acc[j][0],acc[j][1],acc[j][2],acc[j][3]);

        // lb = proj channels 0..63, straight from registers
        if (og < 8) {
            float4* lb4 = (float4*)lb;
            #pragma unroll
            for (int j=0;j<8;++j)
                lb4[(size_t)(b*64 + o0+j)*16384 + (p0>>2) + pg] =
                    make_float4(acc[j][0],acc[j][1],acc[j][2],acc[j][3]);
        }
    }
    __syncthreads();       // proj output ready

    // ---- pre conv (64x64) + pooled partial sums
    {
        const int o0 = og*4;
        float acc[4][4];
        #pragma unroll
        for (int j=0;j<4;++j){acc[j][0]=0.f;acc[j][1]=0.f;acc[j][2]=0.f;acc[j][3]=0.f;}
        const float4* W4 = (const float4*)Wpre;
        for (int c = 0; c < 64; c += 4) {
            float4 x0 = st4[(c+0)*16+pg];
            float4 x1 = st4[(c+1)*16+pg];
            float4 x2 = st4[(c+2)*16+pg];
            float4 x3 = st4[(c+3)*16+pg];
            #pragma unroll
            for (int j=0;j<4;++j)
                fma4(acc[j], W4[(o0+j)*16 + (c>>2)], x0,x1,x2,x3);
        }
        float4* pre4 = (float4*)pre;
        #pragma unroll
        for (int j=0;j<4;++j){
            float bs = bpre[o0+j];
            float4 vv = make_float4(acc[j][0]+bs, acc[j][1]+bs, acc[j][2]+bs, acc[j][3]+bs);
            pre4[(size_t)(b*64 + o0+j)*16384 + (p0>>2) + pg] = vv;
            float s = vv.x+vv.y+vv.z+vv.w;
            s += __shfl_xor(s,1); s += __shfl_xor(s,2);
            s += __shfl_xor(s,4); s += __shfl_xor(s,8);
            if (pg == 0) atomicAdd(&pooled_part[slot*256 + b*64 + o0 + j], s);
        }
    }

    // ---- qkv conv (192x64)
    {
        const int o0 = og*12;
        float acc[12][4];
        #pragma unroll
        for (int j=0;j<12;++j){acc[j][0]=0.f;acc[j][1]=0.f;acc[j][2]=0.f;acc[j][3]=0.f;}
        const float4* W4 = (const float4*)Wqkv;
        for (int c = 0; c < 64; c += 4) {
            float4 x0 = st4[(64+c+0)*16+pg];
            float4 x1 = st4[(64+c+1)*16+pg];
            float4 x2 = st4[(64+c+2)*16+pg];
            float4 x3 = st4[(64+c+3)*16+pg];
            #pragma unroll
            for (int j=0;j<12;++j)
                fma4(acc[j], W4[(o0+j)*16 + (c>>2)], x0,x1,x2,x3);
        }
        float4* qkv4 = (float4*)qkv;
        #pragma unroll
        for (int j=0;j<12;++j)
            qkv4[(size_t)(b*192 + o0+j)*16384 + (p0>>2) + pg] =
                make_float4(acc[j][0],acc[j][1],acc[j][2],acc[j][3]);
    }

    // ---- gate hidden (32x64) -> ht
    {
        const int o0 = og*2;
        float acc[2][4];
        #pragma unroll
        for (int j=0;j<2;++j){acc[j][0]=0.f;acc[j][1]=0.f;acc[j][2]=0.f;acc[j][3]=0.f;}
        const float4* W4 = (const float4*)Wg1;
        for (int c = 0; c < 64; c += 4) {
            float4 x0 = st4[(64+c+0)*16+pg];
            float4 x1 = st4[(64+c+1)*16+pg];
            float4 x2 = st4[(64+c+2)*16+pg];
            float4 x3 = st4[(64+c+3)*16+pg];
            #pragma unroll
            for (int j=0;j<2;++j)
                fma4(acc[j], W4[(o0+j)*16 + (c>>2)], x0,x1,x2,x3);
        }
        #pragma unroll
        for (int j=0;j<2;++j){
            float bs = bg1[o0+j];
            #pragma unroll
            for (int k=0;k<4;++k)
                ht[(o0+j)*64 + pg*4 + k] = fmaxf(acc[j][k]+bs, 0.0f);
        }
    }
    __syncthreads();

    // ---- gate scalar
    if (t < 64) {
        float g = bg2[0];
        #pragma unroll
        for (int c = 0; c < 32; ++c) g += wg2[c]*ht[c*64 + t];
        g = sgm(g);
        g += __shfl_xor(g,1);  g += __shfl_xor(g,2);  g += __shfl_xor(g,4);
        g += __shfl_xor(g,8);  g += __shfl_xor(g,16); g += __shfl_xor(g,32);
        if (t == 0) atomicAdd(&gate_part[slot], g);
    }
}

// ---------------------------------------------------------------------------
// K2: pooled -> cw, gate mean -> kdyn. single block.
// ---------------------------------------------------------------------------
__global__ void k2_small(const float* __restrict__ pooled_part,
                         const float* __restrict__ gate_part,
                         const float* __restrict__ w1, const float* __restrict__ b1,
                         const float* __restrict__ w2, const float* __restrict__ b2,
                         float* __restrict__ cw, float* __restrict__ kdyn)
{
    __shared__ float pl[256];
    const int t = threadIdx.x;
    float s = 0.f;
    for (int sl = 0; sl < 64; ++sl) s += pooled_part[sl*256 + t];
    pl[t] = s * (1.0f/65536.0f);
    __syncthreads();
    const int b = t >> 6, g = (t >> 3) & 7, c = t & 7;
    float h0 = b1[g*2+0], h1 = b1[g*2+1];
    #pragma unroll
    for (int cc = 0; cc < 8; ++cc) {
        float p = pl[b*64 + g*8 + cc];
        h0 += p*w1[g*16 + 0*8 + cc];
        h1 += p*w1[g*16 + 1*8 + cc];
    }
    h0 = fmaxf(h0, 0.f); h1 = fmaxf(h1, 0.f);
    cw[t] = sgm(h0*w2[g*16 + c*2 + 0] + h1*w2[g*16 + c*2 + 1] + b2[g*8+c]);
    if (t == 0) {
        float gs = 0.f;
        for (int sl = 0; sl < 64; ++sl) gs += gate_part[sl];
        float kd = floorf(8.0f * (gs * (1.0f/262144.0f)));
        *kdyn = fminf(fmaxf(kd, 1.0f), 8.0f);
    }
}

// ---------------------------------------------------------------------------
// K3: resp partial sums for thr.
// ---------------------------------------------------------------------------
__global__ __launch_bounds__(256) void k3_thr(
    const float* __restrict__ pre, const float* __restrict__ cw,
    const float* __restrict__ sw,  const float* __restrict__ sb,
    float* __restrict__ thr_sum)
{
    __shared__ float part[4][8];
    const int t = threadIdx.x;
    const int b = blockIdx.x >> 8;
    const int p = ((blockIdx.x & 255) << 8) + t;
    float rs[8];
    #pragma unroll
    for (int g = 0; g < 8; ++g) {
        float xc[8];
        float spa = sb[g];
        #pragma unroll
        for (int c = 0; c < 8; ++c) {
            float xv = pre[(size_t)(b*64 + g*8 + c)*HWN + p];
            xc[c] = xv * cw[b*64 + g*8 + c];
            spa += xc[c]*sw[g*8 + c];
        }
        float sp = sgm(spa);
        float s = 0.f;
        #pragma unroll
        for (int c = 0; c < 8; ++c) s += sgm(xc[c]*sp);
        rs[g] = s;
    }
    const int lane = t & 63, wv = t >> 6;
    #pragma unroll
    for (int g = 0; g < 8; ++g) {
        float val = rs[g];
        val += __shfl_xor(val,1);  val += __shfl_xor(val,2);  val += __shfl_xor(val,4);
        val += __shfl_xor(val,8);  val += __shfl_xor(val,16); val += __shfl_xor(val,32);
        if (lane == 0) part[wv][g] = val;
    }
    __syncthreads();
    if (t < 8)
        atomicAdd(&thr_sum[b*8 + t], part[0][t]+part[1][t]+part[2][t]+part[3][t]);
}

// ---------------------------------------------------------------------------
// K4: depthwise 3x3; block = (b, h, 8-row band of 256 cols).
// In-loop wave-reduced Gram/norm accumulation (no S[64] array -> no spill),
// double-buffered LDS, launch_bounds(256,3). See R3 notes.
// ---------------------------------------------------------------------------
#define K4_ROWSTRIDE 264            // 4 pad | 256 data | 4 pad (floats)
#define K4_BUF (10*K4_ROWSTRIDE)    // 10 halo rows

__global__ __launch_bounds__(256,3) void k4_dw(
    const float* __restrict__ qkv, const float* __restrict__ dww,
    float* __restrict__ v, float* __restrict__ Sg, float* __restrict__ sumsq)
{
    __shared__ float sh[2*K4_BUF];  // 21120 B

    const int t    = threadIdx.x;
    const int b    = blockIdx.x >> 8;         // 256 blocks / batch
    const int h    = (blockIdx.x >> 5) & 7;
    const int band = blockIdx.x & 31;
    const int r0   = band * 8;
    const int lr   = t >> 5;                  // output row 0..7
    const int c0   = (t & 31) * 4;            // group0 cols c0..c0+3; group1 +128
    const int lane = t & 63;

    // edge columns (global col -1 and 256) are always zero; init once per buffer
    if (t < 40) {
        int bufi = t / 20, r = (t % 20) >> 1, side = t & 1;
        sh[bufi*K4_BUF + r*K4_ROWSTRIDE + (side ? 260 : 3)] = 0.0f;
    }

    float4 reg[3];

    auto issue_loads = [&](int ch) {
        const float4* base = (const float4*)(qkv + (size_t)(b*192 + ch)*HWN);
        #pragma unroll
        for (int j = 0; j < 3; ++j) {
            int i = t + 256*j;
            float4 val = make_float4(0.f,0.f,0.f,0.f);
            if (i < 640) {
                int row = i >> 6, col4 = i & 63;
                int gy = r0 - 1 + row;
                if (gy >= 0 && gy < 256) val = base[gy*64 + col4];
            }
            reg[j] = val;
        }
    };

    auto write_lds = [&](float* buf) {
        #pragma unroll
        for (int j = 0; j < 3; ++j) {
            int i = t + 256*j;
            if (i < 640) {
                int row = i >> 6, col4 = i & 63;
                *(float4*)&buf[row*K4_ROWSTRIDE + 4 + col4*4] = reg[j];
            }
        }
    };

    auto conv8 = [&](const float* buf, const float* __restrict__ w9, float out[8]) {
        #pragma unroll
        for (int g = 0; g < 2; ++g) {
            const int cc = c0 + g*128;
            float a0=0.f, a1=0.f, a2=0.f, a3=0.f;
            #pragma unroll
            for (int rr = 0; rr < 3; ++rr) {
                const float* row = &buf[(lr+rr)*K4_ROWSTRIDE + 4 + cc];
                float4 m = *(const float4*)row;
                float l = row[-1], r = row[4];
                float w0 = w9[rr*3+0], w1 = w9[rr*3+1], w2 = w9[rr*3+2];
                a0 = fmaf(w0,l,   fmaf(w1,m.x, fmaf(w2,m.y, a0)));
                a1 = fmaf(w0,m.x, fmaf(w1,m.y, fmaf(w2,m.z, a1)));
                a2 = fmaf(w0,m.y, fmaf(w1,m.z, fmaf(w2,m.w, a2)));
                a3 = fmaf(w0,m.z, fmaf(w1,m.w, fmaf(w2,r,   a3)));
            }
            out[g*4+0]=a0; out[g*4+1]=a1; out[g*4+2]=a2; out[g*4+3]=a3;
        }
    };

    auto wsum = [&](float val) {
        val += __shfl_xor(val,1);  val += __shfl_xor(val,2);  val += __shfl_xor(val,4);
        val += __shfl_xor(val,8);  val += __shfl_xor(val,16); val += __shfl_xor(val,32);
        return val;
    };

    float dq[8][8];

    float* sq_q = &sumsq[b*128 + h*8];
    float* sq_k = &sumsq[b*128 + 64 + h*8];
    float* Sgb  = &Sg[(size_t)(b*8+h)*64];

    issue_loads(h*8 + 0);   // first q channel

    // ---- Q channels: conv + immediate ||q||^2 partial
    #pragma unroll
    for (int ch = 0; ch < 8; ++ch) {
        float* buf = sh + (ch & 1)*K4_BUF;
        write_lds(buf);
        issue_loads(ch < 7 ? (h*8 + ch + 1) : (64 + h*8));
        __syncthreads();
        conv8(buf, dww + (h*8 + ch)*9, dq[ch]);
        float ss = 0.f;
        #pragma unroll
        for (int p = 0; p < 8; ++p) ss = fmaf(dq[ch][p], dq[ch][p], ss);
        ss = wsum(ss);
        if (lane == 0) atomicAdd(&sq_q[ch], ss);
    }

    // ---- K channels: conv + Gram row + ||k||^2, all reduced in-loop
    #pragma unroll
    for (int ch = 0; ch < 8; ++ch) {
        float* buf = sh + (ch & 1)*K4_BUF;
        write_lds(buf);
        issue_loads(ch < 7 ? (64 + h*8 + ch + 1) : (128 + h*8));
        __syncthreads();
        float dk[8];
        conv8(buf, dww + (64 + h*8 + ch)*9, dk);
        float ss = 0.f;
        #pragma unroll
        for (int p = 0; p < 8; ++p) ss = fmaf(dk[p], dk[p], ss);
        ss = wsum(ss);
        if (lane == 0) atomicAdd(&sq_k[ch], ss);
        #pragma unroll
        for (int c = 0; c < 8; ++c) {
            float acc = 0.f;
            #pragma unroll
            for (int p = 0; p < 8; ++p) acc = fmaf(dq[c][p], dk[p], acc);
            acc = wsum(acc);
            if (lane == 0) atomicAdd(&Sgb[c*8 + ch], acc);
        }
    }

    // ---- V channels (compute + store only)
    #pragma unroll
    for (int ch = 0; ch < 8; ++ch) {
        float* buf = sh + (ch & 1)*K4_BUF;
        write_lds(buf);
        if (ch < 7) issue_loads(128 + h*8 + ch + 1);
        __syncthreads();
        float dv[8];
        conv8(buf, dww + (128 + h*8 + ch)*9, dv);
        float* vb = v + (size_t)(b*64 + h*8 + ch)*HWN + (r0 + lr)*256;
        *(float4*)&vb[c0]       = make_float4(dv[0],dv[1],dv[2],dv[3]);
        *(float4*)&vb[c0 + 128] = make_float4(dv[4],dv[5],dv[6],dv[7]);
    }
}

// ---------------------------------------------------------------------------
// K6: finalize attention weights and thr. single block.
// ---------------------------------------------------------------------------
__global__ void k6_attn(const float* __restrict__ Sg, const float* __restrict__ sumsq,
                        const float* __restrict__ temp, const float* __restrict__ kdynp,
                        const float* __restrict__ thr_sum, const float* __restrict__ scales,
                        float* __restrict__ A, float* __restrict__ thr)
{
    const int t = threadIdx.x;
    if (t < 32) thr[t] = thr_sum[t] * (1.0f/(8.0f*65536.0f));
    const int b = t >> 6, h = (t >> 3) & 7, c = t & 7;
    const float kd = *kdynp;
    const float ssum = scales[0]+scales[1]+scales[2]+scales[3];
    const float nq = fmaxf(sqrtf(sumsq[b*128 + h*8 + c]), 1e-12f);
    const float tv = temp[h];
    const float* Srow = Sg + (size_t)(b*8+h)*64 + c*8;
    float a[8];
    #pragma unroll
    for (int d = 0; d < 8; ++d) {
        float nk = fmaxf(sqrtf(sumsq[b*128 + 64 + h*8 + d]), 1e-12f);
        a[d] = Srow[d] / (nq*nk) * tv;
    }
    bool keep[8];
    #pragma unroll
    for (int d = 0; d < 8; ++d) {
        int r = 0;
        #pragma unroll
        for (int e = 0; e < 8; ++e)
            r += (a[e] > a[d]) || (a[e] == a[d] && e < d);
        keep[d] = ((float)r < kd);
    }
    float m = -INFINITY;
    #pragma unroll
    for (int d = 0; d < 8; ++d) if (keep[d]) m = fmaxf(m, a[d]);
    float ex[8]; float sum = 0.f;
    #pragma unroll
    for (int d = 0; d < 8; ++d) { ex[d] = keep[d] ? expf(a[d]-m) : 0.f; sum += ex[d]; }
    const float inv = ssum / sum;
    #pragma unroll
    for (int d = 0; d < 8; ++d)
        A[(size_t)(b*8+h)*64 + c*8 + d] = ex[d]*inv;
}

// ---------------------------------------------------------------------------
// K7: mask path + post conv + residual + attn@v + proj_out, fused epilogue.
// R1 ft-based version (known-good); (256,2).
// ---------------------------------------------------------------------------
__global__ __launch_bounds__(256,2) void k7_final(
    const float* __restrict__ pre, const float* __restrict__ lb, const float* __restrict__ v,
    const float* __restrict__ cw,  const float* __restrict__ thr,
    const float* __restrict__ sw,  const float* __restrict__ sb,
    const float* __restrict__ A,
    const float* __restrict__ Wpost, const float* __restrict__ bpost,
    const float* __restrict__ Wout,  float* __restrict__ out)
{
    __shared__ float pr[64*64];
    __shared__ float vt[64*64];
    __shared__ float ft[128*64];
    float4* pr4 = (float4*)pr;
    float4* vt4 = (float4*)vt;
    float4* ft4 = (float4*)ft;

    const int t   = threadIdx.x;
    const int blk = blockIdx.x;
    const int b   = blk >> 10;
    const int p0  = (blk & 1023) << 6;
    const int pg  = t & 15;
    const int og  = t >> 4;

    const float4* pre4g = (const float4*)pre;
    const float4* v4g   = (const float4*)v;
    #pragma unroll
    for (int i = 0; i < 4; ++i) {
        int idx = t + 256*i;
        int c = idx >> 4, q = idx & 15;
        size_t gi = (size_t)(b*64 + c)*16384 + (p0>>2) + q;
        pr4[c*16+q] = pre4g[gi];
        vt4[c*16+q] = v4g[gi];
    }
    __syncthreads();

    #pragma unroll
    for (int s = 0; s < 2; ++s) {
        int task = t + 256*s;
        int g = task >> 6, px = task & 63;
        float xc[8], xv[8];
        float spa = sb[g];
        #pragma unroll
        for (int c = 0; c < 8; ++c) {
            xv[c] = pr[(g*8+c)*64 + px];
            xc[c] = xv[c]*cw[b*64 + g*8 + c];
            spa += xc[c]*sw[g*8 + c];
        }
        float sp = sgm(spa);
        float th = thr[b*8 + g];
        #pragma unroll
        for (int c = 0; c < 8; ++c) {
            float resp = sgm(xc[c]*sp);
            float mask = resp > th ? 1.0f : resp;
            pr[(g*8+c)*64 + px] = xv[c]*mask;
        }
    }
    __syncthreads();

    {
        const int o0 = og*4;
        float acc[4][4];
        #pragma unroll
        for (int j=0;j<4;++j){acc[j][0]=0.f;acc[j][1]=0.f;acc[j][2]=0.f;acc[j][3]=0.f;}
        const float4* W4 = (const float4*)Wpost;
        for (int c = 0; c < 64; c += 4) {
            float4 x0 = pr4[(c+0)*16+pg];
            float4 x1 = pr4[(c+1)*16+pg];
            float4 x2 = pr4[(c+2)*16+pg];
            float4 x3 = pr4[(c+3)*16+pg];
            #pragma unroll
            for (int j=0;j<4;++j)
                fma4(acc[j], W4[(o0+j)*16 + (c>>2)], x0,x1,x2,x3);
        }
        const float4* lb4 = (const float4*)lb;
        #pragma unroll
        for (int j=0;j<4;++j){
            float bs = bpost[o0+j];
            float4 lv = lb4[(size_t)(b*64 + o0+j)*16384 + (p0>>2) + pg];
            ft4[(64+o0+j)*16 + pg] = make_float4(acc[j][0]+bs+lv.x, acc[j][1]+bs+lv.y,
                                                 acc[j][2]+bs+lv.z, acc[j][3]+bs+lv.w);
        }
    }

    {
        const int ch0 = og*4;
        #pragma unroll
        for (int j = 0; j < 4; ++j) {
            int ch = ch0 + j;
            int hh = ch >> 3, c = ch & 7;
            const float* Ar = A + (size_t)(b*8+hh)*64 + c*8;
            float4 acc = make_float4(0.f,0.f,0.f,0.f);
            #pragma unroll
            for (int d = 0; d < 8; ++d) {
                float av = Ar[d];
                float4 vv = vt4[(hh*8+d)*16 + pg];
                acc.x += av*vv.x; acc.y += av*vv.y; acc.z += av*vv.z; acc.w += av*vv.w;
            }
            ft4[ch*16 + pg] = acc;
        }
    }
    __syncthreads();

    {
        const int o0 = og*8;
        float acc[8][4];
        #pragma unroll
        for (int j=0;j<8;++j){acc[j][0]=0.f;acc[j][1]=0.f;acc[j][2]=0.f;acc[j][3]=0.f;}
        const float4* W4 = (const float4*)Wout;
        for (int c = 0; c < 128; c += 4) {
            float4 x0 = ft4[(c+0)*16+pg];
            float4 x1 = ft4[(c+1)*16+pg];
            float4 x2 = ft4[(c+2)*16+pg];
            float4 x3 = ft4[(c+3)*16+pg];
            #pragma unroll
            for (int j=0;j<8;++j)
                fma4(acc[j], W4[(o0+j)*32 + (c>>2)], x0,x1,x2,x3);
        }
        float4* out4 = (float4*)out;
        #pragma unroll
        for (int j=0;j<8;++j)
            out4[(size_t)(b*128 + o0+j)*16384 + (p0>>2) + pg] =
                make_float4(acc[j][0],acc[j][1],acc[j][2],acc[j][3]);
    }
}

// ---------------------------------------------------------------------------
extern "C" void kernel_launch(void* const* d_in, const int* in_sizes, int n_in,
                              void* d_out, int out_size, void* d_ws, size_t ws_size,
                              hipStream_t stream)
{
    const float* x     = (const float*)d_in[0];
    const float* Wp    = (const float*)d_in[1];
    const float* Wpre  = (const float*)d_in[2];
    const float* bpre  = (const float*)d_in[3];
    const float* w1    = (const float*)d_in[4];
    const float* b1    = (const float*)d_in[5];
    const float* w2    = (const float*)d_in[6];
    const float* b2    = (const float*)d_in[7];
    const float* sw    = (const float*)d_in[8];
    const float* sb    = (const float*)d_in[9];
    const float* Wpost = (const float*)d_in[10];
    const float* bpost = (const float*)d_in[11];
    const float* Wqkv  = (const float*)d_in[12];
    const float* dww   = (const float*)d_in[13];
    const float* Wg1   = (const float*)d_in[14];
    const float* bg1   = (const float*)d_in[15];
    const float* wg2   = (const float*)d_in[16];
    const float* bg2   = (const float*)d_in[17];
    const float* temp  = (const float*)d_in[18];
    const float* scales= (const float*)d_in[19];
    const float* Wout  = (const float*)d_in[20];
    float* out = (float*)d_out;

    float* ws = (float*)d_ws;
    float* pooled_part = ws;                 // 16384
    float* gate_part   = ws + 16384;         // 64
    float* thr_sum     = ws + 16448;         // 32
    float* sumsq       = ws + 16480;         // 512
    float* Sg          = ws + 16992;         // 2048
    float* cw          = ws + 19040;         // 256
    float* kdyn        = ws + 19296;         // 1
    float* thr         = ws + 19328;         // 32
    float* A           = ws + 19360;         // 2048

    float* lb  = ws + 32768;
    float* pre = lb  + 16777216;
    float* qkv = pre + 16777216;
    float* v   = qkv + 50331648;

    hipMemsetAsync(ws, 0, (size_t)19040*sizeof(float), stream);

    k1_proj <<<4096, 256, 0, stream>>>(x, Wp, Wpre, bpre, Wqkv, Wg1, bg1, wg2, bg2,
                                       lb, pre, qkv, pooled_part, gate_part);
    k2_small<<<1,    256, 0, stream>>>(pooled_part, gate_part, w1, b1, w2, b2, cw, kdyn);
    k3_thr  <<<1024, 256, 0, stream>>>(pre, cw, sw, sb, thr_sum);
    k4_dw   <<<1024, 256, 0, stream>>>(qkv, dww, v, Sg, sumsq);
    k6_attn <<<1,    256, 0, stream>>>(Sg, sumsq, temp, kdyn, thr_sum, scales, A, thr);
    k7_final<<<4096, 256, 0, stream>>>(pre, lb, v, cw, thr, sw, sb, A,
                                       Wpost, bpost, Wout, out);
}

// Round 7
// 850.149 us; speedup vs baseline: 1.4587x; 1.0299x over previous
//
#include <hip/hip_runtime.h>
#include <math.h>

#define HWN 65536

__device__ __forceinline__ float sgm(float x){ return 1.0f/(1.0f+expf(-x)); }

__device__ __forceinline__ void fma4(float acc[4], const float4 w,
                                     const float4 x0, const float4 x1,
                                     const float4 x2, const float4 x3){
    acc[0] += w.x*x0.x + w.y*x1.x + w.z*x2.x + w.w*x3.x;
    acc[1] += w.x*x0.y + w.y*x1.y + w.z*x2.y + w.w*x3.y;
    acc[2] += w.x*x0.z + w.y*x1.z + w.z*x2.z + w.w*x3.z;
    acc[3] += w.x*x0.w + w.y*x1.w + w.z*x2.w + w.w*x3.w;
}

// ---------------------------------------------------------------------------
// K1: input_proj + lb store + lgce_pre (+pooled partials) + qkv + gate.
//
// R7 (8 px/thread): occupancy fully falsified as k1's lever (21/33/32% occ ->
// 385/410/378 us). k1 is ISSUE-bound: ~44% of VALU issues are non-FMA
// (weight-load addressing, float4 moves). Fix = raise arithmetic intensity:
// 128 px/block, 8 px/thread -> each weight register feeds 8 FMAs (was 4),
// weight VMEM + addressing per pixel halved, FMA:load 10.7 -> ~16-21.
// Thread's px = {pg*4..+3} U {64+pg*4..+3} so every LDS b128 read keeps the
// 16-B lane stride (2-way bank alias = free; 32-B stride would be 4-way).
// acc capped at 64 regs/phase (proj 8x8, qkv 2 chunks of 6x8) -- R0 spilled
// at ~170 live, R1 ran 100 clean. Single 64 KB LDS buffer: x staging ->
// in-place proj output -> first 16 KB reused as ht behind a barrier.
// 2 blocks/CU; launch_bounds(256,2) (NEVER raise arg2 -- R3 disaster).
// ---------------------------------------------------------------------------
__global__ __launch_bounds__(256,2) void k1_proj(
    const float* __restrict__ x,   const float* __restrict__ Wp,
    const float* __restrict__ Wpre,const float* __restrict__ bpre,
    const float* __restrict__ Wqkv,
    const float* __restrict__ Wg1, const float* __restrict__ bg1,
    const float* __restrict__ wg2, const float* __restrict__ bg2,
    float* __restrict__ lb, float* __restrict__ pre, float* __restrict__ qkv,
    float* __restrict__ pooled_part, float* __restrict__ gate_part)
{
    __shared__ float st[128*128];         // 64 KB: x staging -> proj output -> ht alias
    float4* st4 = (float4*)st;
    float*  ht  = st;                     // 32x128 floats = 16 KB, used after barrier

    const int t    = threadIdx.x;
    const int blk  = blockIdx.x;
    const int b    = blk >> 9;            // 512 blocks per batch
    const int p0   = (blk & 511) << 7;    // 128 px / block
    const int pg   = t & 15;              // pixel group: px pg*4..+3 and 64+pg*4..+3
    const int og   = t >> 4;              // output group
    const int slot = blk & 63;

    const float4* x4 = (const float4*)x;

    // ---- stage all of x (one burst)
    #pragma unroll
    for (int i = 0; i < 16; ++i) {
        int idx = t + 256*i;
        int c = idx >> 5, q = idx & 31;
        st4[c*32 + q] = x4[(size_t)(b*128 + c)*16384 + (p0>>2) + q];
    }
    __syncthreads();

    // ---- proj (128x128): og owns outs og*8..+7, 8 px each -> acc[8][8]
    {
        const int o0 = og*8;
        float acc[8][8];
        #pragma unroll
        for (int j=0;j<8;++j)
            #pragma unroll
            for (int k=0;k<8;++k) acc[j][k]=0.f;
        const float4* W4 = (const float4*)Wp;
        for (int c = 0; c < 128; c += 4) {
            float4 xa0 = st4[(c+0)*32 + pg],      xb0 = st4[(c+0)*32 + 16 + pg];
            float4 xa1 = st4[(c+1)*32 + pg],      xb1 = st4[(c+1)*32 + 16 + pg];
            float4 xa2 = st4[(c+2)*32 + pg],      xb2 = st4[(c+2)*32 + 16 + pg];
            float4 xa3 = st4[(c+3)*32 + pg],      xb3 = st4[(c+3)*32 + 16 + pg];
            #pragma unroll
            for (int j = 0; j < 8; ++j) {
                float4 w = W4[(o0+j)*32 + (c>>2)];
                fma4(&acc[j][0], w, xa0,xa1,xa2,xa3);
                fma4(&acc[j][4], w, xb0,xb1,xb2,xb3);
            }
        }
        __syncthreads();   // every thread done READING x before any overwrite

        #pragma unroll
        for (int j = 0; j < 8; ++j) {
            st4[(o0+j)*32 + pg]      = make_float4(acc[j][0],acc[j][1],acc[j][2],acc[j][3]);
            st4[(o0+j)*32 + 16 + pg] = make_float4(acc[j][4],acc[j][5],acc[j][6],acc[j][7]);
        }
        if (og < 8) {      // lb = proj channels 0..63, straight from registers
            float4* lb4 = (float4*)lb;
            #pragma unroll
            for (int j = 0; j < 8; ++j) {
                lb4[(size_t)(b*64 + o0+j)*16384 + (p0>>2) + pg] =
                    make_float4(acc[j][0],acc[j][1],acc[j][2],acc[j][3]);
                lb4[(size_t)(b*64 + o0+j)*16384 + (p0>>2) + 16 + pg] =
                    make_float4(acc[j][4],acc[j][5],acc[j][6],acc[j][7]);
            }
        }
    }
    __syncthreads();       // proj output ready

    // ---- pre conv (64x64): og owns 4 outs -> acc[4][8]; + pooled partials
    {
        const int o0 = og*4;
        float acc[4][8];
        #pragma unroll
        for (int j=0;j<4;++j)
            #pragma unroll
            for (int k=0;k<8;++k) acc[j][k]=0.f;
        const float4* W4 = (const float4*)Wpre;
        for (int c = 0; c < 64; c += 4) {
            float4 xa0 = st4[(c+0)*32 + pg],      xb0 = st4[(c+0)*32 + 16 + pg];
            float4 xa1 = st4[(c+1)*32 + pg],      xb1 = st4[(c+1)*32 + 16 + pg];
            float4 xa2 = st4[(c+2)*32 + pg],      xb2 = st4[(c+2)*32 + 16 + pg];
            float4 xa3 = st4[(c+3)*32 + pg],      xb3 = st4[(c+3)*32 + 16 + pg];
            #pragma unroll
            for (int j = 0; j < 4; ++j) {
                float4 w = W4[(o0+j)*16 + (c>>2)];
                fma4(&acc[j][0], w, xa0,xa1,xa2,xa3);
                fma4(&acc[j][4], w, xb0,xb1,xb2,xb3);
            }
        }
        float4* pre4 = (float4*)pre;
        #pragma unroll
        for (int j = 0; j < 4; ++j) {
            float bs = bpre[o0+j];
            float4 v0 = make_float4(acc[j][0]+bs, acc[j][1]+bs, acc[j][2]+bs, acc[j][3]+bs);
            float4 v1 = make_float4(acc[j][4]+bs, acc[j][5]+bs, acc[j][6]+bs, acc[j][7]+bs);
            pre4[(size_t)(b*64 + o0+j)*16384 + (p0>>2) + pg]      = v0;
            pre4[(size_t)(b*64 + o0+j)*16384 + (p0>>2) + 16 + pg] = v1;
            float s = v0.x+v0.y+v0.z+v0.w + v1.x+v1.y+v1.z+v1.w;
            s += __shfl_xor(s,1); s += __shfl_xor(s,2);
            s += __shfl_xor(s,4); s += __shfl_xor(s,8);
            if (pg == 0) atomicAdd(&pooled_part[slot*256 + b*64 + o0 + j], s);
        }
    }

    // ---- qkv conv (192x64): og owns 12 outs, 2 chunks of 6 -> acc[6][8]
    #pragma unroll
    for (int chk = 0; chk < 2; ++chk) {
        const int o0 = og*12 + chk*6;
        float acc[6][8];
        #pragma unroll
        for (int j=0;j<6;++j)
            #pragma unroll
            for (int k=0;k<8;++k) acc[j][k]=0.f;
        const float4* W4 = (const float4*)Wqkv;
        for (int c = 0; c < 64; c += 4) {
            float4 xa0 = st4[(64+c+0)*32 + pg],   xb0 = st4[(64+c+0)*32 + 16 + pg];
            float4 xa1 = st4[(64+c+1)*32 + pg],   xb1 = st4[(64+c+1)*32 + 16 + pg];
            float4 xa2 = st4[(64+c+2)*32 + pg],   xb2 = st4[(64+c+2)*32 + 16 + pg];
            float4 xa3 = st4[(64+c+3)*32 + pg],   xb3 = st4[(64+c+3)*32 + 16 + pg];
            #pragma unroll
            for (int j = 0; j < 6; ++j) {
                float4 w = W4[(o0+j)*16 + (c>>2)];
                fma4(&acc[j][0], w, xa0,xa1,xa2,xa3);
                fma4(&acc[j][4], w, xb0,xb1,xb2,xb3);
            }
        }
        float4* qkv4 = (float4*)qkv;
        #pragma unroll
        for (int j = 0; j < 6; ++j) {
            qkv4[(size_t)(b*192 + o0+j)*16384 + (p0>>2) + pg] =
                make_float4(acc[j][0],acc[j][1],acc[j][2],acc[j][3]);
            qkv4[(size_t)(b*192 + o0+j)*16384 + (p0>>2) + 16 + pg] =
                make_float4(acc[j][4],acc[j][5],acc[j][6],acc[j][7]);
        }
    }

    // ---- gate hidden (32x64): og owns 2 outs -> acc[2][8], held across barrier
    {
        const int o0 = og*2;
        float acc[2][8];
        #pragma unroll
        for (int j=0;j<2;++j)
            #pragma unroll
            for (int k=0;k<8;++k) acc[j][k]=0.f;
        const float4* W4 = (const float4*)Wg1;
        for (int c = 0; c < 64; c += 4) {
            float4 xa0 = st4[(64+c+0)*32 + pg],   xb0 = st4[(64+c+0)*32 + 16 + pg];
            float4 xa1 = st4[(64+c+1)*32 + pg],   xb1 = st4[(64+c+1)*32 + 16 + pg];
            float4 xa2 = st4[(64+c+2)*32 + pg],   xb2 = st4[(64+c+2)*32 + 16 + pg];
            float4 xa3 = st4[(64+c+3)*32 + pg],   xb3 = st4[(64+c+3)*32 + 16 + pg];
            #pragma unroll
            for (int j = 0; j < 2; ++j) {
                float4 w = W4[(o0+j)*16 + (c>>2)];
                fma4(&acc[j][0], w, xa0,xa1,xa2,xa3);
                fma4(&acc[j][4], w, xb0,xb1,xb2,xb3);
            }
        }
        __syncthreads();   // ALL pt reads complete before ht overwrites st
        #pragma unroll
        for (int j = 0; j < 2; ++j) {
            float bs = bg1[o0+j];
            #pragma unroll
            for (int k = 0; k < 4; ++k) {
                ht[(o0+j)*128 + pg*4 + k]      = fmaxf(acc[j][k]+bs,   0.0f);
                ht[(o0+j)*128 + 64 + pg*4 + k] = fmaxf(acc[j][4+k]+bs, 0.0f);
            }
        }
    }
    __syncthreads();

    // ---- gate scalar: 128 px, 2 waves, wave-reduce + atomic each
    if (t < 128) {
        float g = bg2[0];
        #pragma unroll
        for (int c = 0; c < 32; ++c) g += wg2[c]*ht[c*128 + t];
        g = sgm(g);
        g += __shfl_xor(g,1);  g += __shfl_xor(g,2);  g += __shfl_xor(g,4);
        g += __shfl_xor(g,8);  g += __shfl_xor(g,16); g += __shfl_xor(g,32);
        if ((t & 63) == 0) atomicAdd(&gate_part[slot], g);
    }
}

// ---------------------------------------------------------------------------
// K2: pooled -> cw, gate mean -> kdyn. single block.
// ---------------------------------------------------------------------------
__global__ void k2_small(const float* __restrict__ pooled_part,
                         const float* __restrict__ gate_part,
                         const float* __restrict__ w1, const float* __restrict__ b1,
                         const float* __restrict__ w2, const float* __restrict__ b2,
                         float* __restrict__ cw, float* __restrict__ kdyn)
{
    __shared__ float pl[256];
    const int t = threadIdx.x;
    float s = 0.f;
    for (int sl = 0; sl < 64; ++sl) s += pooled_part[sl*256 + t];
    pl[t] = s * (1.0f/65536.0f);
    __syncthreads();
    const int b = t >> 6, g = (t >> 3) & 7, c = t & 7;
    float h0 = b1[g*2+0], h1 = b1[g*2+1];
    #pragma unroll
    for (int cc = 0; cc < 8; ++cc) {
        float p = pl[b*64 + g*8 + cc];
        h0 += p*w1[g*16 + 0*8 + cc];
        h1 += p*w1[g*16 + 1*8 + cc];
    }
    h0 = fmaxf(h0, 0.f); h1 = fmaxf(h1, 0.f);
    cw[t] = sgm(h0*w2[g*16 + c*2 + 0] + h1*w2[g*16 + c*2 + 1] + b2[g*8+c]);
    if (t == 0) {
        float gs = 0.f;
        for (int sl = 0; sl < 64; ++sl) gs += gate_part[sl];
        float kd = floorf(8.0f * (gs * (1.0f/262144.0f)));
        *kdyn = fminf(fmaxf(kd, 1.0f), 8.0f);
    }
}

// ---------------------------------------------------------------------------
// K3: resp partial sums for thr.
// ---------------------------------------------------------------------------
__global__ __launch_bounds__(256) void k3_thr(
    const float* __restrict__ pre, const float* __restrict__ cw,
    const float* __restrict__ sw,  const float* __restrict__ sb,
    float* __restrict__ thr_sum)
{
    __shared__ float part[4][8];
    const int t = threadIdx.x;
    const int b = blockIdx.x >> 8;
    const int p = ((blockIdx.x & 255) << 8) + t;
    float rs[8];
    #pragma unroll
    for (int g = 0; g < 8; ++g) {
        float xc[8];
        float spa = sb[g];
        #pragma unroll
        for (int c = 0; c < 8; ++c) {
            float xv = pre[(size_t)(b*64 + g*8 + c)*HWN + p];
            xc[c] = xv * cw[b*64 + g*8 + c];
            spa += xc[c]*sw[g*8 + c];
        }
        float sp = sgm(spa);
        float s = 0.f;
        #pragma unroll
        for (int c = 0; c < 8; ++c) s += sgm(xc[c]*sp);
        rs[g] = s;
    }
    const int lane = t & 63, wv = t >> 6;
    #pragma unroll
    for (int g = 0; g < 8; ++g) {
        float val = rs[g];
        val += __shfl_xor(val,1);  val += __shfl_xor(val,2);  val += __shfl_xor(val,4);
        val += __shfl_xor(val,8);  val += __shfl_xor(val,16); val += __shfl_xor(val,32);
        if (lane == 0) part[wv][g] = val;
    }
    __syncthreads();
    if (t < 8)
        atomicAdd(&thr_sum[b*8 + t], part[0][t]+part[1][t]+part[2][t]+part[3][t]);
}

// ---------------------------------------------------------------------------
// K4: depthwise 3x3; block = (b, h, 8-row band of 256 cols).
// In-loop wave-reduced Gram/norm accumulation (no S[64] array -> no spill),
// double-buffered LDS, launch_bounds(256,3). See R3 notes.
// ---------------------------------------------------------------------------
#define K4_ROWSTRIDE 264            // 4 pad | 256 data | 4 pad (floats)
#define K4_BUF (10*K4_ROWSTRIDE)    // 10 halo rows

__global__ __launch_bounds__(256,3) void k4_dw(
    const float* __restrict__ qkv, const float* __restrict__ dww,
    float* __restrict__ v, float* __restrict__ Sg, float* __restrict__ sumsq)
{
    __shared__ float sh[2*K4_BUF];  // 21120 B

    const int t    = threadIdx.x;
    const int b    = blockIdx.x >> 8;         // 256 blocks / batch
    const int h    = (blockIdx.x >> 5) & 7;
    const int band = blockIdx.x & 31;
    const int r0   = band * 8;
    const int lr   = t >> 5;                  // output row 0..7
    const int c0   = (t & 31) * 4;            // group0 cols c0..c0+3; group1 +128
    const int lane = t & 63;

    // edge columns (global col -1 and 256) are always zero; init once per buffer
    if (t < 40) {
        int bufi = t / 20, r = (t % 20) >> 1, side = t & 1;
        sh[bufi*K4_BUF + r*K4_ROWSTRIDE + (side ? 260 : 3)] = 0.0f;
    }

    float4 reg[3];

    auto issue_loads = [&](int ch) {
        const float4* base = (const float4*)(qkv + (size_t)(b*192 + ch)*HWN);
        #pragma unroll
        for (int j = 0; j < 3; ++j) {
            int i = t + 256*j;
            float4 val = make_float4(0.f,0.f,0.f,0.f);
            if (i < 640) {
                int row = i >> 6, col4 = i & 63;
                int gy = r0 - 1 + row;
                if (gy >= 0 && gy < 256) val = base[gy*64 + col4];
            }
            reg[j] = val;
        }
    };

    auto write_lds = [&](float* buf) {
        #pragma unroll
        for (int j = 0; j < 3; ++j) {
            int i = t + 256*j;
            if (i < 640) {
                int row = i >> 6, col4 = i & 63;
                *(float4*)&buf[row*K4_ROWSTRIDE + 4 + col4*4] = reg[j];
            }
        }
    };

    auto conv8 = [&](const float* buf, const float* __restrict__ w9, float out[8]) {
        #pragma unroll
        for (int g = 0; g < 2; ++g) {
            const int cc = c0 + g*128;
            float a0=0.f, a1=0.f, a2=0.f, a3=0.f;
            #pragma unroll
            for (int rr = 0; rr < 3; ++rr) {
                const float* row = &buf[(lr+rr)*K4_ROWSTRIDE + 4 + cc];
                float4 m = *(const float4*)row;
                float l = row[-1], r = row[4];
                float w0 = w9[rr*3+0], w1 = w9[rr*3+1], w2 = w9[rr*3+2];
                a0 = fmaf(w0,l,   fmaf(w1,m.x, fmaf(w2,m.y, a0)));
                a1 = fmaf(w0,m.x, fmaf(w1,m.y, fmaf(w2,m.z, a1)));
                a2 = fmaf(w0,m.y, fmaf(w1,m.z, fmaf(w2,m.w, a2)));
                a3 = fmaf(w0,m.z, fmaf(w1,m.w, fmaf(w2,r,   a3)));
            }
            out[g*4+0]=a0; out[g*4+1]=a1; out[g*4+2]=a2; out[g*4+3]=a3;
        }
    };

    auto wsum = [&](float val) {
        val += __shfl_xor(val,1);  val += __shfl_xor(val,2);  val += __shfl_xor(val,4);
        val += __shfl_xor(val,8);  val += __shfl_xor(val,16); val += __shfl_xor(val,32);
        return val;
    };

    float dq[8][8];

    float* sq_q = &sumsq[b*128 + h*8];
    float* sq_k = &sumsq[b*128 + 64 + h*8];
    float* Sgb  = &Sg[(size_t)(b*8+h)*64];

    issue_loads(h*8 + 0);   // first q channel

    // ---- Q channels: conv + immediate ||q||^2 partial
    #pragma unroll
    for (int ch = 0; ch < 8; ++ch) {
        float* buf = sh + (ch & 1)*K4_BUF;
        write_lds(buf);
        issue_loads(ch < 7 ? (h*8 + ch + 1) : (64 + h*8));
        __syncthreads();
        conv8(buf, dww + (h*8 + ch)*9, dq[ch]);
        float ss = 0.f;
        #pragma unroll
        for (int p = 0; p < 8; ++p) ss = fmaf(dq[ch][p], dq[ch][p], ss);
        ss = wsum(ss);
        if (lane == 0) atomicAdd(&sq_q[ch], ss);
    }

    // ---- K channels: conv + Gram row + ||k||^2, all reduced in-loop
    #pragma unroll
    for (int ch = 0; ch < 8; ++ch) {
        float* buf = sh + (ch & 1)*K4_BUF;
        write_lds(buf);
        issue_loads(ch < 7 ? (64 + h*8 + ch + 1) : (128 + h*8));
        __syncthreads();
        float dk[8];
        conv8(buf, dww + (64 + h*8 + ch)*9, dk);
        float ss = 0.f;
        #pragma unroll
        for (int p = 0; p < 8; ++p) ss = fmaf(dk[p], dk[p], ss);
        ss = wsum(ss);
        if (lane == 0) atomicAdd(&sq_k[ch], ss);
        #pragma unroll
        for (int c = 0; c < 8; ++c) {
            float acc = 0.f;
            #pragma unroll
            for (int p = 0; p < 8; ++p) acc = fmaf(dq[c][p], dk[p], acc);
            acc = wsum(acc);
            if (lane == 0) atomicAdd(&Sgb[c*8 + ch], acc);
        }
    }

    // ---- V channels (compute + store only)
    #pragma unroll
    for (int ch = 0; ch < 8; ++ch) {
        float* buf = sh + (ch & 1)*K4_BUF;
        write_lds(buf);
        if (ch < 7) issue_loads(128 + h*8 + ch + 1);
        __syncthreads();
        float dv[8];
        conv8(buf, dww + (128 + h*8 + ch)*9, dv);
        float* vb = v + (size_t)(b*64 + h*8 + ch)*HWN + (r0 + lr)*256;
        *(float4*)&vb[c0]       = make_float4(dv[0],dv[1],dv[2],dv[3]);
        *(float4*)&vb[c0 + 128] = make_float4(dv[4],dv[5],dv[6],dv[7]);
    }
}

// ---------------------------------------------------------------------------
// K6: finalize attention weights and thr. single block.
// ---------------------------------------------------------------------------
__global__ void k6_attn(const float* __restrict__ Sg, const float* __restrict__ sumsq,
                        const float* __restrict__ temp, const float* __restrict__ kdynp,
                        const float* __restrict__ thr_sum, const float* __restrict__ scales,
                        float* __restrict__ A, float* __restrict__ thr)
{
    const int t = threadIdx.x;
    if (t < 32) thr[t] = thr_sum[t] * (1.0f/(8.0f*65536.0f));
    const int b = t >> 6, h = (t >> 3) & 7, c = t & 7;
    const float kd = *kdynp;
    const float ssum = scales[0]+scales[1]+scales[2]+scales[3];
    const float nq = fmaxf(sqrtf(sumsq[b*128 + h*8 + c]), 1e-12f);
    const float tv = temp[h];
    const float* Srow = Sg + (size_t)(b*8+h)*64 + c*8;
    float a[8];
    #pragma unroll
    for (int d = 0; d < 8; ++d) {
        float nk = fmaxf(sqrtf(sumsq[b*128 + 64 + h*8 + d]), 1e-12f);
        a[d] = Srow[d] / (nq*nk) * tv;
    }
    bool keep[8];
    #pragma unroll
    for (int d = 0; d < 8; ++d) {
        int r = 0;
        #pragma unroll
        for (int e = 0; e < 8; ++e)
            r += (a[e] > a[d]) || (a[e] == a[d] && e < d);
        keep[d] = ((float)r < kd);
    }
    float m = -INFINITY;
    #pragma unroll
    for (int d = 0; d < 8; ++d) if (keep[d]) m = fmaxf(m, a[d]);
    float ex[8]; float sum = 0.f;
    #pragma unroll
    for (int d = 0; d < 8; ++d) { ex[d] = keep[d] ? expf(a[d]-m) : 0.f; sum += ex[d]; }
    const float inv = ssum / sum;
    #pragma unroll
    for (int d = 0; d < 8; ++d)
        A[(size_t)(b*8+h)*64 + c*8 + d] = ex[d]*inv;
}

// ---------------------------------------------------------------------------
// K7: mask path + post conv + residual + attn@v + proj_out, fused epilogue.
// R1 ft-based version (known-good); (256,2).
// ---------------------------------------------------------------------------
__global__ __launch_bounds__(256,2) void k7_final(
    const float* __restrict__ pre, const float* __restrict__ lb, const float* __restrict__ v,
    const float* __restrict__ cw,  const float* __restrict__ thr,
    const float* __restrict__ sw,  const float* __restrict__ sb,
    const float* __restrict__ A,
    const float* __restrict__ Wpost, const float* __restrict__ bpost,
    const float* __restrict__ Wout,  float* __restrict__ out)
{
    __shared__ float pr[64*64];
    __shared__ float vt[64*64];
    __shared__ float ft[128*64];
    float4* pr4 = (float4*)pr;
    float4* vt4 = (float4*)vt;
    float4* ft4 = (float4*)ft;

    const int t   = threadIdx.x;
    const int blk = blockIdx.x;
    const int b   = blk >> 10;
    const int p0  = (blk & 1023) << 6;
    const int pg  = t & 15;
    const int og  = t >> 4;

    const float4* pre4g = (const float4*)pre;
    const float4* v4g   = (const float4*)v;
    #pragma unroll
    for (int i = 0; i < 4; ++i) {
        int idx = t + 256*i;
        int c = idx >> 4, q = idx & 15;
        size_t gi = (size_t)(b*64 + c)*16384 + (p0>>2) + q;
        pr4[c*16+q] = pre4g[gi];
        vt4[c*16+q] = v4g[gi];
    }
    __syncthreads();

    #pragma unroll
    for (int s = 0; s < 2; ++s) {
        int task = t + 256*s;
        int g = task >> 6, px = task & 63;
        float xc[8], xv[8];
        float spa = sb[g];
        #pragma unroll
        for (int c = 0; c < 8; ++c) {
            xv[c] = pr[(g*8+c)*64 + px];
            xc[c] = xv[c]*cw[b*64 + g*8 + c];
            spa += xc[c]*sw[g*8 + c];
        }
        float sp = sgm(spa);
        float th = thr[b*8 + g];
        #pragma unroll
        for (int c = 0; c < 8; ++c) {
            float resp = sgm(xc[c]*sp);
            float mask = resp > th ? 1.0f : resp;
            pr[(g*8+c)*64 + px] = xv[c]*mask;
        }
    }
    __syncthreads();

    {
        const int o0 = og*4;
        float acc[4][4];
        #pragma unroll
        for (int j=0;j<4;++j){acc[j][0]=0.f;acc[j][1]=0.f;acc[j][2]=0.f;acc[j][3]=0.f;}
        const float4* W4 = (const float4*)Wpost;
        for (int c = 0; c < 64; c += 4) {
            float4 x0 = pr4[(c+0)*16+pg];
            float4 x1 = pr4[(c+1)*16+pg];
            float4 x2 = pr4[(c+2)*16+pg];
            float4 x3 = pr4[(c+3)*16+pg];
            #pragma unroll
            for (int j=0;j<4;++j)
                fma4(acc[j], W4[(o0+j)*16 + (c>>2)], x0,x1,x2,x3);
        }
        const float4* lb4 = (const float4*)lb;
        #pragma unroll
        for (int j=0;j<4;++j){
            float bs = bpost[o0+j];
            float4 lv = lb4[(size_t)(b*64 + o0+j)*16384 + (p0>>2) + pg];
            ft4[(64+o0+j)*16 + pg] = make_float4(acc[j][0]+bs+lv.x, acc[j][1]+bs+lv.y,
                                                 acc[j][2]+bs+lv.z, acc[j][3]+bs+lv.w);
        }
    }

    {
        const int ch0 = og*4;
        #pragma unroll
        for (int j = 0; j < 4; ++j) {
            int ch = ch0 + j;
            int hh = ch >> 3, c = ch & 7;
            const float* Ar = A + (size_t)(b*8+hh)*64 + c*8;
            float4 acc = make_float4(0.f,0.f,0.f,0.f);
            #pragma unroll
            for (int d = 0; d < 8; ++d) {
                float av = Ar[d];
                float4 vv = vt4[(hh*8+d)*16 + pg];
                acc.x += av*vv.x; acc.y += av*vv.y; acc.z += av*vv.z; acc.w += av*vv.w;
            }
            ft4[ch*16 + pg] = acc;
        }
    }
    __syncthreads();

    {
        const int o0 = og*8;
        float acc[8][4];
        #pragma unroll
        for (int j=0;j<8;++j){acc[j][0]=0.f;acc[j][1]=0.f;acc[j][2]=0.f;acc[j][3]=0.f;}
        const float4* W4 = (const float4*)Wout;
        for (int c = 0; c < 128; c += 4) {
            float4 x0 = ft4[(c+0)*16+pg];
            float4 x1 = ft4[(c+1)*16+pg];
            float4 x2 = ft4[(c+2)*16+pg];
            float4 x3 = ft4[(c+3)*16+pg];
            #pragma unroll
            for (int j=0;j<8;++j)
                fma4(acc[j], W4[(o0+j)*32 + (c>>2)], x0,x1,x2,x3);
        }
        float4* out4 = (float4*)out;
        #pragma unroll
        for (int j=0;j<8;++j)
            out4[(size_t)(b*128 + o0+j)*16384 + (p0>>2) + pg] =
                make_float4(acc[j][0],acc[j][1],acc[j][2],acc[j][3]);
    }
}

// ---------------------------------------------------------------------------
extern "C" void kernel_launch(void* const* d_in, const int* in_sizes, int n_in,
                              void* d_out, int out_size, void* d_ws, size_t ws_size,
                              hipStream_t stream)
{
    const float* x     = (const float*)d_in[0];
    const float* Wp    = (const float*)d_in[1];
    const float* Wpre  = (const float*)d_in[2];
    const float* bpre  = (const float*)d_in[3];
    const float* w1    = (const float*)d_in[4];
    const float* b1    = (const float*)d_in[5];
    const float* w2    = (const float*)d_in[6];
    const float* b2    = (const float*)d_in[7];
    const float* sw    = (const float*)d_in[8];
    const float* sb    = (const float*)d_in[9];
    const float* Wpost = (const float*)d_in[10];
    const float* bpost = (const float*)d_in[11];
    const float* Wqkv  = (const float*)d_in[12];
    const float* dww   = (const float*)d_in[13];
    const float* Wg1   = (const float*)d_in[14];
    const float* bg1   = (const float*)d_in[15];
    const float* wg2   = (const float*)d_in[16];
    const float* bg2   = (const float*)d_in[17];
    const float* temp  = (const float*)d_in[18];
    const float* scales= (const float*)d_in[19];
    const float* Wout  = (const float*)d_in[20];
    float* out = (float*)d_out;

    float* ws = (float*)d_ws;
    float* pooled_part = ws;                 // 16384
    float* gate_part   = ws + 16384;         // 64
    float* thr_sum     = ws + 16448;         // 32
    float* sumsq       = ws + 16480;         // 512
    float* Sg          = ws + 16992;         // 2048
    float* cw          = ws + 19040;         // 256
    float* kdyn        = ws + 19296;         // 1
    float* thr         = ws + 19328;         // 32
    float* A           = ws + 19360;         // 2048

    float* lb  = ws + 32768;
    float* pre = lb  + 16777216;
    float* qkv = pre + 16777216;
    float* v   = qkv + 50331648;

    hipMemsetAsync(ws, 0, (size_t)19040*sizeof(float), stream);

    k1_proj <<<2048, 256, 0, stream>>>(x, Wp, Wpre, bpre, Wqkv, Wg1, bg1, wg2, bg2,
                                       lb, pre, qkv, pooled_part, gate_part);
    k2_small<<<1,    256, 0, stream>>>(pooled_part, gate_part, w1, b1, w2, b2, cw, kdyn);
    k3_thr  <<<1024, 256, 0, stream>>>(pre, cw, sw, sb, thr_sum);
    k4_dw   <<<1024, 256, 0, stream>>>(qkv, dww, v, Sg, sumsq);
    k6_attn <<<1,    256, 0, stream>>>(Sg, sumsq, temp, kdyn, thr_sum, scales, A, thr);
    k7_final<<<4096, 256, 0, stream>>>(pre, lb, v, cw, thr, sw, sb, A,
                                       Wpost, bpost, Wout, out);
}

// Round 8
// 807.298 us; speedup vs baseline: 1.5361x; 1.0531x over previous
//
#include <hip/hip_runtime.h>
#include <math.h>

#define HWN 65536

__device__ __forceinline__ float sgm(float x){ return 1.0f/(1.0f+expf(-x)); }

__device__ __forceinline__ void fma4(float acc[4], const float4 w,
                                     const float4 x0, const float4 x1,
                                     const float4 x2, const float4 x3){
    acc[0] += w.x*x0.x + w.y*x1.x + w.z*x2.x + w.w*x3.x;
    acc[1] += w.x*x0.y + w.y*x1.y + w.z*x2.y + w.w*x3.y;
    acc[2] += w.x*x0.z + w.y*x1.z + w.z*x2.z + w.w*x3.z;
    acc[3] += w.x*x0.w + w.y*x1.w + w.z*x2.w + w.w*x3.w;
}

// ---------------------------------------------------------------------------
// K1: input_proj + lb store + lgce_pre (+pooled partials) + qkv + gate.
// R7 structure (8 px/thread, 128 px/block): 323 us, VALUBusy 62%, VGPR 104.
// History: occupancy falsified (21/33/32% -> 385/410/378); SGPR-broadcast
// falsified (R4 spill, R5 scalar-latency). Issue-intensity is the lever.
// launch_bounds(256,2): NEVER raise arg2 (R3: (256,4) -> VGPR 64 -> 4 GB spill).
// ---------------------------------------------------------------------------
__global__ __launch_bounds__(256,2) void k1_proj(
    const float* __restrict__ x,   const float* __restrict__ Wp,
    const float* __restrict__ Wpre,const float* __restrict__ bpre,
    const float* __restrict__ Wqkv,
    const float* __restrict__ Wg1, const float* __restrict__ bg1,
    const float* __restrict__ wg2, const float* __restrict__ bg2,
    float* __restrict__ lb, float* __restrict__ pre, float* __restrict__ qkv,
    float* __restrict__ pooled_part, float* __restrict__ gate_part)
{
    __shared__ float st[128*128];         // 64 KB: x staging -> proj output -> ht alias
    float4* st4 = (float4*)st;
    float*  ht  = st;                     // 32x128 floats = 16 KB, used after barrier

    const int t    = threadIdx.x;
    const int blk  = blockIdx.x;
    const int b    = blk >> 9;            // 512 blocks per batch
    const int p0   = (blk & 511) << 7;    // 128 px / block
    const int pg   = t & 15;              // pixel group: px pg*4..+3 and 64+pg*4..+3
    const int og   = t >> 4;              // output group
    const int slot = blk & 63;

    const float4* x4 = (const float4*)x;

    // ---- stage all of x (one burst)
    #pragma unroll
    for (int i = 0; i < 16; ++i) {
        int idx = t + 256*i;
        int c = idx >> 5, q = idx & 31;
        st4[c*32 + q] = x4[(size_t)(b*128 + c)*16384 + (p0>>2) + q];
    }
    __syncthreads();

    // ---- proj (128x128): og owns outs og*8..+7, 8 px each -> acc[8][8]
    {
        const int o0 = og*8;
        float acc[8][8];
        #pragma unroll
        for (int j=0;j<8;++j)
            #pragma unroll
            for (int k=0;k<8;++k) acc[j][k]=0.f;
        const float4* W4 = (const float4*)Wp;
        for (int c = 0; c < 128; c += 4) {
            float4 xa0 = st4[(c+0)*32 + pg],      xb0 = st4[(c+0)*32 + 16 + pg];
            float4 xa1 = st4[(c+1)*32 + pg],      xb1 = st4[(c+1)*32 + 16 + pg];
            float4 xa2 = st4[(c+2)*32 + pg],      xb2 = st4[(c+2)*32 + 16 + pg];
            float4 xa3 = st4[(c+3)*32 + pg],      xb3 = st4[(c+3)*32 + 16 + pg];
            #pragma unroll
            for (int j = 0; j < 8; ++j) {
                float4 w = W4[(o0+j)*32 + (c>>2)];
                fma4(&acc[j][0], w, xa0,xa1,xa2,xa3);
                fma4(&acc[j][4], w, xb0,xb1,xb2,xb3);
            }
        }
        __syncthreads();   // every thread done READING x before any overwrite

        #pragma unroll
        for (int j = 0; j < 8; ++j) {
            st4[(o0+j)*32 + pg]      = make_float4(acc[j][0],acc[j][1],acc[j][2],acc[j][3]);
            st4[(o0+j)*32 + 16 + pg] = make_float4(acc[j][4],acc[j][5],acc[j][6],acc[j][7]);
        }
        if (og < 8) {      // lb = proj channels 0..63, straight from registers
            float4* lb4 = (float4*)lb;
            #pragma unroll
            for (int j = 0; j < 8; ++j) {
                lb4[(size_t)(b*64 + o0+j)*16384 + (p0>>2) + pg] =
                    make_float4(acc[j][0],acc[j][1],acc[j][2],acc[j][3]);
                lb4[(size_t)(b*64 + o0+j)*16384 + (p0>>2) + 16 + pg] =
                    make_float4(acc[j][4],acc[j][5],acc[j][6],acc[j][7]);
            }
        }
    }
    __syncthreads();       // proj output ready

    // ---- pre conv (64x64): og owns 4 outs -> acc[4][8]; + pooled partials
    {
        const int o0 = og*4;
        float acc[4][8];
        #pragma unroll
        for (int j=0;j<4;++j)
            #pragma unroll
            for (int k=0;k<8;++k) acc[j][k]=0.f;
        const float4* W4 = (const float4*)Wpre;
        for (int c = 0; c < 64; c += 4) {
            float4 xa0 = st4[(c+0)*32 + pg],      xb0 = st4[(c+0)*32 + 16 + pg];
            float4 xa1 = st4[(c+1)*32 + pg],      xb1 = st4[(c+1)*32 + 16 + pg];
            float4 xa2 = st4[(c+2)*32 + pg],      xb2 = st4[(c+2)*32 + 16 + pg];
            float4 xa3 = st4[(c+3)*32 + pg],      xb3 = st4[(c+3)*32 + 16 + pg];
            #pragma unroll
            for (int j = 0; j < 4; ++j) {
                float4 w = W4[(o0+j)*16 + (c>>2)];
                fma4(&acc[j][0], w, xa0,xa1,xa2,xa3);
                fma4(&acc[j][4], w, xb0,xb1,xb2,xb3);
            }
        }
        float4* pre4 = (float4*)pre;
        #pragma unroll
        for (int j = 0; j < 4; ++j) {
            float bs = bpre[o0+j];
            float4 v0 = make_float4(acc[j][0]+bs, acc[j][1]+bs, acc[j][2]+bs, acc[j][3]+bs);
            float4 v1 = make_float4(acc[j][4]+bs, acc[j][5]+bs, acc[j][6]+bs, acc[j][7]+bs);
            pre4[(size_t)(b*64 + o0+j)*16384 + (p0>>2) + pg]      = v0;
            pre4[(size_t)(b*64 + o0+j)*16384 + (p0>>2) + 16 + pg] = v1;
            float s = v0.x+v0.y+v0.z+v0.w + v1.x+v1.y+v1.z+v1.w;
            s += __shfl_xor(s,1); s += __shfl_xor(s,2);
            s += __shfl_xor(s,4); s += __shfl_xor(s,8);
            if (pg == 0) atomicAdd(&pooled_part[slot*256 + b*64 + o0 + j], s);
        }
    }

    // ---- qkv conv (192x64): og owns 12 outs, 2 chunks of 6 -> acc[6][8]
    #pragma unroll
    for (int chk = 0; chk < 2; ++chk) {
        const int o0 = og*12 + chk*6;
        float acc[6][8];
        #pragma unroll
        for (int j=0;j<6;++j)
            #pragma unroll
            for (int k=0;k<8;++k) acc[j][k]=0.f;
        const float4* W4 = (const float4*)Wqkv;
        for (int c = 0; c < 64; c += 4) {
            float4 xa0 = st4[(64+c+0)*32 + pg],   xb0 = st4[(64+c+0)*32 + 16 + pg];
            float4 xa1 = st4[(64+c+1)*32 + pg],   xb1 = st4[(64+c+1)*32 + 16 + pg];
            float4 xa2 = st4[(64+c+2)*32 + pg],   xb2 = st4[(64+c+2)*32 + 16 + pg];
            float4 xa3 = st4[(64+c+3)*32 + pg],   xb3 = st4[(64+c+3)*32 + 16 + pg];
            #pragma unroll
            for (int j = 0; j < 6; ++j) {
                float4 w = W4[(o0+j)*16 + (c>>2)];
                fma4(&acc[j][0], w, xa0,xa1,xa2,xa3);
                fma4(&acc[j][4], w, xb0,xb1,xb2,xb3);
            }
        }
        float4* qkv4 = (float4*)qkv;
        #pragma unroll
        for (int j = 0; j < 6; ++j) {
            qkv4[(size_t)(b*192 + o0+j)*16384 + (p0>>2) + pg] =
                make_float4(acc[j][0],acc[j][1],acc[j][2],acc[j][3]);
            qkv4[(size_t)(b*192 + o0+j)*16384 + (p0>>2) + 16 + pg] =
                make_float4(acc[j][4],acc[j][5],acc[j][6],acc[j][7]);
        }
    }

    // ---- gate hidden (32x64): og owns 2 outs -> acc[2][8], held across barrier
    {
        const int o0 = og*2;
        float acc[2][8];
        #pragma unroll
        for (int j=0;j<2;++j)
            #pragma unroll
            for (int k=0;k<8;++k) acc[j][k]=0.f;
        const float4* W4 = (const float4*)Wg1;
        for (int c = 0; c < 64; c += 4) {
            float4 xa0 = st4[(64+c+0)*32 + pg],   xb0 = st4[(64+c+0)*32 + 16 + pg];
            float4 xa1 = st4[(64+c+1)*32 + pg],   xb1 = st4[(64+c+1)*32 + 16 + pg];
            float4 xa2 = st4[(64+c+2)*32 + pg],   xb2 = st4[(64+c+2)*32 + 16 + pg];
            float4 xa3 = st4[(64+c+3)*32 + pg],   xb3 = st4[(64+c+3)*32 + 16 + pg];
            #pragma unroll
            for (int j = 0; j < 2; ++j) {
                float4 w = W4[(o0+j)*16 + (c>>2)];
                fma4(&acc[j][0], w, xa0,xa1,xa2,xa3);
                fma4(&acc[j][4], w, xb0,xb1,xb2,xb3);
            }
        }
        __syncthreads();   // ALL pt reads complete before ht overwrites st
        #pragma unroll
        for (int j = 0; j < 2; ++j) {
            float bs = bg1[o0+j];
            #pragma unroll
            for (int k = 0; k < 4; ++k) {
                ht[(o0+j)*128 + pg*4 + k]      = fmaxf(acc[j][k]+bs,   0.0f);
                ht[(o0+j)*128 + 64 + pg*4 + k] = fmaxf(acc[j][4+k]+bs, 0.0f);
            }
        }
    }
    __syncthreads();

    // ---- gate scalar: 128 px, 2 waves, wave-reduce + atomic each
    if (t < 128) {
        float g = bg2[0];
        #pragma unroll
        for (int c = 0; c < 32; ++c) g += wg2[c]*ht[c*128 + t];
        g = sgm(g);
        g += __shfl_xor(g,1);  g += __shfl_xor(g,2);  g += __shfl_xor(g,4);
        g += __shfl_xor(g,8);  g += __shfl_xor(g,16); g += __shfl_xor(g,32);
        if ((t & 63) == 0) atomicAdd(&gate_part[slot], g);
    }
}

// ---------------------------------------------------------------------------
// K2: pooled -> cw, gate mean -> kdyn. single block.
// ---------------------------------------------------------------------------
__global__ void k2_small(const float* __restrict__ pooled_part,
                         const float* __restrict__ gate_part,
                         const float* __restrict__ w1, const float* __restrict__ b1,
                         const float* __restrict__ w2, const float* __restrict__ b2,
                         float* __restrict__ cw, float* __restrict__ kdyn)
{
    __shared__ float pl[256];
    const int t = threadIdx.x;
    float s = 0.f;
    for (int sl = 0; sl < 64; ++sl) s += pooled_part[sl*256 + t];
    pl[t] = s * (1.0f/65536.0f);
    __syncthreads();
    const int b = t >> 6, g = (t >> 3) & 7, c = t & 7;
    float h0 = b1[g*2+0], h1 = b1[g*2+1];
    #pragma unroll
    for (int cc = 0; cc < 8; ++cc) {
        float p = pl[b*64 + g*8 + cc];
        h0 += p*w1[g*16 + 0*8 + cc];
        h1 += p*w1[g*16 + 1*8 + cc];
    }
    h0 = fmaxf(h0, 0.f); h1 = fmaxf(h1, 0.f);
    cw[t] = sgm(h0*w2[g*16 + c*2 + 0] + h1*w2[g*16 + c*2 + 1] + b2[g*8+c]);
    if (t == 0) {
        float gs = 0.f;
        for (int sl = 0; sl < 64; ++sl) gs += gate_part[sl];
        float kd = floorf(8.0f * (gs * (1.0f/262144.0f)));
        *kdyn = fminf(fmaxf(kd, 1.0f), 8.0f);
    }
}

// ---------------------------------------------------------------------------
// K3: resp partial sums for thr.
// ---------------------------------------------------------------------------
__global__ __launch_bounds__(256) void k3_thr(
    const float* __restrict__ pre, const float* __restrict__ cw,
    const float* __restrict__ sw,  const float* __restrict__ sb,
    float* __restrict__ thr_sum)
{
    __shared__ float part[4][8];
    const int t = threadIdx.x;
    const int b = blockIdx.x >> 8;
    const int p = ((blockIdx.x & 255) << 8) + t;
    float rs[8];
    #pragma unroll
    for (int g = 0; g < 8; ++g) {
        float xc[8];
        float spa = sb[g];
        #pragma unroll
        for (int c = 0; c < 8; ++c) {
            float xv = pre[(size_t)(b*64 + g*8 + c)*HWN + p];
            xc[c] = xv * cw[b*64 + g*8 + c];
            spa += xc[c]*sw[g*8 + c];
        }
        float sp = sgm(spa);
        float s = 0.f;
        #pragma unroll
        for (int c = 0; c < 8; ++c) s += sgm(xc[c]*sp);
        rs[g] = s;
    }
    const int lane = t & 63, wv = t >> 6;
    #pragma unroll
    for (int g = 0; g < 8; ++g) {
        float val = rs[g];
        val += __shfl_xor(val,1);  val += __shfl_xor(val,2);  val += __shfl_xor(val,4);
        val += __shfl_xor(val,8);  val += __shfl_xor(val,16); val += __shfl_xor(val,32);
        if (lane == 0) part[wv][g] = val;
    }
    __syncthreads();
    if (t < 8)
        atomicAdd(&thr_sum[b*8 + t], part[0][t]+part[1][t]+part[2][t]+part[3][t]);
}

// ---------------------------------------------------------------------------
// K4: depthwise 3x3; block = (b, h, 8-row band of 256 cols).
// In-loop wave-reduced Gram/norm accumulation (no S[64] array -> no spill),
// double-buffered LDS, launch_bounds(256,3). See R3 notes.
// ---------------------------------------------------------------------------
#define K4_ROWSTRIDE 264            // 4 pad | 256 data | 4 pad (floats)
#define K4_BUF (10*K4_ROWSTRIDE)    // 10 halo rows

__global__ __launch_bounds__(256,3) void k4_dw(
    const float* __restrict__ qkv, const float* __restrict__ dww,
    float* __restrict__ v, float* __restrict__ Sg, float* __restrict__ sumsq)
{
    __shared__ float sh[2*K4_BUF];  // 21120 B

    const int t    = threadIdx.x;
    const int b    = blockIdx.x >> 8;         // 256 blocks / batch
    const int h    = (blockIdx.x >> 5) & 7;
    const int band = blockIdx.x & 31;
    const int r0   = band * 8;
    const int lr   = t >> 5;                  // output row 0..7
    const int c0   = (t & 31) * 4;            // group0 cols c0..c0+3; group1 +128
    const int lane = t & 63;

    // edge columns (global col -1 and 256) are always zero; init once per buffer
    if (t < 40) {
        int bufi = t / 20, r = (t % 20) >> 1, side = t & 1;
        sh[bufi*K4_BUF + r*K4_ROWSTRIDE + (side ? 260 : 3)] = 0.0f;
    }

    float4 reg[3];

    auto issue_loads = [&](int ch) {
        const float4* base = (const float4*)(qkv + (size_t)(b*192 + ch)*HWN);
        #pragma unroll
        for (int j = 0; j < 3; ++j) {
            int i = t + 256*j;
            float4 val = make_float4(0.f,0.f,0.f,0.f);
            if (i < 640) {
                int row = i >> 6, col4 = i & 63;
                int gy = r0 - 1 + row;
                if (gy >= 0 && gy < 256) val = base[gy*64 + col4];
            }
            reg[j] = val;
        }
    };

    auto write_lds = [&](float* buf) {
        #pragma unroll
        for (int j = 0; j < 3; ++j) {
            int i = t + 256*j;
            if (i < 640) {
                int row = i >> 6, col4 = i & 63;
                *(float4*)&buf[row*K4_ROWSTRIDE + 4 + col4*4] = reg[j];
            }
        }
    };

    auto conv8 = [&](const float* buf, const float* __restrict__ w9, float out[8]) {
        #pragma unroll
        for (int g = 0; g < 2; ++g) {
            const int cc = c0 + g*128;
            float a0=0.f, a1=0.f, a2=0.f, a3=0.f;
            #pragma unroll
            for (int rr = 0; rr < 3; ++rr) {
                const float* row = &buf[(lr+rr)*K4_ROWSTRIDE + 4 + cc];
                float4 m = *(const float4*)row;
                float l = row[-1], r = row[4];
                float w0 = w9[rr*3+0], w1 = w9[rr*3+1], w2 = w9[rr*3+2];
                a0 = fmaf(w0,l,   fmaf(w1,m.x, fmaf(w2,m.y, a0)));
                a1 = fmaf(w0,m.x, fmaf(w1,m.y, fmaf(w2,m.z, a1)));
                a2 = fmaf(w0,m.y, fmaf(w1,m.z, fmaf(w2,m.w, a2)));
                a3 = fmaf(w0,m.z, fmaf(w1,m.w, fmaf(w2,r,   a3)));
            }
            out[g*4+0]=a0; out[g*4+1]=a1; out[g*4+2]=a2; out[g*4+3]=a3;
        }
    };

    auto wsum = [&](float val) {
        val += __shfl_xor(val,1);  val += __shfl_xor(val,2);  val += __shfl_xor(val,4);
        val += __shfl_xor(val,8);  val += __shfl_xor(val,16); val += __shfl_xor(val,32);
        return val;
    };

    float dq[8][8];

    float* sq_q = &sumsq[b*128 + h*8];
    float* sq_k = &sumsq[b*128 + 64 + h*8];
    float* Sgb  = &Sg[(size_t)(b*8+h)*64];

    issue_loads(h*8 + 0);   // first q channel

    // ---- Q channels: conv + immediate ||q||^2 partial
    #pragma unroll
    for (int ch = 0; ch < 8; ++ch) {
        float* buf = sh + (ch & 1)*K4_BUF;
        write_lds(buf);
        issue_loads(ch < 7 ? (h*8 + ch + 1) : (64 + h*8));
        __syncthreads();
        conv8(buf, dww + (h*8 + ch)*9, dq[ch]);
        float ss = 0.f;
        #pragma unroll
        for (int p = 0; p < 8; ++p) ss = fmaf(dq[ch][p], dq[ch][p], ss);
        ss = wsum(ss);
        if (lane == 0) atomicAdd(&sq_q[ch], ss);
    }

    // ---- K channels: conv + Gram row + ||k||^2, all reduced in-loop
    #pragma unroll
    for (int ch = 0; ch < 8; ++ch) {
        float* buf = sh + (ch & 1)*K4_BUF;
        write_lds(buf);
        issue_loads(ch < 7 ? (64 + h*8 + ch + 1) : (128 + h*8));
        __syncthreads();
        float dk[8];
        conv8(buf, dww + (64 + h*8 + ch)*9, dk);
        float ss = 0.f;
        #pragma unroll
        for (int p = 0; p < 8; ++p) ss = fmaf(dk[p], dk[p], ss);
        ss = wsum(ss);
        if (lane == 0) atomicAdd(&sq_k[ch], ss);
        #pragma unroll
        for (int c = 0; c < 8; ++c) {
            float acc = 0.f;
            #pragma unroll
            for (int p = 0; p < 8; ++p) acc = fmaf(dq[c][p], dk[p], acc);
            acc = wsum(acc);
            if (lane == 0) atomicAdd(&Sgb[c*8 + ch], acc);
        }
    }

    // ---- V channels (compute + store only)
    #pragma unroll
    for (int ch = 0; ch < 8; ++ch) {
        float* buf = sh + (ch & 1)*K4_BUF;
        write_lds(buf);
        if (ch < 7) issue_loads(128 + h*8 + ch + 1);
        __syncthreads();
        float dv[8];
        conv8(buf, dww + (128 + h*8 + ch)*9, dv);
        float* vb = v + (size_t)(b*64 + h*8 + ch)*HWN + (r0 + lr)*256;
        *(float4*)&vb[c0]       = make_float4(dv[0],dv[1],dv[2],dv[3]);
        *(float4*)&vb[c0 + 128] = make_float4(dv[4],dv[5],dv[6],dv[7]);
    }
}

// ---------------------------------------------------------------------------
// K6: finalize attention weights and thr. single block.
// ---------------------------------------------------------------------------
__global__ void k6_attn(const float* __restrict__ Sg, const float* __restrict__ sumsq,
                        const float* __restrict__ temp, const float* __restrict__ kdynp,
                        const float* __restrict__ thr_sum, const float* __restrict__ scales,
                        float* __restrict__ A, float* __restrict__ thr)
{
    const int t = threadIdx.x;
    if (t < 32) thr[t] = thr_sum[t] * (1.0f/(8.0f*65536.0f));
    const int b = t >> 6, h = (t >> 3) & 7, c = t & 7;
    const float kd = *kdynp;
    const float ssum = scales[0]+scales[1]+scales[2]+scales[3];
    const float nq = fmaxf(sqrtf(sumsq[b*128 + h*8 + c]), 1e-12f);
    const float tv = temp[h];
    const float* Srow = Sg + (size_t)(b*8+h)*64 + c*8;
    float a[8];
    #pragma unroll
    for (int d = 0; d < 8; ++d) {
        float nk = fmaxf(sqrtf(sumsq[b*128 + 64 + h*8 + d]), 1e-12f);
        a[d] = Srow[d] / (nq*nk) * tv;
    }
    bool keep[8];
    #pragma unroll
    for (int d = 0; d < 8; ++d) {
        int r = 0;
        #pragma unroll
        for (int e = 0; e < 8; ++e)
            r += (a[e] > a[d]) || (a[e] == a[d] && e < d);
        keep[d] = ((float)r < kd);
    }
    float m = -INFINITY;
    #pragma unroll
    for (int d = 0; d < 8; ++d) if (keep[d]) m = fmaxf(m, a[d]);
    float ex[8]; float sum = 0.f;
    #pragma unroll
    for (int d = 0; d < 8; ++d) { ex[d] = keep[d] ? expf(a[d]-m) : 0.f; sum += ex[d]; }
    const float inv = ssum / sum;
    #pragma unroll
    for (int d = 0; d < 8; ++d)
        A[(size_t)(b*8+h)*64 + c*8 + d] = ex[d]*inv;
}

// ---------------------------------------------------------------------------
// K7: mask path + post conv + residual + attn@v + proj_out, fused epilogue.
//
// R8 (8 px/thread + in-place, the R7 lever applied here): 128 px/block,
// each weight/attn register feeds 8 FMAs (was 4); ft buffer dropped --
// post+lb and attn@v accumulate in registers, write back IN PLACE into
// pr/vt after a barrier (out conv reads ch 0..63 from vt = attn half,
// 64..127 from pr = post half; FP order identical to the ft layout,
// validated in R2). LDS 64 KB (pr+vt), (256,2), peak live ~100 VGPR.
// ---------------------------------------------------------------------------
__global__ __launch_bounds__(256,2) void k7_final(
    const float* __restrict__ pre, const float* __restrict__ lb, const float* __restrict__ v,
    const float* __restrict__ cw,  const float* __restrict__ thr,
    const float* __restrict__ sw,  const float* __restrict__ sb,
    const float* __restrict__ A,
    const float* __restrict__ Wpost, const float* __restrict__ bpost,
    const float* __restrict__ Wout,  float* __restrict__ out)
{
    __shared__ float pr[64*128];   // 32 KB: pre -> masked -> post+lb result
    __shared__ float vt[64*128];   // 32 KB: v   -> attn@v result
    float4* pr4 = (float4*)pr;
    float4* vt4 = (float4*)vt;

    const int t   = threadIdx.x;
    const int blk = blockIdx.x;
    const int b   = blk >> 9;            // 512 blocks per batch
    const int p0  = (blk & 511) << 7;    // 128 px / block
    const int pg  = t & 15;              // px pg*4..+3 and 64+pg*4..+3
    const int og  = t >> 4;

    const float4* pre4g = (const float4*)pre;
    const float4* v4g   = (const float4*)v;
    #pragma unroll
    for (int i = 0; i < 8; ++i) {
        int idx = t + 256*i;
        int c = idx >> 5, q = idx & 31;
        size_t gi = (size_t)(b*64 + c)*16384 + (p0>>2) + q;
        pr4[c*32+q] = pre4g[gi];
        vt4[c*32+q] = v4g[gi];
    }
    __syncthreads();

    // ---- mask path, in place on pr: 8 groups x 128 px = 1024 tasks, 4/thread
    #pragma unroll
    for (int s = 0; s < 4; ++s) {
        int task = t + 256*s;
        int g = task >> 7, px = task & 127;
        float xc[8], xv[8];
        float spa = sb[g];
        #pragma unroll
        for (int c = 0; c < 8; ++c) {
            xv[c] = pr[(g*8+c)*128 + px];
            xc[c] = xv[c]*cw[b*64 + g*8 + c];
            spa += xc[c]*sw[g*8 + c];
        }
        float sp = sgm(spa);
        float th = thr[b*8 + g];
        #pragma unroll
        for (int c = 0; c < 8; ++c) {
            float resp = sgm(xc[c]*sp);
            float mask = resp > th ? 1.0f : resp;
            pr[(g*8+c)*128 + px] = xv[c]*mask;
        }
    }
    __syncthreads();

    // ---- post conv (64x64) + bias + lb residual -> registers (acc[4][8])
    float postv[4][8];
    {
        const int o0 = og*4;
        float acc[4][8];
        #pragma unroll
        for (int j=0;j<4;++j)
            #pragma unroll
            for (int k=0;k<8;++k) acc[j][k]=0.f;
        const float4* W4 = (const float4*)Wpost;
        for (int c = 0; c < 64; c += 4) {
            float4 xa0 = pr4[(c+0)*32 + pg],      xb0 = pr4[(c+0)*32 + 16 + pg];
            float4 xa1 = pr4[(c+1)*32 + pg],      xb1 = pr4[(c+1)*32 + 16 + pg];
            float4 xa2 = pr4[(c+2)*32 + pg],      xb2 = pr4[(c+2)*32 + 16 + pg];
            float4 xa3 = pr4[(c+3)*32 + pg],      xb3 = pr4[(c+3)*32 + 16 + pg];
            #pragma unroll
            for (int j = 0; j < 4; ++j) {
                float4 w = W4[(o0+j)*16 + (c>>2)];
                fma4(&acc[j][0], w, xa0,xa1,xa2,xa3);
                fma4(&acc[j][4], w, xb0,xb1,xb2,xb3);
            }
        }
        const float4* lb4 = (const float4*)lb;
        #pragma unroll
        for (int j = 0; j < 4; ++j) {
            float bs = bpost[o0+j];
            float4 l0 = lb4[(size_t)(b*64 + o0+j)*16384 + (p0>>2) + pg];
            float4 l1 = lb4[(size_t)(b*64 + o0+j)*16384 + (p0>>2) + 16 + pg];
            postv[j][0]=acc[j][0]+bs+l0.x; postv[j][1]=acc[j][1]+bs+l0.y;
            postv[j][2]=acc[j][2]+bs+l0.z; postv[j][3]=acc[j][3]+bs+l0.w;
            postv[j][4]=acc[j][4]+bs+l1.x; postv[j][5]=acc[j][5]+bs+l1.y;
            postv[j][6]=acc[j][6]+bs+l1.z; postv[j][7]=acc[j][7]+bs+l1.w;
        }
    }

    // ---- attn @ v -> registers (acc[4][8])
    float attv[4][8];
    {
        const int ch0 = og*4;
        #pragma unroll
        for (int j = 0; j < 4; ++j) {
            int ch = ch0 + j;
            int hh = ch >> 3, c = ch & 7;
            const float* Ar = A + (size_t)(b*8+hh)*64 + c*8;
            float a0=0.f,a1=0.f,a2=0.f,a3=0.f,a4=0.f,a5=0.f,a6=0.f,a7=0.f;
            #pragma unroll
            for (int d = 0; d < 8; ++d) {
                float av = Ar[d];
                float4 v0 = vt4[(hh*8+d)*32 + pg];
                float4 v1 = vt4[(hh*8+d)*32 + 16 + pg];
                a0 += av*v0.x; a1 += av*v0.y; a2 += av*v0.z; a3 += av*v0.w;
                a4 += av*v1.x; a5 += av*v1.y; a6 += av*v1.z; a7 += av*v1.w;
            }
            attv[j][0]=a0; attv[j][1]=a1; attv[j][2]=a2; attv[j][3]=a3;
            attv[j][4]=a4; attv[j][5]=a5; attv[j][6]=a6; attv[j][7]=a7;
        }
    }
    __syncthreads();   // all pr/vt reads complete

    // ---- write back in place: vt <- attn half (ch 0..63), pr <- post half
    {
        const int o0 = og*4;
        #pragma unroll
        for (int j = 0; j < 4; ++j) {
            vt4[(o0+j)*32 + pg]      = make_float4(attv[j][0],attv[j][1],attv[j][2],attv[j][3]);
            vt4[(o0+j)*32 + 16 + pg] = make_float4(attv[j][4],attv[j][5],attv[j][6],attv[j][7]);
            pr4[(o0+j)*32 + pg]      = make_float4(postv[j][0],postv[j][1],postv[j][2],postv[j][3]);
            pr4[(o0+j)*32 + 16 + pg] = make_float4(postv[j][4],postv[j][5],postv[j][6],postv[j][7]);
        }
    }
    __syncthreads();

    // ---- out conv (128x128): ch 0..63 = vt (attn), 64..127 = pr (post)
    {
        const int o0 = og*8;
        float acc[8][8];
        #pragma unroll
        for (int j=0;j<8;++j)
            #pragma unroll
            for (int k=0;k<8;++k) acc[j][k]=0.f;
        const float4* W4 = (const float4*)Wout;
        for (int c = 0; c < 64; c += 4) {
            float4 xa0 = vt4[(c+0)*32 + pg],      xb0 = vt4[(c+0)*32 + 16 + pg];
            float4 xa1 = vt4[(c+1)*32 + pg],      xb1 = vt4[(c+1)*32 + 16 + pg];
            float4 xa2 = vt4[(c+2)*32 + pg],      xb2 = vt4[(c+2)*32 + 16 + pg];
            float4 xa3 = vt4[(c+3)*32 + pg],      xb3 = vt4[(c+3)*32 + 16 + pg];
            #pragma unroll
            for (int j = 0; j < 8; ++j) {
                float4 w = W4[(o0+j)*32 + (c>>2)];
                fma4(&acc[j][0], w, xa0,xa1,xa2,xa3);
                fma4(&acc[j][4], w, xb0,xb1,xb2,xb3);
            }
        }
        for (int c = 0; c < 64; c += 4) {
            float4 xa0 = pr4[(c+0)*32 + pg],      xb0 = pr4[(c+0)*32 + 16 + pg];
            float4 xa1 = pr4[(c+1)*32 + pg],      xb1 = pr4[(c+1)*32 + 16 + pg];
            float4 xa2 = pr4[(c+2)*32 + pg],      xb2 = pr4[(c+2)*32 + 16 + pg];
            float4 xa3 = pr4[(c+3)*32 + pg],      xb3 = pr4[(c+3)*32 + 16 + pg];
            #pragma unroll
            for (int j = 0; j < 8; ++j) {
                float4 w = W4[(o0+j)*32 + 16 + (c>>2)];
                fma4(&acc[j][0], w, xa0,xa1,xa2,xa3);
                fma4(&acc[j][4], w, xb0,xb1,xb2,xb3);
            }
        }
        float4* out4 = (float4*)out;
        #pragma unroll
        for (int j = 0; j < 8; ++j) {
            out4[(size_t)(b*128 + o0+j)*16384 + (p0>>2) + pg] =
                make_float4(acc[j][0],acc[j][1],acc[j][2],acc[j][3]);
            out4[(size_t)(b*128 + o0+j)*16384 + (p0>>2) + 16 + pg] =
                make_float4(acc[j][4],acc[j][5],acc[j][6],acc[j][7]);
        }
    }
}

// ---------------------------------------------------------------------------
extern "C" void kernel_launch(void* const* d_in, const int* in_sizes, int n_in,
                              void* d_out, int out_size, void* d_ws, size_t ws_size,
                              hipStream_t stream)
{
    const float* x     = (const float*)d_in[0];
    const float* Wp    = (const float*)d_in[1];
    const float* Wpre  = (const float*)d_in[2];
    const float* bpre  = (const float*)d_in[3];
    const float* w1    = (const float*)d_in[4];
    const float* b1    = (const float*)d_in[5];
    const float* w2    = (const float*)d_in[6];
    const float* b2    = (const float*)d_in[7];
    const float* sw    = (const float*)d_in[8];
    const float* sb    = (const float*)d_in[9];
    const float* Wpost = (const float*)d_in[10];
    const float* bpost = (const float*)d_in[11];
    const float* Wqkv  = (const float*)d_in[12];
    const float* dww   = (const float*)d_in[13];
    const float* Wg1   = (const float*)d_in[14];
    const float* bg1   = (const float*)d_in[15];
    const float* wg2   = (const float*)d_in[16];
    const float* bg2   = (const float*)d_in[17];
    const float* temp  = (const float*)d_in[18];
    const float* scales= (const float*)d_in[19];
    const float* Wout  = (const float*)d_in[20];
    float* out = (float*)d_out;

    float* ws = (float*)d_ws;
    float* pooled_part = ws;                 // 16384
    float* gate_part   = ws + 16384;         // 64
    float* thr_sum     = ws + 16448;         // 32
    float* sumsq       = ws + 16480;         // 512
    float* Sg          = ws + 16992;         // 2048
    float* cw          = ws + 19040;         // 256
    float* kdyn        = ws + 19296;         // 1
    float* thr         = ws + 19328;         // 32
    float* A           = ws + 19360;         // 2048

    float* lb  = ws + 32768;
    float* pre = lb  + 16777216;
    float* qkv = pre + 16777216;
    float* v   = qkv + 50331648;

    hipMemsetAsync(ws, 0, (size_t)19040*sizeof(float), stream);

    k1_proj <<<2048, 256, 0, stream>>>(x, Wp, Wpre, bpre, Wqkv, Wg1, bg1, wg2, bg2,
                                       lb, pre, qkv, pooled_part, gate_part);
    k2_small<<<1,    256, 0, stream>>>(pooled_part, gate_part, w1, b1, w2, b2, cw, kdyn);
    k3_thr  <<<1024, 256, 0, stream>>>(pre, cw, sw, sb, thr_sum);
    k4_dw   <<<1024, 256, 0, stream>>>(qkv, dww, v, Sg, sumsq);
    k6_attn <<<1,    256, 0, stream>>>(Sg, sumsq, temp, kdyn, thr_sum, scales, A, thr);
    k7_final<<<2048, 256, 0, stream>>>(pre, lb, v, cw, thr, sw, sb, A,
                                       Wpost, bpost, Wout, out);
}

// Round 9
// 796.963 us; speedup vs baseline: 1.5560x; 1.0130x over previous
//
#include <hip/hip_runtime.h>
#include <math.h>

#define HWN 65536

__device__ __forceinline__ float sgm(float x){ return 1.0f/(1.0f+expf(-x)); }

__device__ __forceinline__ void fma4(float acc[4], const float4 w,
                                     const float4 x0, const float4 x1,
                                     const float4 x2, const float4 x3){
    acc[0] += w.x*x0.x + w.y*x1.x + w.z*x2.x + w.w*x3.x;
    acc[1] += w.x*x0.y + w.y*x1.y + w.z*x2.y + w.w*x3.y;
    acc[2] += w.x*x0.z + w.y*x1.z + w.z*x2.z + w.w*x3.z;
    acc[3] += w.x*x0.w + w.y*x1.w + w.z*x2.w + w.w*x3.w;
}

// ---------------------------------------------------------------------------
// K1: input_proj + lb store + lgce_pre (+pooled partials) + qkv + gate.
// R7 structure (8 px/thread, 128 px/block): 323 us, VALUBusy 62%, VGPR 104.
// R9: #pragma unroll 2 on conv c-loops -- ILP lever; at 2 waves/SIMD only
// in-wave parallelism hides LDS/weight-load latency. VGPR headroom to 256
// at (256,2). History: occupancy falsified (21/33/32% -> 385/410/378);
// SGPR-broadcast falsified (R4 spill, R5 scalar-latency).
// launch_bounds(256,2): NEVER raise arg2 (R3: (256,4) -> VGPR 64 -> 4 GB spill).
// ---------------------------------------------------------------------------
__global__ __launch_bounds__(256,2) void k1_proj(
    const float* __restrict__ x,   const float* __restrict__ Wp,
    const float* __restrict__ Wpre,const float* __restrict__ bpre,
    const float* __restrict__ Wqkv,
    const float* __restrict__ Wg1, const float* __restrict__ bg1,
    const float* __restrict__ wg2, const float* __restrict__ bg2,
    float* __restrict__ lb, float* __restrict__ pre, float* __restrict__ qkv,
    float* __restrict__ pooled_part, float* __restrict__ gate_part)
{
    __shared__ float st[128*128];         // 64 KB: x staging -> proj output -> ht alias
    float4* st4 = (float4*)st;
    float*  ht  = st;                     // 32x128 floats = 16 KB, used after barrier

    const int t    = threadIdx.x;
    const int blk  = blockIdx.x;
    const int b    = blk >> 9;            // 512 blocks per batch
    const int p0   = (blk & 511) << 7;    // 128 px / block
    const int pg   = t & 15;              // pixel group: px pg*4..+3 and 64+pg*4..+3
    const int og   = t >> 4;              // output group
    const int slot = blk & 63;

    const float4* x4 = (const float4*)x;

    // ---- stage all of x (one burst)
    #pragma unroll
    for (int i = 0; i < 16; ++i) {
        int idx = t + 256*i;
        int c = idx >> 5, q = idx & 31;
        st4[c*32 + q] = x4[(size_t)(b*128 + c)*16384 + (p0>>2) + q];
    }
    __syncthreads();

    // ---- proj (128x128): og owns outs og*8..+7, 8 px each -> acc[8][8]
    {
        const int o0 = og*8;
        float acc[8][8];
        #pragma unroll
        for (int j=0;j<8;++j)
            #pragma unroll
            for (int k=0;k<8;++k) acc[j][k]=0.f;
        const float4* W4 = (const float4*)Wp;
        #pragma unroll 2
        for (int c = 0; c < 128; c += 4) {
            float4 xa0 = st4[(c+0)*32 + pg],      xb0 = st4[(c+0)*32 + 16 + pg];
            float4 xa1 = st4[(c+1)*32 + pg],      xb1 = st4[(c+1)*32 + 16 + pg];
            float4 xa2 = st4[(c+2)*32 + pg],      xb2 = st4[(c+2)*32 + 16 + pg];
            float4 xa3 = st4[(c+3)*32 + pg],      xb3 = st4[(c+3)*32 + 16 + pg];
            #pragma unroll
            for (int j = 0; j < 8; ++j) {
                float4 w = W4[(o0+j)*32 + (c>>2)];
                fma4(&acc[j][0], w, xa0,xa1,xa2,xa3);
                fma4(&acc[j][4], w, xb0,xb1,xb2,xb3);
            }
        }
        __syncthreads();   // every thread done READING x before any overwrite

        #pragma unroll
        for (int j = 0; j < 8; ++j) {
            st4[(o0+j)*32 + pg]      = make_float4(acc[j][0],acc[j][1],acc[j][2],acc[j][3]);
            st4[(o0+j)*32 + 16 + pg] = make_float4(acc[j][4],acc[j][5],acc[j][6],acc[j][7]);
        }
        if (og < 8) {      // lb = proj channels 0..63, straight from registers
            float4* lb4 = (float4*)lb;
            #pragma unroll
            for (int j = 0; j < 8; ++j) {
                lb4[(size_t)(b*64 + o0+j)*16384 + (p0>>2) + pg] =
                    make_float4(acc[j][0],acc[j][1],acc[j][2],acc[j][3]);
                lb4[(size_t)(b*64 + o0+j)*16384 + (p0>>2) + 16 + pg] =
                    make_float4(acc[j][4],acc[j][5],acc[j][6],acc[j][7]);
            }
        }
    }
    __syncthreads();       // proj output ready

    // ---- pre conv (64x64): og owns 4 outs -> acc[4][8]; + pooled partials
    {
        const int o0 = og*4;
        float acc[4][8];
        #pragma unroll
        for (int j=0;j<4;++j)
            #pragma unroll
            for (int k=0;k<8;++k) acc[j][k]=0.f;
        const float4* W4 = (const float4*)Wpre;
        #pragma unroll 2
        for (int c = 0; c < 64; c += 4) {
            float4 xa0 = st4[(c+0)*32 + pg],      xb0 = st4[(c+0)*32 + 16 + pg];
            float4 xa1 = st4[(c+1)*32 + pg],      xb1 = st4[(c+1)*32 + 16 + pg];
            float4 xa2 = st4[(c+2)*32 + pg],      xb2 = st4[(c+2)*32 + 16 + pg];
            float4 xa3 = st4[(c+3)*32 + pg],      xb3 = st4[(c+3)*32 + 16 + pg];
            #pragma unroll
            for (int j = 0; j < 4; ++j) {
                float4 w = W4[(o0+j)*16 + (c>>2)];
                fma4(&acc[j][0], w, xa0,xa1,xa2,xa3);
                fma4(&acc[j][4], w, xb0,xb1,xb2,xb3);
            }
        }
        float4* pre4 = (float4*)pre;
        #pragma unroll
        for (int j = 0; j < 4; ++j) {
            float bs = bpre[o0+j];
            float4 v0 = make_float4(acc[j][0]+bs, acc[j][1]+bs, acc[j][2]+bs, acc[j][3]+bs);
            float4 v1 = make_float4(acc[j][4]+bs, acc[j][5]+bs, acc[j][6]+bs, acc[j][7]+bs);
            pre4[(size_t)(b*64 + o0+j)*16384 + (p0>>2) + pg]      = v0;
            pre4[(size_t)(b*64 + o0+j)*16384 + (p0>>2) + 16 + pg] = v1;
            float s = v0.x+v0.y+v0.z+v0.w + v1.x+v1.y+v1.z+v1.w;
            s += __shfl_xor(s,1); s += __shfl_xor(s,2);
            s += __shfl_xor(s,4); s += __shfl_xor(s,8);
            if (pg == 0) atomicAdd(&pooled_part[slot*256 + b*64 + o0 + j], s);
        }
    }

    // ---- qkv conv (192x64): og owns 12 outs, 2 chunks of 6 -> acc[6][8]
    #pragma unroll
    for (int chk = 0; chk < 2; ++chk) {
        const int o0 = og*12 + chk*6;
        float acc[6][8];
        #pragma unroll
        for (int j=0;j<6;++j)
            #pragma unroll
            for (int k=0;k<8;++k) acc[j][k]=0.f;
        const float4* W4 = (const float4*)Wqkv;
        #pragma unroll 2
        for (int c = 0; c < 64; c += 4) {
            float4 xa0 = st4[(64+c+0)*32 + pg],   xb0 = st4[(64+c+0)*32 + 16 + pg];
            float4 xa1 = st4[(64+c+1)*32 + pg],   xb1 = st4[(64+c+1)*32 + 16 + pg];
            float4 xa2 = st4[(64+c+2)*32 + pg],   xb2 = st4[(64+c+2)*32 + 16 + pg];
            float4 xa3 = st4[(64+c+3)*32 + pg],   xb3 = st4[(64+c+3)*32 + 16 + pg];
            #pragma unroll
            for (int j = 0; j < 6; ++j) {
                float4 w = W4[(o0+j)*16 + (c>>2)];
                fma4(&acc[j][0], w, xa0,xa1,xa2,xa3);
                fma4(&acc[j][4], w, xb0,xb1,xb2,xb3);
            }
        }
        float4* qkv4 = (float4*)qkv;
        #pragma unroll
        for (int j = 0; j < 6; ++j) {
            qkv4[(size_t)(b*192 + o0+j)*16384 + (p0>>2) + pg] =
                make_float4(acc[j][0],acc[j][1],acc[j][2],acc[j][3]);
            qkv4[(size_t)(b*192 + o0+j)*16384 + (p0>>2) + 16 + pg] =
                make_float4(acc[j][4],acc[j][5],acc[j][6],acc[j][7]);
        }
    }

    // ---- gate hidden (32x64): og owns 2 outs -> acc[2][8], held across barrier
    {
        const int o0 = og*2;
        float acc[2][8];
        #pragma unroll
        for (int j=0;j<2;++j)
            #pragma unroll
            for (int k=0;k<8;++k) acc[j][k]=0.f;
        const float4* W4 = (const float4*)Wg1;
        for (int c = 0; c < 64; c += 4) {
            float4 xa0 = st4[(64+c+0)*32 + pg],   xb0 = st4[(64+c+0)*32 + 16 + pg];
            float4 xa1 = st4[(64+c+1)*32 + pg],   xb1 = st4[(64+c+1)*32 + 16 + pg];
            float4 xa2 = st4[(64+c+2)*32 + pg],   xb2 = st4[(64+c+2)*32 + 16 + pg];
            float4 xa3 = st4[(64+c+3)*32 + pg],   xb3 = st4[(64+c+3)*32 + 16 + pg];
            #pragma unroll
            for (int j = 0; j < 2; ++j) {
                float4 w = W4[(o0+j)*16 + (c>>2)];
                fma4(&acc[j][0], w, xa0,xa1,xa2,xa3);
                fma4(&acc[j][4], w, xb0,xb1,xb2,xb3);
            }
        }
        __syncthreads();   // ALL pt reads complete before ht overwrites st
        #pragma unroll
        for (int j = 0; j < 2; ++j) {
            float bs = bg1[o0+j];
            #pragma unroll
            for (int k = 0; k < 4; ++k) {
                ht[(o0+j)*128 + pg*4 + k]      = fmaxf(acc[j][k]+bs,   0.0f);
                ht[(o0+j)*128 + 64 + pg*4 + k] = fmaxf(acc[j][4+k]+bs, 0.0f);
            }
        }
    }
    __syncthreads();

    // ---- gate scalar: 128 px, 2 waves, wave-reduce + atomic each
    if (t < 128) {
        float g = bg2[0];
        #pragma unroll
        for (int c = 0; c < 32; ++c) g += wg2[c]*ht[c*128 + t];
        g = sgm(g);
        g += __shfl_xor(g,1);  g += __shfl_xor(g,2);  g += __shfl_xor(g,4);
        g += __shfl_xor(g,8);  g += __shfl_xor(g,16); g += __shfl_xor(g,32);
        if ((t & 63) == 0) atomicAdd(&gate_part[slot], g);
    }
}

// ---------------------------------------------------------------------------
// K2: pooled -> cw, gate mean -> kdyn. single block.
// ---------------------------------------------------------------------------
__global__ void k2_small(const float* __restrict__ pooled_part,
                         const float* __restrict__ gate_part,
                         const float* __restrict__ w1, const float* __restrict__ b1,
                         const float* __restrict__ w2, const float* __restrict__ b2,
                         float* __restrict__ cw, float* __restrict__ kdyn)
{
    __shared__ float pl[256];
    const int t = threadIdx.x;
    float s = 0.f;
    for (int sl = 0; sl < 64; ++sl) s += pooled_part[sl*256 + t];
    pl[t] = s * (1.0f/65536.0f);
    __syncthreads();
    const int b = t >> 6, g = (t >> 3) & 7, c = t & 7;
    float h0 = b1[g*2+0], h1 = b1[g*2+1];
    #pragma unroll
    for (int cc = 0; cc < 8; ++cc) {
        float p = pl[b*64 + g*8 + cc];
        h0 += p*w1[g*16 + 0*8 + cc];
        h1 += p*w1[g*16 + 1*8 + cc];
    }
    h0 = fmaxf(h0, 0.f); h1 = fmaxf(h1, 0.f);
    cw[t] = sgm(h0*w2[g*16 + c*2 + 0] + h1*w2[g*16 + c*2 + 1] + b2[g*8+c]);
    if (t == 0) {
        float gs = 0.f;
        for (int sl = 0; sl < 64; ++sl) gs += gate_part[sl];
        float kd = floorf(8.0f * (gs * (1.0f/262144.0f)));
        *kdyn = fminf(fmaxf(kd, 1.0f), 8.0f);
    }
}

// ---------------------------------------------------------------------------
// K4: depthwise 3x3 + FUSED group-gate resp sums (was k3).
// Block = (b, h, 8-row band). In-loop wave-reduced Gram/norm accumulation
// (no S[64] -> no spill), double-buffered LDS, (256,3).
// R9 fusion: block already owns group g==h and rows r0..r0+7; the resp
// partial sum for thr reads 64 KB of L3-resident `pre` per block and adds
// ~70 exp/thread -- absorbed into k4's idle memory/VALU gaps, eliminating
// the standalone 67 MB k3 pass (~55 us). Requires launch after k2 (cw).
// ---------------------------------------------------------------------------
#define K4_ROWSTRIDE 264            // 4 pad | 256 data | 4 pad (floats)
#define K4_BUF (10*K4_ROWSTRIDE)    // 10 halo rows

__global__ __launch_bounds__(256,3) void k4_dw(
    const float* __restrict__ qkv, const float* __restrict__ dww,
    const float* __restrict__ pre, const float* __restrict__ cw,
    const float* __restrict__ sw,  const float* __restrict__ sb,
    float* __restrict__ v, float* __restrict__ Sg, float* __restrict__ sumsq,
    float* __restrict__ thr_sum)
{
    __shared__ float sh[2*K4_BUF];  // 21120 B

    const int t    = threadIdx.x;
    const int b    = blockIdx.x >> 8;         // 256 blocks / batch
    const int h    = (blockIdx.x >> 5) & 7;
    const int band = blockIdx.x & 31;
    const int r0   = band * 8;
    const int lr   = t >> 5;                  // output row 0..7
    const int c0   = (t & 31) * 4;            // group0 cols c0..c0+3; group1 +128
    const int lane = t & 63;

    // edge columns (global col -1 and 256) are always zero; init once per buffer
    if (t < 40) {
        int bufi = t / 20, r = (t % 20) >> 1, side = t & 1;
        sh[bufi*K4_BUF + r*K4_ROWSTRIDE + (side ? 260 : 3)] = 0.0f;
    }

    float4 reg[3];

    auto issue_loads = [&](int ch) {
        const float4* base = (const float4*)(qkv + (size_t)(b*192 + ch)*HWN);
        #pragma unroll
        for (int j = 0; j < 3; ++j) {
            int i = t + 256*j;
            float4 val = make_float4(0.f,0.f,0.f,0.f);
            if (i < 640) {
                int row = i >> 6, col4 = i & 63;
                int gy = r0 - 1 + row;
                if (gy >= 0 && gy < 256) val = base[gy*64 + col4];
            }
            reg[j] = val;
        }
    };

    auto write_lds = [&](float* buf) {
        #pragma unroll
        for (int j = 0; j < 3; ++j) {
            int i = t + 256*j;
            if (i < 640) {
                int row = i >> 6, col4 = i & 63;
                *(float4*)&buf[row*K4_ROWSTRIDE + 4 + col4*4] = reg[j];
            }
        }
    };

    auto conv8 = [&](const float* buf, const float* __restrict__ w9, float out[8]) {
        #pragma unroll
        for (int g = 0; g < 2; ++g) {
            const int cc = c0 + g*128;
            float a0=0.f, a1=0.f, a2=0.f, a3=0.f;
            #pragma unroll
            for (int rr = 0; rr < 3; ++rr) {
                const float* row = &buf[(lr+rr)*K4_ROWSTRIDE + 4 + cc];
                float4 m = *(const float4*)row;
                float l = row[-1], r = row[4];
                float w0 = w9[rr*3+0], w1 = w9[rr*3+1], w2 = w9[rr*3+2];
                a0 = fmaf(w0,l,   fmaf(w1,m.x, fmaf(w2,m.y, a0)));
                a1 = fmaf(w0,m.x, fmaf(w1,m.y, fmaf(w2,m.z, a1)));
                a2 = fmaf(w0,m.y, fmaf(w1,m.z, fmaf(w2,m.w, a2)));
                a3 = fmaf(w0,m.z, fmaf(w1,m.w, fmaf(w2,r,   a3)));
            }
            out[g*4+0]=a0; out[g*4+1]=a1; out[g*4+2]=a2; out[g*4+3]=a3;
        }
    };

    auto wsum = [&](float val) {
        val += __shfl_xor(val,1);  val += __shfl_xor(val,2);  val += __shfl_xor(val,4);
        val += __shfl_xor(val,8);  val += __shfl_xor(val,16); val += __shfl_xor(val,32);
        return val;
    };

    float dq[8][8];

    float* sq_q = &sumsq[b*128 + h*8];
    float* sq_k = &sumsq[b*128 + 64 + h*8];
    float* Sgb  = &Sg[(size_t)(b*8+h)*64];

    issue_loads(h*8 + 0);   // first q channel

    // ---- Q channels: conv + immediate ||q||^2 partial
    #pragma unroll
    for (int ch = 0; ch < 8; ++ch) {
        float* buf = sh + (ch & 1)*K4_BUF;
        write_lds(buf);
        issue_loads(ch < 7 ? (h*8 + ch + 1) : (64 + h*8));
        __syncthreads();
        conv8(buf, dww + (h*8 + ch)*9, dq[ch]);
        float ss = 0.f;
        #pragma unroll
        for (int p = 0; p < 8; ++p) ss = fmaf(dq[ch][p], dq[ch][p], ss);
        ss = wsum(ss);
        if (lane == 0) atomicAdd(&sq_q[ch], ss);
    }

    // ---- K channels: conv + Gram row + ||k||^2, all reduced in-loop
    #pragma unroll
    for (int ch = 0; ch < 8; ++ch) {
        float* buf = sh + (ch & 1)*K4_BUF;
        write_lds(buf);
        issue_loads(ch < 7 ? (64 + h*8 + ch + 1) : (128 + h*8));
        __syncthreads();
        float dk[8];
        conv8(buf, dww + (64 + h*8 + ch)*9, dk);
        float ss = 0.f;
        #pragma unroll
        for (int p = 0; p < 8; ++p) ss = fmaf(dk[p], dk[p], ss);
        ss = wsum(ss);
        if (lane == 0) atomicAdd(&sq_k[ch], ss);
        #pragma unroll
        for (int c = 0; c < 8; ++c) {
            float acc = 0.f;
            #pragma unroll
            for (int p = 0; p < 8; ++p) acc = fmaf(dq[c][p], dk[p], acc);
            acc = wsum(acc);
            if (lane == 0) atomicAdd(&Sgb[c*8 + ch], acc);
        }
    }

    // ---- V channels (compute + store only)
    #pragma unroll
    for (int ch = 0; ch < 8; ++ch) {
        float* buf = sh + (ch & 1)*K4_BUF;
        write_lds(buf);
        if (ch < 7) issue_loads(128 + h*8 + ch + 1);
        __syncthreads();
        float dv[8];
        conv8(buf, dww + (128 + h*8 + ch)*9, dv);
        float* vb = v + (size_t)(b*64 + h*8 + ch)*HWN + (r0 + lr)*256;
        *(float4*)&vb[c0]       = make_float4(dv[0],dv[1],dv[2],dv[3]);
        *(float4*)&vb[c0 + 128] = make_float4(dv[4],dv[5],dv[6],dv[7]);
    }

    // ---- fused k3: resp partial sums for thr (this block's group g == h)
    {
        float cwr[8], swr[8];
        #pragma unroll
        for (int c = 0; c < 8; ++c) {
            cwr[c] = cw[b*64 + h*8 + c];
            swr[c] = sw[h*8 + c];
        }
        const float sbg = sb[h];
        float rs = 0.f;
        const float* preb = pre + (size_t)(b*64 + h*8)*HWN + (size_t)(r0 + lr)*256;
        #pragma unroll
        for (int g2 = 0; g2 < 2; ++g2) {
            const int cc = c0 + g2*128;
            float xc[8][4];
            float spa0 = sbg, spa1 = sbg, spa2 = sbg, spa3 = sbg;
            #pragma unroll
            for (int c = 0; c < 8; ++c) {
                float4 xv = *(const float4*)&preb[(size_t)c*HWN + cc];
                xc[c][0] = xv.x*cwr[c]; xc[c][1] = xv.y*cwr[c];
                xc[c][2] = xv.z*cwr[c]; xc[c][3] = xv.w*cwr[c];
                spa0 = fmaf(xc[c][0], swr[c], spa0);
                spa1 = fmaf(xc[c][1], swr[c], spa1);
                spa2 = fmaf(xc[c][2], swr[c], spa2);
                spa3 = fmaf(xc[c][3], swr[c], spa3);
            }
            float sp0 = sgm(spa0), sp1 = sgm(spa1), sp2 = sgm(spa2), sp3 = sgm(spa3);
            #pragma unroll
            for (int c = 0; c < 8; ++c) {
                rs += sgm(xc[c][0]*sp0);
                rs += sgm(xc[c][1]*sp1);
                rs += sgm(xc[c][2]*sp2);
                rs += sgm(xc[c][3]*sp3);
            }
        }
        rs = wsum(rs);
        if (lane == 0) atomicAdd(&thr_sum[b*8 + h], rs);
    }
}

// ---------------------------------------------------------------------------
// K6: finalize attention weights and thr. single block.
// ---------------------------------------------------------------------------
__global__ void k6_attn(const float* __restrict__ Sg, const float* __restrict__ sumsq,
                        const float* __restrict__ temp, const float* __restrict__ kdynp,
                        const float* __restrict__ thr_sum, const float* __restrict__ scales,
                        float* __restrict__ A, float* __restrict__ thr)
{
    const int t = threadIdx.x;
    if (t < 32) thr[t] = thr_sum[t] * (1.0f/(8.0f*65536.0f));
    const int b = t >> 6, h = (t >> 3) & 7, c = t & 7;
    const float kd = *kdynp;
    const float ssum = scales[0]+scales[1]+scales[2]+scales[3];
    const float nq = fmaxf(sqrtf(sumsq[b*128 + h*8 + c]), 1e-12f);
    const float tv = temp[h];
    const float* Srow = Sg + (size_t)(b*8+h)*64 + c*8;
    float a[8];
    #pragma unroll
    for (int d = 0; d < 8; ++d) {
        float nk = fmaxf(sqrtf(sumsq[b*128 + 64 + h*8 + d]), 1e-12f);
        a[d] = Srow[d] / (nq*nk) * tv;
    }
    bool keep[8];
    #pragma unroll
    for (int d = 0; d < 8; ++d) {
        int r = 0;
        #pragma unroll
        for (int e = 0; e < 8; ++e)
            r += (a[e] > a[d]) || (a[e] == a[d] && e < d);
        keep[d] = ((float)r < kd);
    }
    float m = -INFINITY;
    #pragma unroll
    for (int d = 0; d < 8; ++d) if (keep[d]) m = fmaxf(m, a[d]);
    float ex[8]; float sum = 0.f;
    #pragma unroll
    for (int d = 0; d < 8; ++d) { ex[d] = keep[d] ? expf(a[d]-m) : 0.f; sum += ex[d]; }
    const float inv = ssum / sum;
    #pragma unroll
    for (int d = 0; d < 8; ++d)
        A[(size_t)(b*8+h)*64 + c*8 + d] = ex[d]*inv;
}

// ---------------------------------------------------------------------------
// K7: mask path + post conv + residual + attn@v + proj_out, fused epilogue.
// R8 structure (8 px/thread, 128 px/block, in-place pr/vt, no ft). (256,2).
// ---------------------------------------------------------------------------
__global__ __launch_bounds__(256,2) void k7_final(
    const float* __restrict__ pre, const float* __restrict__ lb, const float* __restrict__ v,
    const float* __restrict__ cw,  const float* __restrict__ thr,
    const float* __restrict__ sw,  const float* __restrict__ sb,
    const float* __restrict__ A,
    const float* __restrict__ Wpost, const float* __restrict__ bpost,
    const float* __restrict__ Wout,  float* __restrict__ out)
{
    __shared__ float pr[64*128];   // 32 KB: pre -> masked -> post+lb result
    __shared__ float vt[64*128];   // 32 KB: v   -> attn@v result
    float4* pr4 = (float4*)pr;
    float4* vt4 = (float4*)vt;

    const int t   = threadIdx.x;
    const int blk = blockIdx.x;
    const int b   = blk >> 9;            // 512 blocks per batch
    const int p0  = (blk & 511) << 7;    // 128 px / block
    const int pg  = t & 15;              // px pg*4..+3 and 64+pg*4..+3
    const int og  = t >> 4;

    const float4* pre4g = (const float4*)pre;
    const float4* v4g   = (const float4*)v;
    #pragma unroll
    for (int i = 0; i < 8; ++i) {
        int idx = t + 256*i;
        int c = idx >> 5, q = idx & 31;
        size_t gi = (size_t)(b*64 + c)*16384 + (p0>>2) + q;
        pr4[c*32+q] = pre4g[gi];
        vt4[c*32+q] = v4g[gi];
    }
    __syncthreads();

    // ---- mask path, in place on pr: 8 groups x 128 px = 1024 tasks, 4/thread
    #pragma unroll
    for (int s = 0; s < 4; ++s) {
        int task = t + 256*s;
        int g = task >> 7, px = task & 127;
        float xc[8], xv[8];
        float spa = sb[g];
        #pragma unroll
        for (int c = 0; c < 8; ++c) {
            xv[c] = pr[(g*8+c)*128 + px];
            xc[c] = xv[c]*cw[b*64 + g*8 + c];
            spa += xc[c]*sw[g*8 + c];
        }
        float sp = sgm(spa);
        float th = thr[b*8 + g];
        #pragma unroll
        for (int c = 0; c < 8; ++c) {
            float resp = sgm(xc[c]*sp);
            float mask = resp > th ? 1.0f : resp;
            pr[(g*8+c)*128 + px] = xv[c]*mask;
        }
    }
    __syncthreads();

    // ---- post conv (64x64) + bias + lb residual -> registers (acc[4][8])
    float postv[4][8];
    {
        const int o0 = og*4;
        float acc[4][8];
        #pragma unroll
        for (int j=0;j<4;++j)
            #pragma unroll
            for (int k=0;k<8;++k) acc[j][k]=0.f;
        const float4* W4 = (const float4*)Wpost;
        #pragma unroll 2
        for (int c = 0; c < 64; c += 4) {
            float4 xa0 = pr4[(c+0)*32 + pg],      xb0 = pr4[(c+0)*32 + 16 + pg];
            float4 xa1 = pr4[(c+1)*32 + pg],      xb1 = pr4[(c+1)*32 + 16 + pg];
            float4 xa2 = pr4[(c+2)*32 + pg],      xb2 = pr4[(c+2)*32 + 16 + pg];
            float4 xa3 = pr4[(c+3)*32 + pg],      xb3 = pr4[(c+3)*32 + 16 + pg];
            #pragma unroll
            for (int j = 0; j < 4; ++j) {
                float4 w = W4[(o0+j)*16 + (c>>2)];
                fma4(&acc[j][0], w, xa0,xa1,xa2,xa3);
                fma4(&acc[j][4], w, xb0,xb1,xb2,xb3);
            }
        }
        const float4* lb4 = (const float4*)lb;
        #pragma unroll
        for (int j = 0; j < 4; ++j) {
            float bs = bpost[o0+j];
            float4 l0 = lb4[(size_t)(b*64 + o0+j)*16384 + (p0>>2) + pg];
            float4 l1 = lb4[(size_t)(b*64 + o0+j)*16384 + (p0>>2) + 16 + pg];
            postv[j][0]=acc[j][0]+bs+l0.x; postv[j][1]=acc[j][1]+bs+l0.y;
            postv[j][2]=acc[j][2]+bs+l0.z; postv[j][3]=acc[j][3]+bs+l0.w;
            postv[j][4]=acc[j][4]+bs+l1.x; postv[j][5]=acc[j][5]+bs+l1.y;
            postv[j][6]=acc[j][6]+bs+l1.z; postv[j][7]=acc[j][7]+bs+l1.w;
        }
    }

    // ---- attn @ v -> registers (acc[4][8])
    float attv[4][8];
    {
        const int ch0 = og*4;
        #pragma unroll
        for (int j = 0; j < 4; ++j) {
            int ch = ch0 + j;
            int hh = ch >> 3, c = ch & 7;
            const float* Ar = A + (size_t)(b*8+hh)*64 + c*8;
            float a0=0.f,a1=0.f,a2=0.f,a3=0.f,a4=0.f,a5=0.f,a6=0.f,a7=0.f;
            #pragma unroll
            for (int d = 0; d < 8; ++d) {
                float av = Ar[d];
                float4 v0 = vt4[(hh*8+d)*32 + pg];
                float4 v1 = vt4[(hh*8+d)*32 + 16 + pg];
                a0 += av*v0.x; a1 += av*v0.y; a2 += av*v0.z; a3 += av*v0.w;
                a4 += av*v1.x; a5 += av*v1.y; a6 += av*v1.z; a7 += av*v1.w;
            }
            attv[j][0]=a0; attv[j][1]=a1; attv[j][2]=a2; attv[j][3]=a3;
            attv[j][4]=a4; attv[j][5]=a5; attv[j][6]=a6; attv[j][7]=a7;
        }
    }
    __syncthreads();   // all pr/vt reads complete

    // ---- write back in place: vt <- attn half (ch 0..63), pr <- post half
    {
        const int o0 = og*4;
        #pragma unroll
        for (int j = 0; j < 4; ++j) {
            vt4[(o0+j)*32 + pg]      = make_float4(attv[j][0],attv[j][1],attv[j][2],attv[j][3]);
            vt4[(o0+j)*32 + 16 + pg] = make_float4(attv[j][4],attv[j][5],attv[j][6],attv[j][7]);
            pr4[(o0+j)*32 + pg]      = make_float4(postv[j][0],postv[j][1],postv[j][2],postv[j][3]);
            pr4[(o0+j)*32 + 16 + pg] = make_float4(postv[j][4],postv[j][5],postv[j][6],postv[j][7]);
        }
    }
    __syncthreads();

    // ---- out conv (128x128): ch 0..63 = vt (attn), 64..127 = pr (post)
    {
        const int o0 = og*8;
        float acc[8][8];
        #pragma unroll
        for (int j=0;j<8;++j)
            #pragma unroll
            for (int k=0;k<8;++k) acc[j][k]=0.f;
        const float4* W4 = (const float4*)Wout;
        #pragma unroll 2
        for (int c = 0; c < 64; c += 4) {
            float4 xa0 = vt4[(c+0)*32 + pg],      xb0 = vt4[(c+0)*32 + 16 + pg];
            float4 xa1 = vt4[(c+1)*32 + pg],      xb1 = vt4[(c+1)*32 + 16 + pg];
            float4 xa2 = vt4[(c+2)*32 + pg],      xb2 = vt4[(c+2)*32 + 16 + pg];
            float4 xa3 = vt4[(c+3)*32 + pg],      xb3 = vt4[(c+3)*32 + 16 + pg];
            #pragma unroll
            for (int j = 0; j < 8; ++j) {
                float4 w = W4[(o0+j)*32 + (c>>2)];
                fma4(&acc[j][0], w, xa0,xa1,xa2,xa3);
                fma4(&acc[j][4], w, xb0,xb1,xb2,xb3);
            }
        }
        #pragma unroll 2
        for (int c = 0; c < 64; c += 4) {
            float4 xa0 = pr4[(c+0)*32 + pg],      xb0 = pr4[(c+0)*32 + 16 + pg];
            float4 xa1 = pr4[(c+1)*32 + pg],      xb1 = pr4[(c+1)*32 + 16 + pg];
            float4 xa2 = pr4[(c+2)*32 + pg],      xb2 = pr4[(c+2)*32 + 16 + pg];
            float4 xa3 = pr4[(c+3)*32 + pg],      xb3 = pr4[(c+3)*32 + 16 + pg];
            #pragma unroll
            for (int j = 0; j < 8; ++j) {
                float4 w = W4[(o0+j)*32 + 16 + (c>>2)];
                fma4(&acc[j][0], w, xa0,xa1,xa2,xa3);
                fma4(&acc[j][4], w, xb0,xb1,xb2,xb3);
            }
        }
        float4* out4 = (float4*)out;
        #pragma unroll
        for (int j = 0; j < 8; ++j) {
            out4[(size_t)(b*128 + o0+j)*16384 + (p0>>2) + pg] =
                make_float4(acc[j][0],acc[j][1],acc[j][2],acc[j][3]);
            out4[(size_t)(b*128 + o0+j)*16384 + (p0>>2) + 16 + pg] =
                make_float4(acc[j][4],acc[j][5],acc[j][6],acc[j][7]);
        }
    }
}

// ---------------------------------------------------------------------------
extern "C" void kernel_launch(void* const* d_in, const int* in_sizes, int n_in,
                              void* d_out, int out_size, void* d_ws, size_t ws_size,
                              hipStream_t stream)
{
    const float* x     = (const float*)d_in[0];
    const float* Wp    = (const float*)d_in[1];
    const float* Wpre  = (const float*)d_in[2];
    const float* bpre  = (const float*)d_in[3];
    const float* w1    = (const float*)d_in[4];
    const float* b1    = (const float*)d_in[5];
    const float* w2    = (const float*)d_in[6];
    const float* b2    = (const float*)d_in[7];
    const float* sw    = (const float*)d_in[8];
    const float* sb    = (const float*)d_in[9];
    const float* Wpost = (const float*)d_in[10];
    const float* bpost = (const float*)d_in[11];
    const float* Wqkv  = (const float*)d_in[12];
    const float* dww   = (const float*)d_in[13];
    const float* Wg1   = (const float*)d_in[14];
    const float* bg1   = (const float*)d_in[15];
    const float* wg2   = (const float*)d_in[16];
    const float* bg2   = (const float*)d_in[17];
    const float* temp  = (const float*)d_in[18];
    const float* scales= (const float*)d_in[19];
    const float* Wout  = (const float*)d_in[20];
    float* out = (float*)d_out;

    float* ws = (float*)d_ws;
    float* pooled_part = ws;                 // 16384
    float* gate_part   = ws + 16384;         // 64
    float* thr_sum     = ws + 16448;         // 32
    float* sumsq       = ws + 16480;         // 512
    float* Sg          = ws + 16992;         // 2048
    float* cw          = ws + 19040;         // 256
    float* kdyn        = ws + 19296;         // 1
    float* thr         = ws + 19328;         // 32
    float* A           = ws + 19360;         // 2048

    float* lb  = ws + 32768;
    float* pre = lb  + 16777216;
    float* qkv = pre + 16777216;
    float* v   = qkv + 50331648;

    hipMemsetAsync(ws, 0, (size_t)19040*sizeof(float), stream);

    k1_proj <<<2048, 256, 0, stream>>>(x, Wp, Wpre, bpre, Wqkv, Wg1, bg1, wg2, bg2,
                                       lb, pre, qkv, pooled_part, gate_part);
    k2_small<<<1,    256, 0, stream>>>(pooled_part, gate_part, w1, b1, w2, b2, cw, kdyn);
    k4_dw   <<<1024, 256, 0, stream>>>(qkv, dww, pre, cw, sw, sb, v, Sg, sumsq, thr_sum);
    k6_attn <<<1,    256, 0, stream>>>(Sg, sumsq, temp, kdyn, thr_sum, scales, A, thr);
    k7_final<<<2048, 256, 0, stream>>>(pre, lb, v, cw, thr, sw, sb, A,
                                       Wpost, bpost, Wout, out);
}

// Round 10
// 736.809 us; speedup vs baseline: 1.6830x; 1.0816x over previous
//
#include <hip/hip_runtime.h>
#include <math.h>

#define HWN 65536

typedef __attribute__((ext_vector_type(8))) short bf16x8;
typedef __attribute__((ext_vector_type(4))) float f32x4;

__device__ __forceinline__ float sgm(float x){ return 1.0f/(1.0f+expf(-x)); }

__device__ __forceinline__ unsigned pack_hi2(float a, float b){
    // [b_hi16 : a_hi16] -- two truncated bf16s, low half = a
    return (__float_as_uint(b) & 0xFFFF0000u) | (__float_as_uint(a) >> 16);
}

__device__ __forceinline__ void fma4(float acc[4], const float4 w,
                                     const float4 x0, const float4 x1,
                                     const float4 x2, const float4 x3){
    acc[0] += w.x*x0.x + w.y*x1.x + w.z*x2.x + w.w*x3.x;
    acc[1] += w.x*x0.y + w.y*x1.y + w.z*x2.y + w.w*x3.y;
    acc[2] += w.x*x0.z + w.y*x1.z + w.z*x2.z + w.w*x3.z;
    acc[3] += w.x*x0.w + w.y*x1.w + w.z*x2.w + w.w*x3.w;
}

// ---------------------------------------------------------------------------
// K1: input_proj + lb store + lgce_pre (+pooled partials) + qkv + gate.
// R7/R9 structure (8 px/thread, 128 px/block, unroll 2): 313 us, VALU 63%,
// VGPR 128. Occupancy falsified; SGPR-broadcast falsified.
// launch_bounds(256,2): NEVER raise arg2 (R3: (256,4) -> VGPR 64 -> 4 GB spill).
// ---------------------------------------------------------------------------
__global__ __launch_bounds__(256,2) void k1_proj(
    const float* __restrict__ x,   const float* __restrict__ Wp,
    const float* __restrict__ Wpre,const float* __restrict__ bpre,
    const float* __restrict__ Wqkv,
    const float* __restrict__ Wg1, const float* __restrict__ bg1,
    const float* __restrict__ wg2, const float* __restrict__ bg2,
    float* __restrict__ lb, float* __restrict__ pre, float* __restrict__ qkv,
    float* __restrict__ pooled_part, float* __restrict__ gate_part)
{
    __shared__ float st[128*128];         // 64 KB: x staging -> proj output -> ht alias
    float4* st4 = (float4*)st;
    float*  ht  = st;                     // 32x128 floats = 16 KB, used after barrier

    const int t    = threadIdx.x;
    const int blk  = blockIdx.x;
    const int b    = blk >> 9;            // 512 blocks per batch
    const int p0   = (blk & 511) << 7;    // 128 px / block
    const int pg   = t & 15;              // pixel group: px pg*4..+3 and 64+pg*4..+3
    const int og   = t >> 4;              // output group
    const int slot = blk & 63;

    const float4* x4 = (const float4*)x;

    // ---- stage all of x (one burst)
    #pragma unroll
    for (int i = 0; i < 16; ++i) {
        int idx = t + 256*i;
        int c = idx >> 5, q = idx & 31;
        st4[c*32 + q] = x4[(size_t)(b*128 + c)*16384 + (p0>>2) + q];
    }
    __syncthreads();

    // ---- proj (128x128): og owns outs og*8..+7, 8 px each -> acc[8][8]
    {
        const int o0 = og*8;
        float acc[8][8];
        #pragma unroll
        for (int j=0;j<8;++j)
            #pragma unroll
            for (int k=0;k<8;++k) acc[j][k]=0.f;
        const float4* W4 = (const float4*)Wp;
        #pragma unroll 2
        for (int c = 0; c < 128; c += 4) {
            float4 xa0 = st4[(c+0)*32 + pg],      xb0 = st4[(c+0)*32 + 16 + pg];
            float4 xa1 = st4[(c+1)*32 + pg],      xb1 = st4[(c+1)*32 + 16 + pg];
            float4 xa2 = st4[(c+2)*32 + pg],      xb2 = st4[(c+2)*32 + 16 + pg];
            float4 xa3 = st4[(c+3)*32 + pg],      xb3 = st4[(c+3)*32 + 16 + pg];
            #pragma unroll
            for (int j = 0; j < 8; ++j) {
                float4 w = W4[(o0+j)*32 + (c>>2)];
                fma4(&acc[j][0], w, xa0,xa1,xa2,xa3);
                fma4(&acc[j][4], w, xb0,xb1,xb2,xb3);
            }
        }
        __syncthreads();   // every thread done READING x before any overwrite

        #pragma unroll
        for (int j = 0; j < 8; ++j) {
            st4[(o0+j)*32 + pg]      = make_float4(acc[j][0],acc[j][1],acc[j][2],acc[j][3]);
            st4[(o0+j)*32 + 16 + pg] = make_float4(acc[j][4],acc[j][5],acc[j][6],acc[j][7]);
        }
        if (og < 8) {      // lb = proj channels 0..63, straight from registers
            float4* lb4 = (float4*)lb;
            #pragma unroll
            for (int j = 0; j < 8; ++j) {
                lb4[(size_t)(b*64 + o0+j)*16384 + (p0>>2) + pg] =
                    make_float4(acc[j][0],acc[j][1],acc[j][2],acc[j][3]);
                lb4[(size_t)(b*64 + o0+j)*16384 + (p0>>2) + 16 + pg] =
                    make_float4(acc[j][4],acc[j][5],acc[j][6],acc[j][7]);
            }
        }
    }
    __syncthreads();       // proj output ready

    // ---- pre conv (64x64): og owns 4 outs -> acc[4][8]; + pooled partials
    {
        const int o0 = og*4;
        float acc[4][8];
        #pragma unroll
        for (int j=0;j<4;++j)
            #pragma unroll
            for (int k=0;k<8;++k) acc[j][k]=0.f;
        const float4* W4 = (const float4*)Wpre;
        #pragma unroll 2
        for (int c = 0; c < 64; c += 4) {
            float4 xa0 = st4[(c+0)*32 + pg],      xb0 = st4[(c+0)*32 + 16 + pg];
            float4 xa1 = st4[(c+1)*32 + pg],      xb1 = st4[(c+1)*32 + 16 + pg];
            float4 xa2 = st4[(c+2)*32 + pg],      xb2 = st4[(c+2)*32 + 16 + pg];
            float4 xa3 = st4[(c+3)*32 + pg],      xb3 = st4[(c+3)*32 + 16 + pg];
            #pragma unroll
            for (int j = 0; j < 4; ++j) {
                float4 w = W4[(o0+j)*16 + (c>>2)];
                fma4(&acc[j][0], w, xa0,xa1,xa2,xa3);
                fma4(&acc[j][4], w, xb0,xb1,xb2,xb3);
            }
        }
        float4* pre4 = (float4*)pre;
        #pragma unroll
        for (int j = 0; j < 4; ++j) {
            float bs = bpre[o0+j];
            float4 v0 = make_float4(acc[j][0]+bs, acc[j][1]+bs, acc[j][2]+bs, acc[j][3]+bs);
            float4 v1 = make_float4(acc[j][4]+bs, acc[j][5]+bs, acc[j][6]+bs, acc[j][7]+bs);
            pre4[(size_t)(b*64 + o0+j)*16384 + (p0>>2) + pg]      = v0;
            pre4[(size_t)(b*64 + o0+j)*16384 + (p0>>2) + 16 + pg] = v1;
            float s = v0.x+v0.y+v0.z+v0.w + v1.x+v1.y+v1.z+v1.w;
            s += __shfl_xor(s,1); s += __shfl_xor(s,2);
            s += __shfl_xor(s,4); s += __shfl_xor(s,8);
            if (pg == 0) atomicAdd(&pooled_part[slot*256 + b*64 + o0 + j], s);
        }
    }

    // ---- qkv conv (192x64): og owns 12 outs, 2 chunks of 6 -> acc[6][8]
    #pragma unroll
    for (int chk = 0; chk < 2; ++chk) {
        const int o0 = og*12 + chk*6;
        float acc[6][8];
        #pragma unroll
        for (int j=0;j<6;++j)
            #pragma unroll
            for (int k=0;k<8;++k) acc[j][k]=0.f;
        const float4* W4 = (const float4*)Wqkv;
        #pragma unroll 2
        for (int c = 0; c < 64; c += 4) {
            float4 xa0 = st4[(64+c+0)*32 + pg],   xb0 = st4[(64+c+0)*32 + 16 + pg];
            float4 xa1 = st4[(64+c+1)*32 + pg],   xb1 = st4[(64+c+1)*32 + 16 + pg];
            float4 xa2 = st4[(64+c+2)*32 + pg],   xb2 = st4[(64+c+2)*32 + 16 + pg];
            float4 xa3 = st4[(64+c+3)*32 + pg],   xb3 = st4[(64+c+3)*32 + 16 + pg];
            #pragma unroll
            for (int j = 0; j < 6; ++j) {
                float4 w = W4[(o0+j)*16 + (c>>2)];
                fma4(&acc[j][0], w, xa0,xa1,xa2,xa3);
                fma4(&acc[j][4], w, xb0,xb1,xb2,xb3);
            }
        }
        float4* qkv4 = (float4*)qkv;
        #pragma unroll
        for (int j = 0; j < 6; ++j) {
            qkv4[(size_t)(b*192 + o0+j)*16384 + (p0>>2) + pg] =
                make_float4(acc[j][0],acc[j][1],acc[j][2],acc[j][3]);
            qkv4[(size_t)(b*192 + o0+j)*16384 + (p0>>2) + 16 + pg] =
                make_float4(acc[j][4],acc[j][5],acc[j][6],acc[j][7]);
        }
    }

    // ---- gate hidden (32x64): og owns 2 outs -> acc[2][8], held across barrier
    {
        const int o0 = og*2;
        float acc[2][8];
        #pragma unroll
        for (int j=0;j<2;++j)
            #pragma unroll
            for (int k=0;k<8;++k) acc[j][k]=0.f;
        const float4* W4 = (const float4*)Wg1;
        for (int c = 0; c < 64; c += 4) {
            float4 xa0 = st4[(64+c+0)*32 + pg],   xb0 = st4[(64+c+0)*32 + 16 + pg];
            float4 xa1 = st4[(64+c+1)*32 + pg],   xb1 = st4[(64+c+1)*32 + 16 + pg];
            float4 xa2 = st4[(64+c+2)*32 + pg],   xb2 = st4[(64+c+2)*32 + 16 + pg];
            float4 xa3 = st4[(64+c+3)*32 + pg],   xb3 = st4[(64+c+3)*32 + 16 + pg];
            #pragma unroll
            for (int j = 0; j < 2; ++j) {
                float4 w = W4[(o0+j)*16 + (c>>2)];
                fma4(&acc[j][0], w, xa0,xa1,xa2,xa3);
                fma4(&acc[j][4], w, xb0,xb1,xb2,xb3);
            }
        }
        __syncthreads();   // ALL pt reads complete before ht overwrites st
        #pragma unroll
        for (int j = 0; j < 2; ++j) {
            float bs = bg1[o0+j];
            #pragma unroll
            for (int k = 0; k < 4; ++k) {
                ht[(o0+j)*128 + pg*4 + k]      = fmaxf(acc[j][k]+bs,   0.0f);
                ht[(o0+j)*128 + 64 + pg*4 + k] = fmaxf(acc[j][4+k]+bs, 0.0f);
            }
        }
    }
    __syncthreads();

    // ---- gate scalar: 128 px, 2 waves, wave-reduce + atomic each
    if (t < 128) {
        float g = bg2[0];
        #pragma unroll
        for (int c = 0; c < 32; ++c) g += wg2[c]*ht[c*128 + t];
        g = sgm(g);
        g += __shfl_xor(g,1);  g += __shfl_xor(g,2);  g += __shfl_xor(g,4);
        g += __shfl_xor(g,8);  g += __shfl_xor(g,16); g += __shfl_xor(g,32);
        if ((t & 63) == 0) atomicAdd(&gate_part[slot], g);
    }
}

// ---------------------------------------------------------------------------
// K2: pooled -> cw, gate mean -> kdyn. single block.
// ---------------------------------------------------------------------------
__global__ void k2_small(const float* __restrict__ pooled_part,
                         const float* __restrict__ gate_part,
                         const float* __restrict__ w1, const float* __restrict__ b1,
                         const float* __restrict__ w2, const float* __restrict__ b2,
                         float* __restrict__ cw, float* __restrict__ kdyn)
{
    __shared__ float pl[256];
    const int t = threadIdx.x;
    float s = 0.f;
    for (int sl = 0; sl < 64; ++sl) s += pooled_part[sl*256 + t];
    pl[t] = s * (1.0f/65536.0f);
    __syncthreads();
    const int b = t >> 6, g = (t >> 3) & 7, c = t & 7;
    float h0 = b1[g*2+0], h1 = b1[g*2+1];
    #pragma unroll
    for (int cc = 0; cc < 8; ++cc) {
        float p = pl[b*64 + g*8 + cc];
        h0 += p*w1[g*16 + 0*8 + cc];
        h1 += p*w1[g*16 + 1*8 + cc];
    }
    h0 = fmaxf(h0, 0.f); h1 = fmaxf(h1, 0.f);
    cw[t] = sgm(h0*w2[g*16 + c*2 + 0] + h1*w2[g*16 + c*2 + 1] + b2[g*8+c]);
    if (t == 0) {
        float gs = 0.f;
        for (int sl = 0; sl < 64; ++sl) gs += gate_part[sl];
        float kd = floorf(8.0f * (gs * (1.0f/262144.0f)));
        *kdyn = fminf(fmaxf(kd, 1.0f), 8.0f);
    }
}

// ---------------------------------------------------------------------------
// K4: depthwise 3x3 + FUSED group-gate resp sums. See R9 notes.
// ---------------------------------------------------------------------------
#define K4_ROWSTRIDE 264            // 4 pad | 256 data | 4 pad (floats)
#define K4_BUF (10*K4_ROWSTRIDE)    // 10 halo rows

__global__ __launch_bounds__(256,3) void k4_dw(
    const float* __restrict__ qkv, const float* __restrict__ dww,
    const float* __restrict__ pre, const float* __restrict__ cw,
    const float* __restrict__ sw,  const float* __restrict__ sb,
    float* __restrict__ v, float* __restrict__ Sg, float* __restrict__ sumsq,
    float* __restrict__ thr_sum)
{
    __shared__ float sh[2*K4_BUF];  // 21120 B

    const int t    = threadIdx.x;
    const int b    = blockIdx.x >> 8;         // 256 blocks / batch
    const int h    = (blockIdx.x >> 5) & 7;
    const int band = blockIdx.x & 31;
    const int r0   = band * 8;
    const int lr   = t >> 5;                  // output row 0..7
    const int c0   = (t & 31) * 4;            // group0 cols c0..c0+3; group1 +128
    const int lane = t & 63;

    if (t < 40) {
        int bufi = t / 20, r = (t % 20) >> 1, side = t & 1;
        sh[bufi*K4_BUF + r*K4_ROWSTRIDE + (side ? 260 : 3)] = 0.0f;
    }

    float4 reg[3];

    auto issue_loads = [&](int ch) {
        const float4* base = (const float4*)(qkv + (size_t)(b*192 + ch)*HWN);
        #pragma unroll
        for (int j = 0; j < 3; ++j) {
            int i = t + 256*j;
            float4 val = make_float4(0.f,0.f,0.f,0.f);
            if (i < 640) {
                int row = i >> 6, col4 = i & 63;
                int gy = r0 - 1 + row;
                if (gy >= 0 && gy < 256) val = base[gy*64 + col4];
            }
            reg[j] = val;
        }
    };

    auto write_lds = [&](float* buf) {
        #pragma unroll
        for (int j = 0; j < 3; ++j) {
            int i = t + 256*j;
            if (i < 640) {
                int row = i >> 6, col4 = i & 63;
                *(float4*)&buf[row*K4_ROWSTRIDE + 4 + col4*4] = reg[j];
            }
        }
    };

    auto conv8 = [&](const float* buf, const float* __restrict__ w9, float out[8]) {
        #pragma unroll
        for (int g = 0; g < 2; ++g) {
            const int cc = c0 + g*128;
            float a0=0.f, a1=0.f, a2=0.f, a3=0.f;
            #pragma unroll
            for (int rr = 0; rr < 3; ++rr) {
                const float* row = &buf[(lr+rr)*K4_ROWSTRIDE + 4 + cc];
                float4 m = *(const float4*)row;
                float l = row[-1], r = row[4];
                float w0 = w9[rr*3+0], w1 = w9[rr*3+1], w2 = w9[rr*3+2];
                a0 = fmaf(w0,l,   fmaf(w1,m.x, fmaf(w2,m.y, a0)));
                a1 = fmaf(w0,m.x, fmaf(w1,m.y, fmaf(w2,m.z, a1)));
                a2 = fmaf(w0,m.y, fmaf(w1,m.z, fmaf(w2,m.w, a2)));
                a3 = fmaf(w0,m.z, fmaf(w1,m.w, fmaf(w2,r,   a3)));
            }
            out[g*4+0]=a0; out[g*4+1]=a1; out[g*4+2]=a2; out[g*4+3]=a3;
        }
    };

    auto wsum = [&](float val) {
        val += __shfl_xor(val,1);  val += __shfl_xor(val,2);  val += __shfl_xor(val,4);
        val += __shfl_xor(val,8);  val += __shfl_xor(val,16); val += __shfl_xor(val,32);
        return val;
    };

    float dq[8][8];

    float* sq_q = &sumsq[b*128 + h*8];
    float* sq_k = &sumsq[b*128 + 64 + h*8];
    float* Sgb  = &Sg[(size_t)(b*8+h)*64];

    issue_loads(h*8 + 0);   // first q channel

    // ---- Q channels
    #pragma unroll
    for (int ch = 0; ch < 8; ++ch) {
        float* buf = sh + (ch & 1)*K4_BUF;
        write_lds(buf);
        issue_loads(ch < 7 ? (h*8 + ch + 1) : (64 + h*8));
        __syncthreads();
        conv8(buf, dww + (h*8 + ch)*9, dq[ch]);
        float ss = 0.f;
        #pragma unroll
        for (int p = 0; p < 8; ++p) ss = fmaf(dq[ch][p], dq[ch][p], ss);
        ss = wsum(ss);
        if (lane == 0) atomicAdd(&sq_q[ch], ss);
    }

    // ---- K channels
    #pragma unroll
    for (int ch = 0; ch < 8; ++ch) {
        float* buf = sh + (ch & 1)*K4_BUF;
        write_lds(buf);
        issue_loads(ch < 7 ? (64 + h*8 + ch + 1) : (128 + h*8));
        __syncthreads();
        float dk[8];
        conv8(buf, dww + (64 + h*8 + ch)*9, dk);
        float ss = 0.f;
        #pragma unroll
        for (int p = 0; p < 8; ++p) ss = fmaf(dk[p], dk[p], ss);
        ss = wsum(ss);
        if (lane == 0) atomicAdd(&sq_k[ch], ss);
        #pragma unroll
        for (int c = 0; c < 8; ++c) {
            float acc = 0.f;
            #pragma unroll
            for (int p = 0; p < 8; ++p) acc = fmaf(dq[c][p], dk[p], acc);
            acc = wsum(acc);
            if (lane == 0) atomicAdd(&Sgb[c*8 + ch], acc);
        }
    }

    // ---- V channels
    #pragma unroll
    for (int ch = 0; ch < 8; ++ch) {
        float* buf = sh + (ch & 1)*K4_BUF;
        write_lds(buf);
        if (ch < 7) issue_loads(128 + h*8 + ch + 1);
        __syncthreads();
        float dv[8];
        conv8(buf, dww + (128 + h*8 + ch)*9, dv);
        float* vb = v + (size_t)(b*64 + h*8 + ch)*HWN + (r0 + lr)*256;
        *(float4*)&vb[c0]       = make_float4(dv[0],dv[1],dv[2],dv[3]);
        *(float4*)&vb[c0 + 128] = make_float4(dv[4],dv[5],dv[6],dv[7]);
    }

    // ---- fused k3: resp partial sums for thr (this block's group g == h)
    {
        float cwr[8], swr[8];
        #pragma unroll
        for (int c = 0; c < 8; ++c) {
            cwr[c] = cw[b*64 + h*8 + c];
            swr[c] = sw[h*8 + c];
        }
        const float sbg = sb[h];
        float rs = 0.f;
        const float* preb = pre + (size_t)(b*64 + h*8)*HWN + (size_t)(r0 + lr)*256;
        #pragma unroll
        for (int g2 = 0; g2 < 2; ++g2) {
            const int cc = c0 + g2*128;
            float xc[8][4];
            float spa0 = sbg, spa1 = sbg, spa2 = sbg, spa3 = sbg;
            #pragma unroll
            for (int c = 0; c < 8; ++c) {
                float4 xv = *(const float4*)&preb[(size_t)c*HWN + cc];
                xc[c][0] = xv.x*cwr[c]; xc[c][1] = xv.y*cwr[c];
                xc[c][2] = xv.z*cwr[c]; xc[c][3] = xv.w*cwr[c];
                spa0 = fmaf(xc[c][0], swr[c], spa0);
                spa1 = fmaf(xc[c][1], swr[c], spa1);
                spa2 = fmaf(xc[c][2], swr[c], spa2);
                spa3 = fmaf(xc[c][3], swr[c], spa3);
            }
            float sp0 = sgm(spa0), sp1 = sgm(spa1), sp2 = sgm(spa2), sp3 = sgm(spa3);
            #pragma unroll
            for (int c = 0; c < 8; ++c) {
                rs += sgm(xc[c][0]*sp0);
                rs += sgm(xc[c][1]*sp1);
                rs += sgm(xc[c][2]*sp2);
                rs += sgm(xc[c][3]*sp3);
            }
        }
        rs = wsum(rs);
        if (lane == 0) atomicAdd(&thr_sum[b*8 + h], rs);
    }
}

// ---------------------------------------------------------------------------
// K6: finalize attention weights and thr. single block.
// ---------------------------------------------------------------------------
__global__ void k6_attn(const float* __restrict__ Sg, const float* __restrict__ sumsq,
                        const float* __restrict__ temp, const float* __restrict__ kdynp,
                        const float* __restrict__ thr_sum, const float* __restrict__ scales,
                        float* __restrict__ A, float* __restrict__ thr)
{
    const int t = threadIdx.x;
    if (t < 32) thr[t] = thr_sum[t] * (1.0f/(8.0f*65536.0f));
    const int b = t >> 6, h = (t >> 3) & 7, c = t & 7;
    const float kd = *kdynp;
    const float ssum = scales[0]+scales[1]+scales[2]+scales[3];
    const float nq = fmaxf(sqrtf(sumsq[b*128 + h*8 + c]), 1e-12f);
    const float tv = temp[h];
    const float* Srow = Sg + (size_t)(b*8+h)*64 + c*8;
    float a[8];
    #pragma unroll
    for (int d = 0; d < 8; ++d) {
        float nk = fmaxf(sqrtf(sumsq[b*128 + 64 + h*8 + d]), 1e-12f);
        a[d] = Srow[d] / (nq*nk) * tv;
    }
    bool keep[8];
    #pragma unroll
    for (int d = 0; d < 8; ++d) {
        int r = 0;
        #pragma unroll
        for (int e = 0; e < 8; ++e)
            r += (a[e] > a[d]) || (a[e] == a[d] && e < d);
        keep[d] = ((float)r < kd);
    }
    float m = -INFINITY;
    #pragma unroll
    for (int d = 0; d < 8; ++d) if (keep[d]) m = fmaxf(m, a[d]);
    float ex[8]; float sum = 0.f;
    #pragma unroll
    for (int d = 0; d < 8; ++d) { ex[d] = keep[d] ? expf(a[d]-m) : 0.f; sum += ex[d]; }
    const float inv = ssum / sum;
    #pragma unroll
    for (int d = 0; d < 8; ++d)
        A[(size_t)(b*8+h)*64 + c*8 + d] = ex[d]*inv;
}

// ---------------------------------------------------------------------------
// K7: mask path + post conv + residual + attn@v + MFMA out-conv.
//
// R10: the out-conv (128x128, 4.3 of k7's 5.9 G-MAC) moves to matrix cores
// via SPLIT-BF16: x = hi + lo (truncated bf16 decomposition, exact), then
// W*X ~= Whi*Xhi + Whi*Xlo + Wlo*Xhi on mfma_f32_16x16x32_bf16 -- relative
// error ~2^-16, 3 MFMAs/tile ~ 5x the fp32-VALU rate. After post/attn
// results land in registers, the pr/vt LDS (64 KB) is dead and is aliased
// as XT_hi/XT_lo[128px][128c] bf16, written with the G4 XOR swizzle
// (ushort idx ^= (px&7)<<3) so the fragment ds_read_b128s are
// bank-conflict-free. Fragment layouts: A/B lane holds K=8*(lane>>4)+r;
// D: col=lane&15, row=(lane>>4)*4+reg (m89-verified). Wave owns 2 out-tiles
// x 8 px-tiles. W fragments built in-register from fp32 Wout (L2-resident).
// ---------------------------------------------------------------------------
__global__ __launch_bounds__(256,2) void k7_final(
    const float* __restrict__ pre, const float* __restrict__ lb, const float* __restrict__ v,
    const float* __restrict__ cw,  const float* __restrict__ thr,
    const float* __restrict__ sw,  const float* __restrict__ sb,
    const float* __restrict__ A,
    const float* __restrict__ Wpost, const float* __restrict__ bpost,
    const float* __restrict__ Wout,  float* __restrict__ out)
{
    __shared__ float smem[16384];          // 64 KB
    float* pr = smem;                      // [64 ch][128 px] fp32
    float* vt = smem + 8192;
    float4* pr4 = (float4*)pr;
    float4* vt4 = (float4*)vt;
    unsigned* XThi32 = (unsigned*)smem;            // aliases pr: [128px][64 u32]
    unsigned* XTlo32 = (unsigned*)(smem + 8192);   // aliases vt
    const unsigned short* XThi = (const unsigned short*)smem;
    const unsigned short* XTlo = (const unsigned short*)(smem + 8192);

    const int t   = threadIdx.x;
    const int blk = blockIdx.x;
    const int b   = blk >> 9;            // 512 blocks per batch
    const int p0  = (blk & 511) << 7;    // 128 px / block
    const int pg  = t & 15;              // px pg*4..+3 and 64+pg*4..+3
    const int og  = t >> 4;

    const float4* pre4g = (const float4*)pre;
    const float4* v4g   = (const float4*)v;
    #pragma unroll
    for (int i = 0; i < 8; ++i) {
        int idx = t + 256*i;
        int c = idx >> 5, q = idx & 31;
        size_t gi = (size_t)(b*64 + c)*16384 + (p0>>2) + q;
        pr4[c*32+q] = pre4g[gi];
        vt4[c*32+q] = v4g[gi];
    }
    __syncthreads();

    // ---- mask path, in place on pr
    #pragma unroll
    for (int s = 0; s < 4; ++s) {
        int task = t + 256*s;
        int g = task >> 7, px = task & 127;
        float xc[8], xv[8];
        float spa = sb[g];
        #pragma unroll
        for (int c = 0; c < 8; ++c) {
            xv[c] = pr[(g*8+c)*128 + px];
            xc[c] = xv[c]*cw[b*64 + g*8 + c];
            spa += xc[c]*sw[g*8 + c];
        }
        float sp = sgm(spa);
        float th = thr[b*8 + g];
        #pragma unroll
        for (int c = 0; c < 8; ++c) {
            float resp = sgm(xc[c]*sp);
            float mask = resp > th ? 1.0f : resp;
            pr[(g*8+c)*128 + px] = xv[c]*mask;
        }
    }
    __syncthreads();

    // ---- post conv (64x64) + bias + lb residual -> registers
    float postv[4][8];
    {
        const int o0 = og*4;
        float acc[4][8];
        #pragma unroll
        for (int j=0;j<4;++j)
            #pragma unroll
            for (int k=0;k<8;++k) acc[j][k]=0.f;
        const float4* W4 = (const float4*)Wpost;
        #pragma unroll 2
        for (int c = 0; c < 64; c += 4) {
            float4 xa0 = pr4[(c+0)*32 + pg],      xb0 = pr4[(c+0)*32 + 16 + pg];
            float4 xa1 = pr4[(c+1)*32 + pg],      xb1 = pr4[(c+1)*32 + 16 + pg];
            float4 xa2 = pr4[(c+2)*32 + pg],      xb2 = pr4[(c+2)*32 + 16 + pg];
            float4 xa3 = pr4[(c+3)*32 + pg],      xb3 = pr4[(c+3)*32 + 16 + pg];
            #pragma unroll
            for (int j = 0; j < 4; ++j) {
                float4 w = W4[(o0+j)*16 + (c>>2)];
                fma4(&acc[j][0], w, xa0,xa1,xa2,xa3);
                fma4(&acc[j][4], w, xb0,xb1,xb2,xb3);
            }
        }
        const float4* lb4 = (const float4*)lb;
        #pragma unroll
        for (int j = 0; j < 4; ++j) {
            float bs = bpost[o0+j];
            float4 l0 = lb4[(size_t)(b*64 + o0+j)*16384 + (p0>>2) + pg];
            float4 l1 = lb4[(size_t)(b*64 + o0+j)*16384 + (p0>>2) + 16 + pg];
            postv[j][0]=acc[j][0]+bs+l0.x; postv[j][1]=acc[j][1]+bs+l0.y;
            postv[j][2]=acc[j][2]+bs+l0.z; postv[j][3]=acc[j][3]+bs+l0.w;
            postv[j][4]=acc[j][4]+bs+l1.x; postv[j][5]=acc[j][5]+bs+l1.y;
            postv[j][6]=acc[j][6]+bs+l1.z; postv[j][7]=acc[j][7]+bs+l1.w;
        }
    }

    // ---- attn @ v -> registers
    float attv[4][8];
    {
        const int ch0 = og*4;
        #pragma unroll
        for (int j = 0; j < 4; ++j) {
            int ch = ch0 + j;
            int hh = ch >> 3, c = ch & 7;
            const float* Ar = A + (size_t)(b*8+hh)*64 + c*8;
            float a0=0.f,a1=0.f,a2=0.f,a3=0.f,a4=0.f,a5=0.f,a6=0.f,a7=0.f;
            #pragma unroll
            for (int d = 0; d < 8; ++d) {
                float av = Ar[d];
                float4 v0 = vt4[(hh*8+d)*32 + pg];
                float4 v1 = vt4[(hh*8+d)*32 + 16 + pg];
                a0 += av*v0.x; a1 += av*v0.y; a2 += av*v0.z; a3 += av*v0.w;
                a4 += av*v1.x; a5 += av*v1.y; a6 += av*v1.z; a7 += av*v1.w;
            }
            attv[j][0]=a0; attv[j][1]=a1; attv[j][2]=a2; attv[j][3]=a3;
            attv[j][4]=a4; attv[j][5]=a5; attv[j][6]=a6; attv[j][7]=a7;
        }
    }
    __syncthreads();   // all pr/vt reads complete -> LDS is now XT

    // ---- write XT_hi/XT_lo (bf16 split): c 0..63 = attn, 64..127 = post
    {
        #pragma unroll
        for (int half = 0; half < 2; ++half) {
            #pragma unroll
            for (int k = 0; k < 4; ++k) {
                const int px = half*64 + pg*4 + k;
                const int sw2 = (px & 7) << 2;
                const int rowb = px*64;
                #pragma unroll
                for (int jj = 0; jj < 4; jj += 2) {
                    float a0 = attv[jj][half*4+k], a1 = attv[jj+1][half*4+k];
                    int i32 = (rowb + ((og*4+jj)>>1)) ^ sw2;
                    XThi32[i32] = pack_hi2(a0, a1);
                    float ah0 = __uint_as_float(__float_as_uint(a0)&0xFFFF0000u);
                    float ah1 = __uint_as_float(__float_as_uint(a1)&0xFFFF0000u);
                    XTlo32[i32] = pack_hi2(a0-ah0, a1-ah1);
                    float q0 = postv[jj][half*4+k], q1 = postv[jj+1][half*4+k];
                    i32 = (rowb + ((64+og*4+jj)>>1)) ^ sw2;
                    XThi32[i32] = pack_hi2(q0, q1);
                    float qh0 = __uint_as_float(__float_as_uint(q0)&0xFFFF0000u);
                    float qh1 = __uint_as_float(__float_as_uint(q1)&0xFFFF0000u);
                    XTlo32[i32] = pack_hi2(q0-qh0, q1-qh1);
                }
            }
        }
    }
    __syncthreads();

    // ---- out conv via MFMA: wave owns out-tiles {2w,2w+1} x 8 px-tiles
    {
        const int lane = t & 63, wv = t >> 6;
        const int lm = lane & 15, lq = lane >> 4;
        #pragma unroll
        for (int oo = 0; oo < 2; ++oo) {
            const int ot = wv*2 + oo;
            f32x4 acc[8];
            #pragma unroll
            for (int pt = 0; pt < 8; ++pt) { acc[pt][0]=0.f; acc[pt][1]=0.f; acc[pt][2]=0.f; acc[pt][3]=0.f; }
            const int orow = ot*16 + lm;
            #pragma unroll
            for (int kk = 0; kk < 4; ++kk) {
                const int cbase = kk*32 + lq*8;
                const float* wp = Wout + orow*128 + cbase;
                float4 w0 = *(const float4*)wp;
                float4 w1 = *(const float4*)(wp+4);
                float we[8] = {w0.x,w0.y,w0.z,w0.w,w1.x,w1.y,w1.z,w1.w};
                bf16x8 Ahi, Alo;
                #pragma unroll
                for (int d = 0; d < 4; ++d) {
                    float e0 = we[2*d], e1 = we[2*d+1];
                    ((unsigned*)&Ahi)[d] = pack_hi2(e0, e1);
                    float h0 = __uint_as_float(__float_as_uint(e0)&0xFFFF0000u);
                    float h1 = __uint_as_float(__float_as_uint(e1)&0xFFFF0000u);
                    ((unsigned*)&Alo)[d] = pack_hi2(e0-h0, e1-h1);
                }
                #pragma unroll
                for (int pt = 0; pt < 8; ++pt) {
                    const int px = pt*16 + lm;
                    const int idx = (px*128 + cbase) ^ ((px&7)<<3);
                    bf16x8 Bhi = *(const bf16x8*)&XThi[idx];
                    bf16x8 Blo = *(const bf16x8*)&XTlo[idx];
                    acc[pt] = __builtin_amdgcn_mfma_f32_16x16x32_bf16(Ahi, Bhi, acc[pt], 0,0,0);
                    acc[pt] = __builtin_amdgcn_mfma_f32_16x16x32_bf16(Ahi, Blo, acc[pt], 0,0,0);
                    acc[pt] = __builtin_amdgcn_mfma_f32_16x16x32_bf16(Alo, Bhi, acc[pt], 0,0,0);
                }
            }
            #pragma unroll
            for (int pt = 0; pt < 8; ++pt) {
                const int px = p0 + pt*16 + lm;
                #pragma unroll
                for (int r = 0; r < 4; ++r) {
                    const int ch = ot*16 + lq*4 + r;
                    out[(size_t)(b*128 + ch)*HWN + px] = acc[pt][r];
                }
            }
        }
    }
}

// ---------------------------------------------------------------------------
extern "C" void kernel_launch(void* const* d_in, const int* in_sizes, int n_in,
                              void* d_out, int out_size, void* d_ws, size_t ws_size,
                              hipStream_t stream)
{
    const float* x     = (const float*)d_in[0];
    const float* Wp    = (const float*)d_in[1];
    const float* Wpre  = (const float*)d_in[2];
    const float* bpre  = (const float*)d_in[3];
    const float* w1    = (const float*)d_in[4];
    const float* b1    = (const float*)d_in[5];
    const float* w2    = (const float*)d_in[6];
    const float* b2    = (const float*)d_in[7];
    const float* sw    = (const float*)d_in[8];
    const float* sb    = (const float*)d_in[9];
    const float* Wpost = (const float*)d_in[10];
    const float* bpost = (const float*)d_in[11];
    const float* Wqkv  = (const float*)d_in[12];
    const float* dww   = (const float*)d_in[13];
    const float* Wg1   = (const float*)d_in[14];
    const float* bg1   = (const float*)d_in[15];
    const float* wg2   = (const float*)d_in[16];
    const float* bg2   = (const float*)d_in[17];
    const float* temp  = (const float*)d_in[18];
    const float* scales= (const float*)d_in[19];
    const float* Wout  = (const float*)d_in[20];
    float* out = (float*)d_out;

    float* ws = (float*)d_ws;
    float* pooled_part = ws;                 // 16384
    float* gate_part   = ws + 16384;         // 64
    float* thr_sum     = ws + 16448;         // 32
    float* sumsq       = ws + 16480;         // 512
    float* Sg          = ws + 16992;         // 2048
    float* cw          = ws + 19040;         // 256
    float* kdyn        = ws + 19296;         // 1
    float* thr         = ws + 19328;         // 32
    float* A           = ws + 19360;         // 2048

    float* lb  = ws + 32768;
    float* pre = lb  + 16777216;
    float* qkv = pre + 16777216;
    float* v   = qkv + 50331648;

    hipMemsetAsync(ws, 0, (size_t)19040*sizeof(float), stream);

    k1_proj <<<2048, 256, 0, stream>>>(x, Wp, Wpre, bpre, Wqkv, Wg1, bg1, wg2, bg2,
                                       lb, pre, qkv, pooled_part, gate_part);
    k2_small<<<1,    256, 0, stream>>>(pooled_part, gate_part, w1, b1, w2, b2, cw, kdyn);
    k4_dw   <<<1024, 256, 0, stream>>>(qkv, dww, pre, cw, sw, sb, v, Sg, sumsq, thr_sum);
    k6_attn <<<1,    256, 0, stream>>>(Sg, sumsq, temp, kdyn, thr_sum, scales, A, thr);
    k7_final<<<2048, 256, 0, stream>>>(pre, lb, v, cw, thr, sw, sb, A,
                                       Wpost, bpost, Wout, out);
}

// Round 12
// 714.596 us; speedup vs baseline: 1.7354x; 1.0311x over previous
//
#include <hip/hip_runtime.h>
#include <math.h>

#define HWN 65536

typedef __attribute__((ext_vector_type(8))) short bf16x8;
typedef __attribute__((ext_vector_type(4))) float f32x4;

__device__ __forceinline__ float sgm(float x){ return 1.0f/(1.0f+expf(-x)); }

__device__ __forceinline__ unsigned pack_hi2(float a, float b){
    // [b_hi16 : a_hi16] -- two truncated bf16s, low half = a
    return (__float_as_uint(b) & 0xFFFF0000u) | (__float_as_uint(a) >> 16);
}

__device__ __forceinline__ void fma4(float acc[4], const float4 w,
                                     const float4 x0, const float4 x1,
                                     const float4 x2, const float4 x3){
    acc[0] += w.x*x0.x + w.y*x1.x + w.z*x2.x + w.w*x3.x;
    acc[1] += w.x*x0.y + w.y*x1.y + w.z*x2.y + w.w*x3.y;
    acc[2] += w.x*x0.z + w.y*x1.z + w.z*x2.z + w.w*x3.z;
    acc[3] += w.x*x0.w + w.y*x1.w + w.z*x2.w + w.w*x3.w;
}

// ---------------------------------------------------------------------------
// K1: input_proj + lb store + lgce_pre (+pooled partials) + qkv + gate.
// R9 fp32 structure (8 px/thread, 128 px/block, unroll 2): 313 us, VGPR 128.
// R12 NOTE: R11's split-bf16 MFMA on qkv/gate FAILED accuracy (1.56e-2):
// q/k errors flip rank-topk comparisons; gate feeds floor() cliff. Split-bf16
// is only safe on output-linear paths. k1 stays fp32.
// launch_bounds(256,2): NEVER raise arg2 (R3: VGPR 64 -> 4 GB spill).
// ---------------------------------------------------------------------------
__global__ __launch_bounds__(256,2) void k1_proj(
    const float* __restrict__ x,   const float* __restrict__ Wp,
    const float* __restrict__ Wpre,const float* __restrict__ bpre,
    const float* __restrict__ Wqkv,
    const float* __restrict__ Wg1, const float* __restrict__ bg1,
    const float* __restrict__ wg2, const float* __restrict__ bg2,
    float* __restrict__ lb, float* __restrict__ pre, float* __restrict__ qkv,
    float* __restrict__ pooled_part, float* __restrict__ gate_part)
{
    __shared__ float st[128*128];         // 64 KB: x staging -> proj output -> ht alias
    float4* st4 = (float4*)st;
    float*  ht  = st;                     // 32x128 floats = 16 KB, used after barrier

    const int t    = threadIdx.x;
    const int blk  = blockIdx.x;
    const int b    = blk >> 9;            // 512 blocks per batch
    const int p0   = (blk & 511) << 7;    // 128 px / block
    const int pg   = t & 15;              // pixel group: px pg*4..+3 and 64+pg*4..+3
    const int og   = t >> 4;              // output group
    const int slot = blk & 63;

    const float4* x4 = (const float4*)x;

    // ---- stage all of x (one burst)
    #pragma unroll
    for (int i = 0; i < 16; ++i) {
        int idx = t + 256*i;
        int c = idx >> 5, q = idx & 31;
        st4[c*32 + q] = x4[(size_t)(b*128 + c)*16384 + (p0>>2) + q];
    }
    __syncthreads();

    // ---- proj (128x128): og owns outs og*8..+7, 8 px each -> acc[8][8]
    {
        const int o0 = og*8;
        float acc[8][8];
        #pragma unroll
        for (int j=0;j<8;++j)
            #pragma unroll
            for (int k=0;k<8;++k) acc[j][k]=0.f;
        const float4* W4 = (const float4*)Wp;
        #pragma unroll 2
        for (int c = 0; c < 128; c += 4) {
            float4 xa0 = st4[(c+0)*32 + pg],      xb0 = st4[(c+0)*32 + 16 + pg];
            float4 xa1 = st4[(c+1)*32 + pg],      xb1 = st4[(c+1)*32 + 16 + pg];
            float4 xa2 = st4[(c+2)*32 + pg],      xb2 = st4[(c+2)*32 + 16 + pg];
            float4 xa3 = st4[(c+3)*32 + pg],      xb3 = st4[(c+3)*32 + 16 + pg];
            #pragma unroll
            for (int j = 0; j < 8; ++j) {
                float4 w = W4[(o0+j)*32 + (c>>2)];
                fma4(&acc[j][0], w, xa0,xa1,xa2,xa3);
                fma4(&acc[j][4], w, xb0,xb1,xb2,xb3);
            }
        }
        __syncthreads();   // every thread done READING x before any overwrite

        #pragma unroll
        for (int j = 0; j < 8; ++j) {
            st4[(o0+j)*32 + pg]      = make_float4(acc[j][0],acc[j][1],acc[j][2],acc[j][3]);
            st4[(o0+j)*32 + 16 + pg] = make_float4(acc[j][4],acc[j][5],acc[j][6],acc[j][7]);
        }
        if (og < 8) {      // lb = proj channels 0..63, straight from registers
            float4* lb4 = (float4*)lb;
            #pragma unroll
            for (int j = 0; j < 8; ++j) {
                lb4[(size_t)(b*64 + o0+j)*16384 + (p0>>2) + pg] =
                    make_float4(acc[j][0],acc[j][1],acc[j][2],acc[j][3]);
                lb4[(size_t)(b*64 + o0+j)*16384 + (p0>>2) + 16 + pg] =
                    make_float4(acc[j][4],acc[j][5],acc[j][6],acc[j][7]);
            }
        }
    }
    __syncthreads();       // proj output ready

    // ---- pre conv (64x64): og owns 4 outs -> acc[4][8]; + pooled partials
    {
        const int o0 = og*4;
        float acc[4][8];
        #pragma unroll
        for (int j=0;j<4;++j)
            #pragma unroll
            for (int k=0;k<8;++k) acc[j][k]=0.f;
        const float4* W4 = (const float4*)Wpre;
        #pragma unroll 2
        for (int c = 0; c < 64; c += 4) {
            float4 xa0 = st4[(c+0)*32 + pg],      xb0 = st4[(c+0)*32 + 16 + pg];
            float4 xa1 = st4[(c+1)*32 + pg],      xb1 = st4[(c+1)*32 + 16 + pg];
            float4 xa2 = st4[(c+2)*32 + pg],      xb2 = st4[(c+2)*32 + 16 + pg];
            float4 xa3 = st4[(c+3)*32 + pg],      xb3 = st4[(c+3)*32 + 16 + pg];
            #pragma unroll
            for (int j = 0; j < 4; ++j) {
                float4 w = W4[(o0+j)*16 + (c>>2)];
                fma4(&acc[j][0], w, xa0,xa1,xa2,xa3);
                fma4(&acc[j][4], w, xb0,xb1,xb2,xb3);
            }
        }
        float4* pre4 = (float4*)pre;
        #pragma unroll
        for (int j = 0; j < 4; ++j) {
            float bs = bpre[o0+j];
            float4 v0 = make_float4(acc[j][0]+bs, acc[j][1]+bs, acc[j][2]+bs, acc[j][3]+bs);
            float4 v1 = make_float4(acc[j][4]+bs, acc[j][5]+bs, acc[j][6]+bs, acc[j][7]+bs);
            pre4[(size_t)(b*64 + o0+j)*16384 + (p0>>2) + pg]      = v0;
            pre4[(size_t)(b*64 + o0+j)*16384 + (p0>>2) + 16 + pg] = v1;
            float s = v0.x+v0.y+v0.z+v0.w + v1.x+v1.y+v1.z+v1.w;
            s += __shfl_xor(s,1); s += __shfl_xor(s,2);
            s += __shfl_xor(s,4); s += __shfl_xor(s,8);
            if (pg == 0) atomicAdd(&pooled_part[slot*256 + b*64 + o0 + j], s);
        }
    }

    // ---- qkv conv (192x64): og owns 12 outs, 2 chunks of 6 -> acc[6][8]
    #pragma unroll
    for (int chk = 0; chk < 2; ++chk) {
        const int o0 = og*12 + chk*6;
        float acc[6][8];
        #pragma unroll
        for (int j=0;j<6;++j)
            #pragma unroll
            for (int k=0;k<8;++k) acc[j][k]=0.f;
        const float4* W4 = (const float4*)Wqkv;
        #pragma unroll 2
        for (int c = 0; c < 64; c += 4) {
            float4 xa0 = st4[(64+c+0)*32 + pg],   xb0 = st4[(64+c+0)*32 + 16 + pg];
            float4 xa1 = st4[(64+c+1)*32 + pg],   xb1 = st4[(64+c+1)*32 + 16 + pg];
            float4 xa2 = st4[(64+c+2)*32 + pg],   xb2 = st4[(64+c+2)*32 + 16 + pg];
            float4 xa3 = st4[(64+c+3)*32 + pg],   xb3 = st4[(64+c+3)*32 + 16 + pg];
            #pragma unroll
            for (int j = 0; j < 6; ++j) {
                float4 w = W4[(o0+j)*16 + (c>>2)];
                fma4(&acc[j][0], w, xa0,xa1,xa2,xa3);
                fma4(&acc[j][4], w, xb0,xb1,xb2,xb3);
            }
        }
        float4* qkv4 = (float4*)qkv;
        #pragma unroll
        for (int j = 0; j < 6; ++j) {
            qkv4[(size_t)(b*192 + o0+j)*16384 + (p0>>2) + pg] =
                make_float4(acc[j][0],acc[j][1],acc[j][2],acc[j][3]);
            qkv4[(size_t)(b*192 + o0+j)*16384 + (p0>>2) + 16 + pg] =
                make_float4(acc[j][4],acc[j][5],acc[j][6],acc[j][7]);
        }
    }

    // ---- gate hidden (32x64): og owns 2 outs -> acc[2][8], held across barrier
    {
        const int o0 = og*2;
        float acc[2][8];
        #pragma unroll
        for (int j=0;j<2;++j)
            #pragma unroll
            for (int k=0;k<8;++k) acc[j][k]=0.f;
        const float4* W4 = (const float4*)Wg1;
        for (int c = 0; c < 64; c += 4) {
            float4 xa0 = st4[(64+c+0)*32 + pg],   xb0 = st4[(64+c+0)*32 + 16 + pg];
            float4 xa1 = st4[(64+c+1)*32 + pg],   xb1 = st4[(64+c+1)*32 + 16 + pg];
            float4 xa2 = st4[(64+c+2)*32 + pg],   xb2 = st4[(64+c+2)*32 + 16 + pg];
            float4 xa3 = st4[(64+c+3)*32 + pg],   xb3 = st4[(64+c+3)*32 + 16 + pg];
            #pragma unroll
            for (int j = 0; j < 2; ++j) {
                float4 w = W4[(o0+j)*16 + (c>>2)];
                fma4(&acc[j][0], w, xa0,xa1,xa2,xa3);
                fma4(&acc[j][4], w, xb0,xb1,xb2,xb3);
            }
        }
        __syncthreads();   // ALL pt reads complete before ht overwrites st
        #pragma unroll
        for (int j = 0; j < 2; ++j) {
            float bs = bg1[o0+j];
            #pragma unroll
            for (int k = 0; k < 4; ++k) {
                ht[(o0+j)*128 + pg*4 + k]      = fmaxf(acc[j][k]+bs,   0.0f);
                ht[(o0+j)*128 + 64 + pg*4 + k] = fmaxf(acc[j][4+k]+bs, 0.0f);
            }
        }
    }
    __syncthreads();

    // ---- gate scalar: 128 px, 2 waves, wave-reduce + atomic each
    if (t < 128) {
        float g = bg2[0];
        #pragma unroll
        for (int c = 0; c < 32; ++c) g += wg2[c]*ht[c*128 + t];
        g = sgm(g);
        g += __shfl_xor(g,1);  g += __shfl_xor(g,2);  g += __shfl_xor(g,4);
        g += __shfl_xor(g,8);  g += __shfl_xor(g,16); g += __shfl_xor(g,32);
        if ((t & 63) == 0) atomicAdd(&gate_part[slot], g);
    }
}

// ---------------------------------------------------------------------------
// K2: pooled -> cw, gate mean -> kdyn. single block.
// ---------------------------------------------------------------------------
__global__ void k2_small(const float* __restrict__ pooled_part,
                         const float* __restrict__ gate_part,
                         const float* __restrict__ w1, const float* __restrict__ b1,
                         const float* __restrict__ w2, const float* __restrict__ b2,
                         float* __restrict__ cw, float* __restrict__ kdyn)
{
    __shared__ float pl[256];
    const int t = threadIdx.x;
    float s = 0.f;
    for (int sl = 0; sl < 64; ++sl) s += pooled_part[sl*256 + t];
    pl[t] = s * (1.0f/65536.0f);
    __syncthreads();
    const int b = t >> 6, g = (t >> 3) & 7, c = t & 7;
    float h0 = b1[g*2+0], h1 = b1[g*2+1];
    #pragma unroll
    for (int cc = 0; cc < 8; ++cc) {
        float p = pl[b*64 + g*8 + cc];
        h0 += p*w1[g*16 + 0*8 + cc];
        h1 += p*w1[g*16 + 1*8 + cc];
    }
    h0 = fmaxf(h0, 0.f); h1 = fmaxf(h1, 0.f);
    cw[t] = sgm(h0*w2[g*16 + c*2 + 0] + h1*w2[g*16 + c*2 + 1] + b2[g*8+c]);
    if (t == 0) {
        float gs = 0.f;
        for (int sl = 0; sl < 64; ++sl) gs += gate_part[sl];
        float kd = floorf(8.0f * (gs * (1.0f/262144.0f)));
        *kdyn = fminf(fmaxf(kd, 1.0f), 8.0f);
    }
}

// ---------------------------------------------------------------------------
// K4: depthwise 3x3 + FUSED group-gate resp sums. See R9 notes.
// ---------------------------------------------------------------------------
#define K4_ROWSTRIDE 264            // 4 pad | 256 data | 4 pad (floats)
#define K4_BUF (10*K4_ROWSTRIDE)    // 10 halo rows

__global__ __launch_bounds__(256,3) void k4_dw(
    const float* __restrict__ qkv, const float* __restrict__ dww,
    const float* __restrict__ pre, const float* __restrict__ cw,
    const float* __restrict__ sw,  const float* __restrict__ sb,
    float* __restrict__ v, float* __restrict__ Sg, float* __restrict__ sumsq,
    float* __restrict__ thr_sum)
{
    __shared__ float sh[2*K4_BUF];  // 21120 B

    const int t    = threadIdx.x;
    const int b    = blockIdx.x >> 8;         // 256 blocks / batch
    const int h    = (blockIdx.x >> 5) & 7;
    const int band = blockIdx.x & 31;
    const int r0   = band * 8;
    const int lr   = t >> 5;                  // output row 0..7
    const int c0   = (t & 31) * 4;            // group0 cols c0..c0+3; group1 +128
    const int lane = t & 63;

    if (t < 40) {
        int bufi = t / 20, r = (t % 20) >> 1, side = t & 1;
        sh[bufi*K4_BUF + r*K4_ROWSTRIDE + (side ? 260 : 3)] = 0.0f;
    }

    float4 reg[3];

    auto issue_loads = [&](int ch) {
        const float4* base = (const float4*)(qkv + (size_t)(b*192 + ch)*HWN);
        #pragma unroll
        for (int j = 0; j < 3; ++j) {
            int i = t + 256*j;
            float4 val = make_float4(0.f,0.f,0.f,0.f);
            if (i < 640) {
                int row = i >> 6, col4 = i & 63;
                int gy = r0 - 1 + row;
                if (gy >= 0 && gy < 256) val = base[gy*64 + col4];
            }
            reg[j] = val;
        }
    };

    auto write_lds = [&](float* buf) {
        #pragma unroll
        for (int j = 0; j < 3; ++j) {
            int i = t + 256*j;
            if (i < 640) {
                int row = i >> 6, col4 = i & 63;
                *(float4*)&buf[row*K4_ROWSTRIDE + 4 + col4*4] = reg[j];
            }
        }
    };

    auto conv8 = [&](const float* buf, const float* __restrict__ w9, float out[8]) {
        #pragma unroll
        for (int g = 0; g < 2; ++g) {
            const int cc = c0 + g*128;
            float a0=0.f, a1=0.f, a2=0.f, a3=0.f;
            #pragma unroll
            for (int rr = 0; rr < 3; ++rr) {
                const float* row = &buf[(lr+rr)*K4_ROWSTRIDE + 4 + cc];
                float4 m = *(const float4*)row;
                float l = row[-1], r = row[4];
                float w0 = w9[rr*3+0], w1 = w9[rr*3+1], w2 = w9[rr*3+2];
                a0 = fmaf(w0,l,   fmaf(w1,m.x, fmaf(w2,m.y, a0)));
                a1 = fmaf(w0,m.x, fmaf(w1,m.y, fmaf(w2,m.z, a1)));
                a2 = fmaf(w0,m.y, fmaf(w1,m.z, fmaf(w2,m.w, a2)));
                a3 = fmaf(w0,m.z, fmaf(w1,m.w, fmaf(w2,r,   a3)));
            }
            out[g*4+0]=a0; out[g*4+1]=a1; out[g*4+2]=a2; out[g*4+3]=a3;
        }
    };

    auto wsum = [&](float val) {
        val += __shfl_xor(val,1);  val += __shfl_xor(val,2);  val += __shfl_xor(val,4);
        val += __shfl_xor(val,8);  val += __shfl_xor(val,16); val += __shfl_xor(val,32);
        return val;
    };

    float dq[8][8];

    float* sq_q = &sumsq[b*128 + h*8];
    float* sq_k = &sumsq[b*128 + 64 + h*8];
    float* Sgb  = &Sg[(size_t)(b*8+h)*64];

    issue_loads(h*8 + 0);   // first q channel

    // ---- Q channels
    #pragma unroll
    for (int ch = 0; ch < 8; ++ch) {
        float* buf = sh + (ch & 1)*K4_BUF;
        write_lds(buf);
        issue_loads(ch < 7 ? (h*8 + ch + 1) : (64 + h*8));
        __syncthreads();
        conv8(buf, dww + (h*8 + ch)*9, dq[ch]);
        float ss = 0.f;
        #pragma unroll
        for (int p = 0; p < 8; ++p) ss = fmaf(dq[ch][p], dq[ch][p], ss);
        ss = wsum(ss);
        if (lane == 0) atomicAdd(&sq_q[ch], ss);
    }

    // ---- K channels
    #pragma unroll
    for (int ch = 0; ch < 8; ++ch) {
        float* buf = sh + (ch & 1)*K4_BUF;
        write_lds(buf);
        issue_loads(ch < 7 ? (64 + h*8 + ch + 1) : (128 + h*8));
        __syncthreads();
        float dk[8];
        conv8(buf, dww + (64 + h*8 + ch)*9, dk);
        float ss = 0.f;
        #pragma unroll
        for (int p = 0; p < 8; ++p) ss = fmaf(dk[p], dk[p], ss);
        ss = wsum(ss);
        if (lane == 0) atomicAdd(&sq_k[ch], ss);
        #pragma unroll
        for (int c = 0; c < 8; ++c) {
            float acc = 0.f;
            #pragma unroll
            for (int p = 0; p < 8; ++p) acc = fmaf(dq[c][p], dk[p], acc);
            acc = wsum(acc);
            if (lane == 0) atomicAdd(&Sgb[c*8 + ch], acc);
        }
    }

    // ---- V channels
    #pragma unroll
    for (int ch = 0; ch < 8; ++ch) {
        float* buf = sh + (ch & 1)*K4_BUF;
        write_lds(buf);
        if (ch < 7) issue_loads(128 + h*8 + ch + 1);
        __syncthreads();
        float dv[8];
        conv8(buf, dww + (128 + h*8 + ch)*9, dv);
        float* vb = v + (size_t)(b*64 + h*8 + ch)*HWN + (r0 + lr)*256;
        *(float4*)&vb[c0]       = make_float4(dv[0],dv[1],dv[2],dv[3]);
        *(float4*)&vb[c0 + 128] = make_float4(dv[4],dv[5],dv[6],dv[7]);
    }

    // ---- fused k3: resp partial sums for thr (this block's group g == h)
    {
        float cwr[8], swr[8];
        #pragma unroll
        for (int c = 0; c < 8; ++c) {
            cwr[c] = cw[b*64 + h*8 + c];
            swr[c] = sw[h*8 + c];
        }
        const float sbg = sb[h];
        float rs = 0.f;
        const float* preb = pre + (size_t)(b*64 + h*8)*HWN + (size_t)(r0 + lr)*256;
        #pragma unroll
        for (int g2 = 0; g2 < 2; ++g2) {
            const int cc = c0 + g2*128;
            float xc[8][4];
            float spa0 = sbg, spa1 = sbg, spa2 = sbg, spa3 = sbg;
            #pragma unroll
            for (int c = 0; c < 8; ++c) {
                float4 xv = *(const float4*)&preb[(size_t)c*HWN + cc];
                xc[c][0] = xv.x*cwr[c]; xc[c][1] = xv.y*cwr[c];
                xc[c][2] = xv.z*cwr[c]; xc[c][3] = xv.w*cwr[c];
                spa0 = fmaf(xc[c][0], swr[c], spa0);
                spa1 = fmaf(xc[c][1], swr[c], spa1);
                spa2 = fmaf(xc[c][2], swr[c], spa2);
                spa3 = fmaf(xc[c][3], swr[c], spa3);
            }
            float sp0 = sgm(spa0), sp1 = sgm(spa1), sp2 = sgm(spa2), sp3 = sgm(spa3);
            #pragma unroll
            for (int c = 0; c < 8; ++c) {
                rs += sgm(xc[c][0]*sp0);
                rs += sgm(xc[c][1]*sp1);
                rs += sgm(xc[c][2]*sp2);
                rs += sgm(xc[c][3]*sp3);
            }
        }
        rs = wsum(rs);
        if (lane == 0) atomicAdd(&thr_sum[b*8 + h], rs);
    }
}

// ---------------------------------------------------------------------------
// K6: finalize attention weights and thr. single block.
// ---------------------------------------------------------------------------
__global__ void k6_attn(const float* __restrict__ Sg, const float* __restrict__ sumsq,
                        const float* __restrict__ temp, const float* __restrict__ kdynp,
                        const float* __restrict__ thr_sum, const float* __restrict__ scales,
                        float* __restrict__ A, float* __restrict__ thr)
{
    const int t = threadIdx.x;
    if (t < 32) thr[t] = thr_sum[t] * (1.0f/(8.0f*65536.0f));
    const int b = t >> 6, h = (t >> 3) & 7, c = t & 7;
    const float kd = *kdynp;
    const float ssum = scales[0]+scales[1]+scales[2]+scales[3];
    const float nq = fmaxf(sqrtf(sumsq[b*128 + h*8 + c]), 1e-12f);
    const float tv = temp[h];
    const float* Srow = Sg + (size_t)(b*8+h)*64 + c*8;
    float a[8];
    #pragma unroll
    for (int d = 0; d < 8; ++d) {
        float nk = fmaxf(sqrtf(sumsq[b*128 + 64 + h*8 + d]), 1e-12f);
        a[d] = Srow[d] / (nq*nk) * tv;
    }
    bool keep[8];
    #pragma unroll
    for (int d = 0; d < 8; ++d) {
        int r = 0;
        #pragma unroll
        for (int e = 0; e < 8; ++e)
            r += (a[e] > a[d]) || (a[e] == a[d] && e < d);
        keep[d] = ((float)r < kd);
    }
    float m = -INFINITY;
    #pragma unroll
    for (int d = 0; d < 8; ++d) if (keep[d]) m = fmaxf(m, a[d]);
    float ex[8]; float sum = 0.f;
    #pragma unroll
    for (int d = 0; d < 8; ++d) { ex[d] = keep[d] ? expf(a[d]-m) : 0.f; sum += ex[d]; }
    const float inv = ssum / sum;
    #pragma unroll
    for (int d = 0; d < 8; ++d)
        A[(size_t)(b*8+h)*64 + c*8 + d] = ex[d]*inv;
}

// ---------------------------------------------------------------------------
// K7: mask path + MFMA post conv + residual + attn@v + MFMA out-conv.
//
// R12: post conv joins the out-conv on matrix cores (both output-linear, so
// split-bf16 is numerically safe; mask decisions still use exact fp32 pre).
// Pipeline: load pr/vt fp32 -> mask values into REGISTERS -> bar -> write
// masked x as split-bf16 XP[128px][64c] (aliases dead pr region, swizzled)
// -> bar -> {post conv MFMA reads XP; attn@v reads vt} -> bar -> write
// out-XT (attn half from attv, post+lb half from postv) over full 64 KB
// -> bar -> out conv MFMA (R10-verified).
// ---------------------------------------------------------------------------
__global__ __launch_bounds__(256,2) void k7_final(
    const float* __restrict__ pre, const float* __restrict__ lb, const float* __restrict__ v,
    const float* __restrict__ cw,  const float* __restrict__ thr,
    const float* __restrict__ sw,  const float* __restrict__ sb,
    const float* __restrict__ A,
    const float* __restrict__ Wpost, const float* __restrict__ bpost,
    const float* __restrict__ Wout,  float* __restrict__ out)
{
    __shared__ float smem[16384];          // 64 KB
    float* pr = smem;                      // [64 ch][128 px] fp32 (pre)
    float* vt = smem + 8192;               // [64 ch][128 px] fp32 (v)
    float4* pr4 = (float4*)pr;
    float4* vt4 = (float4*)vt;
    // masked-x split-bf16 (aliases pr region after mask):
    unsigned* XPhi32 = (unsigned*)smem;            // [128px][32 u32]
    unsigned* XPlo32 = (unsigned*)(smem + 4096);
    const unsigned short* XPhi = (const unsigned short*)smem;
    const unsigned short* XPlo = (const unsigned short*)(smem + 4096);
    // out-conv operand split-bf16 (full 64 KB):
    unsigned* XThi32 = (unsigned*)smem;            // [128px][64 u32]
    unsigned* XTlo32 = (unsigned*)(smem + 8192);
    const unsigned short* XThi = (const unsigned short*)smem;
    const unsigned short* XTlo = (const unsigned short*)(smem + 8192);

    const int t   = threadIdx.x;
    const int blk = blockIdx.x;
    const int b   = blk >> 9;            // 512 blocks per batch
    const int p0  = (blk & 511) << 7;    // 128 px / block
    const int pg  = t & 15;              // px pg*4..+3 and 64+pg*4..+3
    const int og  = t >> 4;
    const int lane = t & 63, wv = t >> 6;
    const int lm = lane & 15, lq = lane >> 4;

    const float4* pre4g = (const float4*)pre;
    const float4* v4g   = (const float4*)v;
    #pragma unroll
    for (int i = 0; i < 8; ++i) {
        int idx = t + 256*i;
        int c = idx >> 5, q = idx & 31;
        size_t gi = (size_t)(b*64 + c)*16384 + (p0>>2) + q;
        pr4[c*32+q] = pre4g[gi];
        vt4[c*32+q] = v4g[gi];
    }
    __syncthreads();

    // ---- mask path: read pr, compute masked values into registers
    float mk[4][8];
    #pragma unroll
    for (int s = 0; s < 4; ++s) {
        int task = t + 256*s;
        int g = task >> 7, px = task & 127;
        float xc[8], xv[8];
        float spa = sb[g];
        #pragma unroll
        for (int c = 0; c < 8; ++c) {
            xv[c] = pr[(g*8+c)*128 + px];
            xc[c] = xv[c]*cw[b*64 + g*8 + c];
            spa += xc[c]*sw[g*8 + c];
        }
        float sp = sgm(spa);
        float th = thr[b*8 + g];
        #pragma unroll
        for (int c = 0; c < 8; ++c) {
            float resp = sgm(xc[c]*sp);
            float mask = resp > th ? 1.0f : resp;
            mk[s][c] = xv[c]*mask;
        }
    }
    __syncthreads();   // all pr reads done

    // ---- write masked x as split-bf16 XP (overwrites pr region)
    #pragma unroll
    for (int s = 0; s < 4; ++s) {
        int task = t + 256*s;
        int g = task >> 7, px = task & 127;
        const int sw2 = (px & 7) << 2;
        const int rowb = px*32;
        #pragma unroll
        for (int c = 0; c < 8; c += 2) {
            float e0 = mk[s][c], e1 = mk[s][c+1];
            int i32 = (rowb + g*4 + (c>>1)) ^ sw2;
            XPhi32[i32] = pack_hi2(e0, e1);
            float h0 = __uint_as_float(__float_as_uint(e0)&0xFFFF0000u);
            float h1 = __uint_as_float(__float_as_uint(e1)&0xFFFF0000u);
            XPlo32[i32] = pack_hi2(e0-h0, e1-h1);
        }
    }
    __syncthreads();

    // ---- post conv (64x64) via MFMA + bias + lb -> postv[8][4]
    float postv[8][4];
    {
        const int ot = wv;                  // 4 waves x 1 out-tile
        const int orow = ot*16 + lm;        // 0..63
        f32x4 acc[8];
        #pragma unroll
        for (int pt = 0; pt < 8; ++pt) { acc[pt][0]=0.f; acc[pt][1]=0.f; acc[pt][2]=0.f; acc[pt][3]=0.f; }
        #pragma unroll
        for (int kk = 0; kk < 2; ++kk) {
            const int cbase = kk*32 + lq*8;
            const float* wp = Wpost + orow*64 + cbase;
            float4 w0 = *(const float4*)wp;
            float4 w1 = *(const float4*)(wp+4);
            float we[8] = {w0.x,w0.y,w0.z,w0.w,w1.x,w1.y,w1.z,w1.w};
            bf16x8 Ahi, Alo;
            #pragma unroll
            for (int d = 0; d < 4; ++d) {
                float e0 = we[2*d], e1 = we[2*d+1];
                ((unsigned*)&Ahi)[d] = pack_hi2(e0, e1);
                float h0 = __uint_as_float(__float_as_uint(e0)&0xFFFF0000u);
                float h1 = __uint_as_float(__float_as_uint(e1)&0xFFFF0000u);
                ((unsigned*)&Alo)[d] = pack_hi2(e0-h0, e1-h1);
            }
            #pragma unroll
            for (int pt = 0; pt < 8; ++pt) {
                const int px = pt*16 + lm;
                const int idx = (px*64 + cbase) ^ ((px&7)<<3);
                bf16x8 Bhi = *(const bf16x8*)&XPhi[idx];
                bf16x8 Blo = *(const bf16x8*)&XPlo[idx];
                acc[pt] = __builtin_amdgcn_mfma_f32_16x16x32_bf16(Ahi, Bhi, acc[pt], 0,0,0);
                acc[pt] = __builtin_amdgcn_mfma_f32_16x16x32_bf16(Ahi, Blo, acc[pt], 0,0,0);
                acc[pt] = __builtin_amdgcn_mfma_f32_16x16x32_bf16(Alo, Bhi, acc[pt], 0,0,0);
            }
        }
        #pragma unroll
        for (int pt = 0; pt < 8; ++pt) {
            const int px = p0 + pt*16 + lm;
            #pragma unroll
            for (int r = 0; r < 4; ++r) {
                const int ch = ot*16 + lq*4 + r;
                postv[pt][r] = acc[pt][r] + bpost[ch]
                             + lb[(size_t)(b*64 + ch)*HWN + px];
            }
        }
    }

    // ---- attn @ v -> attv[4][8] (og/pg mapping; vt fp32 intact)
    float attv[4][8];
    {
        const int ch0 = og*4;
        #pragma unroll
        for (int j = 0; j < 4; ++j) {
            int ch = ch0 + j;
            int hh = ch >> 3, c = ch & 7;
            const float* Ar = A + (size_t)(b*8+hh)*64 + c*8;
            float a0=0.f,a1=0.f,a2=0.f,a3=0.f,a4=0.f,a5=0.f,a6=0.f,a7=0.f;
            #pragma unroll
            for (int d = 0; d < 8; ++d) {
                float av = Ar[d];
                float4 v0 = vt4[(hh*8+d)*32 + pg];
                float4 v1 = vt4[(hh*8+d)*32 + 16 + pg];
                a0 += av*v0.x; a1 += av*v0.y; a2 += av*v0.z; a3 += av*v0.w;
                a4 += av*v1.x; a5 += av*v1.y; a6 += av*v1.z; a7 += av*v1.w;
            }
            attv[j][0]=a0; attv[j][1]=a1; attv[j][2]=a2; attv[j][3]=a3;
            attv[j][4]=a4; attv[j][5]=a5; attv[j][6]=a6; attv[j][7]=a7;
        }
    }
    __syncthreads();   // XP reads + vt reads complete -> full 64 KB is XT

    // ---- write out-XT: attn half (ch 0..63, og/pg mapping)
    {
        #pragma unroll
        for (int half = 0; half < 2; ++half) {
            #pragma unroll
            for (int k = 0; k < 4; ++k) {
                const int px = half*64 + pg*4 + k;
                const int sw2 = (px & 7) << 2;
                const int rowb = px*64;
                #pragma unroll
                for (int jj = 0; jj < 4; jj += 2) {
                    float a0 = attv[jj][half*4+k], a1 = attv[jj+1][half*4+k];
                    int i32 = (rowb + ((og*4+jj)>>1)) ^ sw2;
                    XThi32[i32] = pack_hi2(a0, a1);
                    float ah0 = __uint_as_float(__float_as_uint(a0)&0xFFFF0000u);
                    float ah1 = __uint_as_float(__float_as_uint(a1)&0xFFFF0000u);
                    XTlo32[i32] = pack_hi2(a0-ah0, a1-ah1);
                }
            }
        }
    }
    // ---- write out-XT: post half (ch 64..127, lane mapping from postv)
    {
        const int ot = wv;
        const int colb = 32 + ((ot*16 + lq*4) >> 1);   // u32 col, 32..63
        #pragma unroll
        for (int pt = 0; pt < 8; ++pt) {
            const int px = pt*16 + lm;
            const int sw2 = (px & 7) << 2;
            const int rowb = px*64;
            float q0 = postv[pt][0], q1 = postv[pt][1];
            int i32 = (rowb + colb) ^ sw2;
            XThi32[i32] = pack_hi2(q0, q1);
            float h0 = __uint_as_float(__float_as_uint(q0)&0xFFFF0000u);
            float h1 = __uint_as_float(__float_as_uint(q1)&0xFFFF0000u);
            XTlo32[i32] = pack_hi2(q0-h0, q1-h1);
            float q2 = postv[pt][2], q3 = postv[pt][3];
            i32 = (rowb + colb + 1) ^ sw2;
            XThi32[i32] = pack_hi2(q2, q3);
            float h2 = __uint_as_float(__float_as_uint(q2)&0xFFFF0000u);
            float h3 = __uint_as_float(__float_as_uint(q3)&0xFFFF0000u);
            XTlo32[i32] = pack_hi2(q2-h2, q3-h3);
        }
    }
    __syncthreads();

    // ---- out conv via MFMA (R10-verified): wave owns out-tiles {2w,2w+1}
    {
        #pragma unroll
        for (int oo = 0; oo < 2; ++oo) {
            const int ot = wv*2 + oo;
            f32x4 acc[8];
            #pragma unroll
            for (int pt = 0; pt < 8; ++pt) { acc[pt][0]=0.f; acc[pt][1]=0.f; acc[pt][2]=0.f; acc[pt][3]=0.f; }
            const int orow = ot*16 + lm;
            #pragma unroll
            for (int kk = 0; kk < 4; ++kk) {
                const int cbase = kk*32 + lq*8;
                const float* wp = Wout + orow*128 + cbase;
                float4 w0 = *(const float4*)wp;
                float4 w1 = *(const float4*)(wp+4);
                float we[8] = {w0.x,w0.y,w0.z,w0.w,w1.x,w1.y,w1.z,w1.w};
                bf16x8 Ahi, Alo;
                #pragma unroll
                for (int d = 0; d < 4; ++d) {
                    float e0 = we[2*d], e1 = we[2*d+1];
                    ((unsigned*)&Ahi)[d] = pack_hi2(e0, e1);
                    float h0 = __uint_as_float(__float_as_uint(e0)&0xFFFF0000u);
                    float h1 = __uint_as_float(__float_as_uint(e1)&0xFFFF0000u);
                    ((unsigned*)&Alo)[d] = pack_hi2(e0-h0, e1-h1);
                }
                #pragma unroll
                for (int pt = 0; pt < 8; ++pt) {
                    const int px = pt*16 + lm;
                    const int idx = (px*128 + cbase) ^ ((px&7)<<3);
                    bf16x8 Bhi = *(const bf16x8*)&XThi[idx];
                    bf16x8 Blo = *(const bf16x8*)&XTlo[idx];
                    acc[pt] = __builtin_amdgcn_mfma_f32_16x16x32_bf16(Ahi, Bhi, acc[pt], 0,0,0);
                    acc[pt] = __builtin_amdgcn_mfma_f32_16x16x32_bf16(Ahi, Blo, acc[pt], 0,0,0);
                    acc[pt] = __builtin_amdgcn_mfma_f32_16x16x32_bf16(Alo, Bhi, acc[pt], 0,0,0);
                }
            }
            #pragma unroll
            for (int pt = 0; pt < 8; ++pt) {
                const int px = p0 + pt*16 + lm;
                #pragma unroll
                for (int r = 0; r < 4; ++r) {
                    const int ch = ot*16 + lq*4 + r;
                    out[(size_t)(b*128 + ch)*HWN + px] = acc[pt][r];
                }
            }
        }
    }
}

// ---------------------------------------------------------------------------
extern "C" void kernel_launch(void* const* d_in, const int* in_sizes, int n_in,
                              void* d_out, int out_size, void* d_ws, size_t ws_size,
                              hipStream_t stream)
{
    const float* x     = (const float*)d_in[0];
    const float* Wp    = (const float*)d_in[1];
    const float* Wpre  = (const float*)d_in[2];
    const float* bpre  = (const float*)d_in[3];
    const float* w1    = (const float*)d_in[4];
    const float* b1    = (const float*)d_in[5];
    const float* w2    = (const float*)d_in[6];
    const float* b2    = (const float*)d_in[7];
    const float* sw    = (const float*)d_in[8];
    const float* sb    = (const float*)d_in[9];
    const float* Wpost = (const float*)d_in[10];
    const float* bpost = (const float*)d_in[11];
    const float* Wqkv  = (const float*)d_in[12];
    const float* dww   = (const float*)d_in[13];
    const float* Wg1   = (const float*)d_in[14];
    const float* bg1   = (const float*)d_in[15];
    const float* wg2   = (const float*)d_in[16];
    const float* bg2   = (const float*)d_in[17];
    const float* temp  = (const float*)d_in[18];
    const float* scales= (const float*)d_in[19];
    const float* Wout  = (const float*)d_in[20];
    float* out = (float*)d_out;

    float* ws = (float*)d_ws;
    float* pooled_part = ws;                 // 16384
    float* gate_part   = ws + 16384;         // 64
    float* thr_sum     = ws + 16448;         // 32
    float* sumsq       = ws + 16480;         // 512
    float* Sg          = ws + 16992;         // 2048
    float* cw          = ws + 19040;         // 256
    float* kdyn        = ws + 19296;         // 1
    float* thr         = ws + 19328;         // 32
    float* A           = ws + 19360;         // 2048

    float* lb  = ws + 32768;
    float* pre = lb  + 16777216;
    float* qkv = pre + 16777216;
    float* v   = qkv + 50331648;

    hipMemsetAsync(ws, 0, (size_t)19040*sizeof(float), stream);

    k1_proj <<<2048, 256, 0, stream>>>(x, Wp, Wpre, bpre, Wqkv, Wg1, bg1, wg2, bg2,
                                       lb, pre, qkv, pooled_part, gate_part);
    k2_small<<<1,    256, 0, stream>>>(pooled_part, gate_part, w1, b1, w2, b2, cw, kdyn);
    k4_dw   <<<1024, 256, 0, stream>>>(qkv, dww, pre, cw, sw, sb, v, Sg, sumsq, thr_sum);
    k6_attn <<<1,    256, 0, stream>>>(Sg, sumsq, temp, kdyn, thr_sum, scales, A, thr);
    k7_final<<<2048, 256, 0, stream>>>(pre, lb, v, cw, thr, sw, sb, A,
                                       Wpost, bpost, Wout, out);
}